// Round 1
// baseline (3637.554 us; speedup 1.0000x reference)
//
#include <hip/hip_runtime.h>
#include <math.h>

#define NBATCH 4

// ---------------------------------------------------------------------------
// kNN-16 with ball filter: top-16 smallest d2 (ties -> lower index), replace
// out-of-ball entries by self. d2 computed exactly as reference pdist2:
// max(aa + bb - 2*ab, 0), no fma contraction.
// ---------------------------------------------------------------------------
__global__ __launch_bounds__(256) void knn16_kernel(const float* __restrict__ xyz, int N,
                                                    float r2, int* __restrict__ idx_out,
                                                    int total) {
#pragma clang fp contract(off)
  int gid = blockIdx.x * 256 + threadIdx.x;
  if (gid >= total) return;
  int b = gid / N, n = gid - b * N;
  const float* xb = xyz + (size_t)b * N * 3;
  float qx = xb[n * 3 + 0], qy = xb[n * 3 + 1], qz = xb[n * 3 + 2];
  float qq = qx * qx + qy * qy + qz * qz;
  float v[16];
  int id[16];
#pragma unroll
  for (int k = 0; k < 16; ++k) { v[k] = 3.0e38f; id[k] = n; }
  for (int m = 0; m < N; ++m) {
    float cx = xb[m * 3 + 0], cy = xb[m * 3 + 1], cz = xb[m * 3 + 2];
    float cc = cx * cx + cy * cy + cz * cz;
    float ab = qx * cx + qy * cy + qz * cz;
    float d2 = qq + cc - 2.0f * ab;
    d2 = fmaxf(d2, 0.0f);
    if (d2 < v[15]) {   // strict <: equal d2 with later index excluded (stable top_k)
      v[15] = d2; id[15] = m;
#pragma unroll
      for (int j = 15; j > 0; --j) {
        if (v[j] < v[j - 1]) {
          float tv = v[j]; v[j] = v[j - 1]; v[j - 1] = tv;
          int ti = id[j]; id[j] = id[j - 1]; id[j - 1] = ti;
        }
      }
    }
  }
  int* op = idx_out + (size_t)gid * 16;
#pragma unroll
  for (int k = 0; k < 16; ++k) op[k] = (v[k] <= r2) ? id[k] : n;
}

// ---------------------------------------------------------------------------
// Furthest point sampling. One block (256 threads) per batch. dist kept in
// registers (PTS points per thread). Argmax tie -> lowest point index
// (matches jnp.argmax). Distance = direct (x-c)^2 form like the reference.
// Also emits gathered xyz_out.
// ---------------------------------------------------------------------------
template <int PTS>
__global__ __launch_bounds__(256) void fps_kernel(const float* __restrict__ xyz, int N,
                                                  int npoint, int* __restrict__ idx_out,
                                                  float* __restrict__ xyz_out) {
#pragma clang fp contract(off)
  int b = blockIdx.x;
  int tid = threadIdx.x;
  const float* xb = xyz + (size_t)b * N * 3;
  __shared__ float rv[8];
  __shared__ int ri[8];
  __shared__ int hist[512];
  float px[PTS], py[PTS], pz[PTS], dist[PTS];
#pragma unroll
  for (int p = 0; p < PTS; ++p) {
    int pt = tid + p * 256;
    if (pt < N) { px[p] = xb[pt * 3]; py[p] = xb[pt * 3 + 1]; pz[p] = xb[pt * 3 + 2]; }
    dist[p] = 1e10f;
  }
  int far = 0;
  for (int t = 0; t < npoint; ++t) {
    if (tid == 0) { idx_out[(size_t)b * npoint + t] = far; hist[t] = far; }
    float cx = xb[far * 3], cy = xb[far * 3 + 1], cz = xb[far * 3 + 2];
    float best = -1.0f;
    int besti = N;
#pragma unroll
    for (int p = 0; p < PTS; ++p) {
      int pt = tid + p * 256;
      if (pt < N) {
        float dx = px[p] - cx, dy = py[p] - cy, dz = pz[p] - cz;
        float d = dx * dx + dy * dy + dz * dz;
        float nd = fminf(dist[p], d);
        dist[p] = nd;
        if (nd > best) { best = nd; besti = pt; }  // ascending pt: strict > keeps lowest idx
      }
    }
#pragma unroll
    for (int off = 32; off > 0; off >>= 1) {
      float ov = __shfl_down(best, off);
      int oi = __shfl_down(besti, off);
      if (ov > best || (ov == best && oi < besti)) { best = ov; besti = oi; }
    }
    int wv = tid >> 6;
    int par = (t & 1) * 4;
    if ((tid & 63) == 0) { rv[par + wv] = best; ri[par + wv] = besti; }
    __syncthreads();
    best = rv[par + 0]; besti = ri[par + 0];
#pragma unroll
    for (int w = 1; w < 4; ++w) {
      float ov = rv[par + w];
      int oi = ri[par + w];
      if (ov > best || (ov == best && oi < besti)) { best = ov; besti = oi; }
    }
    far = besti;
  }
  __syncthreads();
  for (int s = tid; s < npoint; s += 256) {
    int idp = hist[s];
    xyz_out[((size_t)b * npoint + s) * 3 + 0] = xb[idp * 3 + 0];
    xyz_out[((size_t)b * npoint + s) * 3 + 1] = xb[idp * 3 + 1];
    xyz_out[((size_t)b * npoint + s) * 3 + 2] = xb[idp * 3 + 2];
  }
}

// ---------------------------------------------------------------------------
// Generic feature gather: dst[b][s][c] = src[b][idx[b][s]][c]
// ---------------------------------------------------------------------------
__global__ __launch_bounds__(256) void gather_kernel(const float* __restrict__ src,
                                                     const int* __restrict__ idx,
                                                     float* __restrict__ dst, int N, int S,
                                                     int C, int total) {
  int gid = blockIdx.x * 256 + threadIdx.x;
  if (gid >= total) return;
  int c = gid % C;
  int s = (gid / C) % S;
  int b = gid / (C * S);
  dst[gid] = src[((size_t)b * N + idx[b * S + s]) * C + c];
}

// ---------------------------------------------------------------------------
// LAE gather-weight: per point, softmax attention over 16 neighbor coord
// offsets, then alpha-weighted feature sum (GEMM applied afterwards since
// softmax weights sum to 1). One 64-lane wave per point; coalesced over Cin.
// ---------------------------------------------------------------------------
__global__ __launch_bounds__(64) void gatherweight_kernel(const float* __restrict__ xyz,
                                                          const float* __restrict__ fea,
                                                          const int* __restrict__ knn,
                                                          const float* __restrict__ A,
                                                          float* __restrict__ wf, int N,
                                                          int Cin) {
  int bn = blockIdx.x;
  int b = bn / N, n = bn - b * N;
  int lane = threadIdx.x;
  const float* xb = xyz + (size_t)b * N * 3;
  const int* kn = knn + (size_t)bn * 16;
  float ax = A[0], ay = A[1], az = A[2];
  float qx = xb[n * 3 + 0], qy = xb[n * 3 + 1], qz = xb[n * 3 + 2];
  int id[16];
  float al[16];
#pragma unroll
  for (int k = 0; k < 16; ++k) id[k] = kn[k];
  float mx = -3.0e38f;
#pragma unroll
  for (int k = 0; k < 16; ++k) {
    float gx = xb[id[k] * 3 + 0] - qx;
    float gy = xb[id[k] * 3 + 1] - qy;
    float gz = xb[id[k] * 3 + 2] - qz;
    float s = gx * ax + gy * ay + gz * az;
    al[k] = s;
    mx = fmaxf(mx, s);
  }
  float sum = 0.0f;
#pragma unroll
  for (int k = 0; k < 16; ++k) { al[k] = expf(al[k] - mx); sum += al[k]; }
#pragma unroll
  for (int k = 0; k < 16; ++k) al[k] = al[k] / sum;
  const float* fb = fea + (size_t)b * N * Cin;
  float* wo = wf + (size_t)bn * Cin;
  for (int c = lane; c < Cin; c += 64) {
    float acc = 0.0f;
#pragma unroll
    for (int k = 0; k < 16; ++k) acc += al[k] * fb[(size_t)id[k] * Cin + c];
    wo[c] = acc;
  }
}

// ---------------------------------------------------------------------------
// Tiled fp32 GEMM: out[r][co] = act(sum_k A[r][k]*W[k][co] + bias).
// Block 256 threads = 64 couts x 4 row-groups; tile 32 rows x 64 couts;
// 8 rows per thread. A-tile staged in LDS transposed ([k][row], stride 36).
// Cout must be a multiple of 64, rows a multiple of 32 (true for all uses).
// ---------------------------------------------------------------------------
__global__ __launch_bounds__(256) void gemm_kernel(const float* __restrict__ Amat,
                                                   const float* __restrict__ W,
                                                   const float* __restrict__ bias,
                                                   float* __restrict__ out, int K, int Cout,
                                                   int relu) {
  __shared__ float lds_a[32 * 36];
  int co = blockIdx.x * 64 + (threadIdx.x & 63);
  int rg = threadIdx.x >> 6;
  int r0 = blockIdx.y * 32;
  float acc[8];
#pragma unroll
  for (int j = 0; j < 8; ++j) acc[j] = 0.0f;
  for (int k0 = 0; k0 < K; k0 += 32) {
    int row = threadIdx.x >> 3;
    int kq = (threadIdx.x & 7) * 4;
    int gk = k0 + kq;
    const float* ap = Amat + (size_t)(r0 + row) * K + gk;
    float a0 = 0.0f, a1 = 0.0f, a2 = 0.0f, a3 = 0.0f;
    if (gk + 3 < K) {
      float4 tv = *(const float4*)ap;
      a0 = tv.x; a1 = tv.y; a2 = tv.z; a3 = tv.w;
    } else {
      if (gk + 0 < K) a0 = ap[0];
      if (gk + 1 < K) a1 = ap[1];
      if (gk + 2 < K) a2 = ap[2];
    }
    __syncthreads();
    lds_a[(kq + 0) * 36 + row] = a0;
    lds_a[(kq + 1) * 36 + row] = a1;
    lds_a[(kq + 2) * 36 + row] = a2;
    lds_a[(kq + 3) * 36 + row] = a3;
    __syncthreads();
    int kmax = K - k0;
    if (kmax > 32) kmax = 32;
    if (kmax == 32) {
#pragma unroll
      for (int kk = 0; kk < 32; ++kk) {
        float w = W[(size_t)(k0 + kk) * Cout + co];
        const float* ar = &lds_a[kk * 36 + rg * 8];
        float4 x0 = *(const float4*)ar;
        float4 x1 = *(const float4*)(ar + 4);
        acc[0] += x0.x * w; acc[1] += x0.y * w; acc[2] += x0.z * w; acc[3] += x0.w * w;
        acc[4] += x1.x * w; acc[5] += x1.y * w; acc[6] += x1.z * w; acc[7] += x1.w * w;
      }
    } else {
      for (int kk = 0; kk < kmax; ++kk) {
        float w = W[(size_t)(k0 + kk) * Cout + co];
        const float* ar = &lds_a[kk * 36 + rg * 8];
        float4 x0 = *(const float4*)ar;
        float4 x1 = *(const float4*)(ar + 4);
        acc[0] += x0.x * w; acc[1] += x0.y * w; acc[2] += x0.z * w; acc[3] += x0.w * w;
        acc[4] += x1.x * w; acc[5] += x1.y * w; acc[6] += x1.z * w; acc[7] += x1.w * w;
      }
    }
  }
  float bb = bias ? bias[co] : 0.0f;
#pragma unroll
  for (int j = 0; j < 8; ++j) {
    float vv = acc[j] + bb;
    if (relu) vv = fmaxf(vv, 0.0f);
    out[(size_t)(r0 + rg * 8 + j) * Cout + co] = vv;
  }
}

// ---------------------------------------------------------------------------
// Self-attention mix: out[n] = softmax(q[n]·k^T) @ v + fea[n]. Block per (b,n).
// ---------------------------------------------------------------------------
__global__ __launch_bounds__(128) void attn_kernel(const float* __restrict__ q,
                                                   const float* __restrict__ k,
                                                   const float* __restrict__ v,
                                                   const float* __restrict__ fea,
                                                   float* __restrict__ out, int N, int C) {
  __shared__ float sa[128];
  __shared__ float sb[128];
  int b = blockIdx.y, n = blockIdx.x, t = threadIdx.x;
  const float* qn = q + ((size_t)b * N + n) * C;
  if (t < N) {
    const float* km = k + ((size_t)b * N + t) * C;
    float acc = 0.0f;
    for (int c = 0; c < C; ++c) acc += qn[c] * km[c];
    sa[t] = acc;
  }
  __syncthreads();
  float mx = -3.0e38f;
  for (int i = 0; i < N; ++i) mx = fmaxf(mx, sa[i]);
  if (t < N) sb[t] = expf(sa[t] - mx);
  __syncthreads();
  float sum = 0.0f;
  for (int i = 0; i < N; ++i) sum += sb[i];
  size_t rowo = ((size_t)b * N + n) * C;
  for (int c = t; c < C; c += 128) {
    float acc = 0.0f;
    for (int m = 0; m < N; ++m) acc += sb[m] * v[((size_t)b * N + m) * C + c];
    out[rowo + c] = acc / sum + fea[rowo + c];
  }
}

// ---------------------------------------------------------------------------
// 3-NN inverse-distance weights (pdist2 form, stable top-3).
// ---------------------------------------------------------------------------
__global__ __launch_bounds__(256) void interp3_kernel(const float* __restrict__ xd,
                                                      const float* __restrict__ xs, int Nd,
                                                      int Ns, int* __restrict__ idx3,
                                                      float* __restrict__ w3, int total) {
#pragma clang fp contract(off)
  int gid = blockIdx.x * 256 + threadIdx.x;
  if (gid >= total) return;
  int b = gid / Nd;
  const float* xb = xs + (size_t)b * Ns * 3;
  float qx = xd[gid * 3 + 0], qy = xd[gid * 3 + 1], qz = xd[gid * 3 + 2];
  float qq = qx * qx + qy * qy + qz * qz;
  float v0 = 3.0e38f, v1 = 3.0e38f, v2 = 3.0e38f;
  int i0 = 0, i1 = 0, i2 = 0;
  for (int m = 0; m < Ns; ++m) {
    float cx = xb[m * 3 + 0], cy = xb[m * 3 + 1], cz = xb[m * 3 + 2];
    float cc = cx * cx + cy * cy + cz * cz;
    float ab = qx * cx + qy * cy + qz * cz;
    float d2 = fmaxf(qq + cc - 2.0f * ab, 0.0f);
    if (d2 < v2) {
      if (d2 < v0) { v2 = v1; i2 = i1; v1 = v0; i1 = i0; v0 = d2; i0 = m; }
      else if (d2 < v1) { v2 = v1; i2 = i1; v1 = d2; i1 = m; }
      else { v2 = d2; i2 = m; }
    }
  }
  float w0 = 1.0f / fmaxf(v0, 1e-10f);
  float w1 = 1.0f / fmaxf(v1, 1e-10f);
  float w2 = 1.0f / fmaxf(v2, 1e-10f);
  float s = w0 + w1 + w2;
  idx3[gid * 3 + 0] = i0; idx3[gid * 3 + 1] = i1; idx3[gid * 3 + 2] = i2;
  w3[gid * 3 + 0] = w0 / s; w3[gid * 3 + 1] = w1 / s; w3[gid * 3 + 2] = w2 / s;
}

// ---------------------------------------------------------------------------
// Skip-concat + 3NN interpolation: out = [fea_d | sum_j w_j fea_s[idx_j]]
// ---------------------------------------------------------------------------
__global__ __launch_bounds__(256) void concat_kernel(const float* __restrict__ fd,
                                                     const float* __restrict__ fs,
                                                     const int* __restrict__ idx3,
                                                     const float* __restrict__ w3,
                                                     float* __restrict__ out, int Nd, int Ns,
                                                     int Cd, int Cs, int total) {
  int gid = blockIdx.x * 256 + threadIdx.x;
  if (gid >= total) return;
  int C = Cd + Cs;
  int c = gid % C;
  int bn = gid / C;
  int b = bn / Nd;
  if (c < Cd) {
    out[gid] = fd[(size_t)bn * Cd + c];
  } else {
    int cc = c - Cd;
    const int* ii = idx3 + (size_t)bn * 3;
    const float* ww = w3 + (size_t)bn * 3;
    const float* fb = fs + (size_t)b * Ns * Cs;
    out[gid] = ww[0] * fb[(size_t)ii[0] * Cs + cc] + ww[1] * fb[(size_t)ii[1] * Cs + cc] +
               ww[2] * fb[(size_t)ii[2] * Cs + cc];
  }
}

// ---------------------------------------------------------------------------
// Final classifier, writes transposed (B, 13, N).
// ---------------------------------------------------------------------------
__global__ __launch_bounds__(256) void final_kernel(const float* __restrict__ fea,
                                                    const float* __restrict__ Wf,
                                                    const float* __restrict__ bfv,
                                                    float* __restrict__ out, int N) {
  int n = blockIdx.x * 256 + threadIdx.x;
  int c = blockIdx.y;
  int b = blockIdx.z;
  const float* fr = fea + ((size_t)b * N + n) * 128;
  float acc = 0.0f;
#pragma unroll 8
  for (int k = 0; k < 128; ++k) acc += fr[k] * Wf[k * 13 + c];
  out[((size_t)b * 13 + c) * N + n] = acc + bfv[c];
}

// ---------------------------------------------------------------------------
extern "C" void kernel_launch(void* const* d_in, const int* in_sizes, int n_in,
                              void* d_out, int out_size, void* d_ws, size_t ws_size,
                              hipStream_t stream) {
  (void)in_sizes; (void)n_in; (void)out_size; (void)ws_size;
  const float* xyz = (const float*)d_in[0];
  const float* W[7]; const float* bi[7]; const float* A[7];
  for (int i = 0; i < 7; ++i) {
    W[i] = (const float*)d_in[1 + 3 * i];
    bi[i] = (const float*)d_in[2 + 3 * i];
    A[i] = (const float*)d_in[3 + 3 * i];
  }
  const float* Wq1 = (const float*)d_in[22];
  const float* Wk1 = (const float*)d_in[23];
  const float* Wv1 = (const float*)d_in[24];
  const float* Wq2 = (const float*)d_in[25];
  const float* Wk2 = (const float*)d_in[26];
  const float* Wv2 = (const float*)d_in[27];
  const float* Wq3 = (const float*)d_in[28];
  const float* Wk3 = (const float*)d_in[29];
  const float* Wv3 = (const float*)d_in[30];
  const float* Wf = (const float*)d_in[31];
  const float* bf = (const float*)d_in[32];
  float* out = (float*)d_out;

  const int B = NBATCH, N0 = 4096, N1 = 512, N2 = 128, N3 = 64;
  char* base = (char*)d_ws;
  size_t off = 0;
  auto alloc = [&](size_t bytes) -> void* {
    void* p = base + off;
    off += (bytes + 255) & ~(size_t)255;
    return p;
  };
  int* idxK0 = (int*)alloc((size_t)B * N0 * 16 * 4);
  int* idxK1 = (int*)alloc((size_t)B * N1 * 16 * 4);
  int* idxK2 = (int*)alloc((size_t)B * N2 * 16 * 4);
  int* idxK3 = (int*)alloc((size_t)B * N3 * 16 * 4);
  int* idx1 = (int*)alloc((size_t)B * N1 * 4);
  int* idx2 = (int*)alloc((size_t)B * N2 * 4);
  int* idx3 = (int*)alloc((size_t)B * N3 * 4);
  float* xyz1 = (float*)alloc((size_t)B * N1 * 3 * 4);
  float* xyz2 = (float*)alloc((size_t)B * N2 * 3 * 4);
  float* xyz3 = (float*)alloc((size_t)B * N3 * 3 * 4);
  float* fea0 = (float*)alloc((size_t)B * N0 * 64 * 4);
  float* fea1in = (float*)alloc((size_t)B * N1 * 64 * 4);
  float* fea1 = (float*)alloc((size_t)B * N1 * 128 * 4);
  float* fea1b = (float*)alloc((size_t)B * N1 * 256 * 4);
  float* fea2in = (float*)alloc((size_t)B * N2 * 128 * 4);
  float* fea2a = (float*)alloc((size_t)B * N2 * 256 * 4);
  float* fea2b = (float*)alloc((size_t)B * N2 * 256 * 4);
  float* fea2c = (float*)alloc((size_t)B * N2 * 256 * 4);
  float* fea2d = (float*)alloc((size_t)B * N2 * 256 * 4);
  float* fea3in = (float*)alloc((size_t)B * N3 * 256 * 4);
  float* fea3a = (float*)alloc((size_t)B * N3 * 512 * 4);
  float* fea3b = (float*)alloc((size_t)B * N3 * 512 * 4);
  float* qb = (float*)alloc((size_t)B * 32768 * 4);  // max(N2*256, N3*512) per batch
  float* kb = (float*)alloc((size_t)B * 32768 * 4);
  float* vb = (float*)alloc((size_t)B * 32768 * 4);
  int* idxI2 = (int*)alloc((size_t)B * N2 * 3 * 4);
  float* wI2 = (float*)alloc((size_t)B * N2 * 3 * 4);
  int* idxI1 = (int*)alloc((size_t)B * N1 * 3 * 4);
  float* wI1 = (float*)alloc((size_t)B * N1 * 3 * 4);
  int* idxI0 = (int*)alloc((size_t)B * N0 * 3 * 4);
  float* wI0 = (float*)alloc((size_t)B * N0 * 3 * 4);
  float* cat2 = (float*)alloc((size_t)B * N2 * 768 * 4);
  float* cat1 = (float*)alloc((size_t)B * N1 * 384 * 4);
  float* cat0 = (float*)alloc((size_t)B * N0 * 320 * 4);
  float* feaL = (float*)alloc((size_t)B * N0 * 128 * 4);
  float* wfb = (float*)alloc((size_t)B * N0 * 320 * 4);

  // radii squared computed in double then cast, matching XLA's constant fold
  float r2_0 = (float)(0.06 * 0.06);
  float r2_1 = (float)(0.12 * 0.12);
  float r2_2 = (float)(0.3 * 0.3);
  float r2_3 = (float)(0.5 * 0.5);

  // ---- Layer 0: lae_conv(xyz, xyz, W0) radius 0.06 -> fea0 (B,4096,64)
  knn16_kernel<<<B * N0 / 256, 256, 0, stream>>>(xyz, N0, r2_0, idxK0, B * N0);
  gatherweight_kernel<<<B * N0, 64, 0, stream>>>(xyz, xyz, idxK0, A[0], wfb, N0, 3);
  gemm_kernel<<<dim3(1, B * N0 / 32), 256, 0, stream>>>(wfb, W[0], bi[0], fea0, 3, 64, 1);

  // ---- FPS 4096 -> 512
  fps_kernel<16><<<B, 256, 0, stream>>>(xyz, N0, N1, idx1, xyz1);
  gather_kernel<<<B * N1 * 64 / 256, 256, 0, stream>>>(fea0, idx1, fea1in, N0, N1, 64,
                                                       B * N1 * 64);
  // ---- Layer 1: radius 0.12 -> fea1 (B,512,128)
  knn16_kernel<<<B * N1 / 256, 256, 0, stream>>>(xyz1, N1, r2_1, idxK1, B * N1);
  gatherweight_kernel<<<B * N1, 64, 0, stream>>>(xyz1, fea1in, idxK1, A[1], wfb, N1, 64);
  gemm_kernel<<<dim3(2, B * N1 / 32), 256, 0, stream>>>(wfb, W[1], bi[1], fea1, 64, 128, 1);

  // ---- FPS 512 -> 128
  fps_kernel<2><<<B, 256, 0, stream>>>(xyz1, N1, N2, idx2, xyz2);
  gather_kernel<<<B * N2 * 128 / 256, 256, 0, stream>>>(fea1, idx2, fea2in, N1, N2, 128,
                                                        B * N2 * 128);
  // ---- Layer 2: radius 0.3 -> fea2a (B,128,256), then self-attn 1
  knn16_kernel<<<B * N2 / 256, 256, 0, stream>>>(xyz2, N2, r2_2, idxK2, B * N2);
  gatherweight_kernel<<<B * N2, 64, 0, stream>>>(xyz2, fea2in, idxK2, A[2], wfb, N2, 128);
  gemm_kernel<<<dim3(4, B * N2 / 32), 256, 0, stream>>>(wfb, W[2], bi[2], fea2a, 128, 256, 1);
  gemm_kernel<<<dim3(4, B * N2 / 32), 256, 0, stream>>>(fea2a, Wq1, nullptr, qb, 256, 256, 0);
  gemm_kernel<<<dim3(4, B * N2 / 32), 256, 0, stream>>>(fea2a, Wk1, nullptr, kb, 256, 256, 0);
  gemm_kernel<<<dim3(4, B * N2 / 32), 256, 0, stream>>>(fea2a, Wv1, nullptr, vb, 256, 256, 0);
  attn_kernel<<<dim3(N2, B), 128, 0, stream>>>(qb, kb, vb, fea2a, fea2b, N2, 256);

  // ---- FPS 128 -> 64
  fps_kernel<1><<<B, 256, 0, stream>>>(xyz2, N2, N3, idx3, xyz3);
  gather_kernel<<<B * N3 * 256 / 256, 256, 0, stream>>>(fea2b, idx3, fea3in, N2, N3, 256,
                                                        B * N3 * 256);
  // ---- Layer 3: radius 0.5 -> fea3a (B,64,512), then self-attn 2
  knn16_kernel<<<B * N3 / 256, 256, 0, stream>>>(xyz3, N3, r2_3, idxK3, B * N3);
  gatherweight_kernel<<<B * N3, 64, 0, stream>>>(xyz3, fea3in, idxK3, A[3], wfb, N3, 256);
  gemm_kernel<<<dim3(8, B * N3 / 32), 256, 0, stream>>>(wfb, W[3], bi[3], fea3a, 256, 512, 1);
  gemm_kernel<<<dim3(8, B * N3 / 32), 256, 0, stream>>>(fea3a, Wq2, nullptr, qb, 512, 512, 0);
  gemm_kernel<<<dim3(8, B * N3 / 32), 256, 0, stream>>>(fea3a, Wk2, nullptr, kb, 512, 512, 0);
  gemm_kernel<<<dim3(8, B * N3 / 32), 256, 0, stream>>>(fea3a, Wv2, nullptr, vb, 512, 512, 0);
  attn_kernel<<<dim3(N3, B), 128, 0, stream>>>(qb, kb, vb, fea3a, fea3b, N3, 512);

  // ---- FP-interp xyz2 <- xyz3, cat2 (B,128,768); Layer 4 -> fea2c; attn 3
  interp3_kernel<<<B * N2 / 256, 256, 0, stream>>>(xyz2, xyz3, N2, N3, idxI2, wI2, B * N2);
  concat_kernel<<<B * N2 * 768 / 256, 256, 0, stream>>>(fea2b, fea3b, idxI2, wI2, cat2, N2,
                                                        N3, 256, 512, B * N2 * 768);
  gatherweight_kernel<<<B * N2, 64, 0, stream>>>(xyz2, cat2, idxK2, A[4], wfb, N2, 768);
  gemm_kernel<<<dim3(4, B * N2 / 32), 256, 0, stream>>>(wfb, W[4], bi[4], fea2c, 768, 256, 1);
  gemm_kernel<<<dim3(4, B * N2 / 32), 256, 0, stream>>>(fea2c, Wq3, nullptr, qb, 256, 256, 0);
  gemm_kernel<<<dim3(4, B * N2 / 32), 256, 0, stream>>>(fea2c, Wk3, nullptr, kb, 256, 256, 0);
  gemm_kernel<<<dim3(4, B * N2 / 32), 256, 0, stream>>>(fea2c, Wv3, nullptr, vb, 256, 256, 0);
  attn_kernel<<<dim3(N2, B), 128, 0, stream>>>(qb, kb, vb, fea2c, fea2d, N2, 256);

  // ---- FP-interp xyz1 <- xyz2, cat1 (B,512,384); Layer 5 -> fea1b
  interp3_kernel<<<B * N1 / 256, 256, 0, stream>>>(xyz1, xyz2, N1, N2, idxI1, wI1, B * N1);
  concat_kernel<<<B * N1 * 384 / 256, 256, 0, stream>>>(fea1, fea2d, idxI1, wI1, cat1, N1, N2,
                                                        128, 256, B * N1 * 384);
  gatherweight_kernel<<<B * N1, 64, 0, stream>>>(xyz1, cat1, idxK1, A[5], wfb, N1, 384);
  gemm_kernel<<<dim3(4, B * N1 / 32), 256, 0, stream>>>(wfb, W[5], bi[5], fea1b, 384, 256, 1);

  // ---- FP-interp xyz <- xyz1, cat0 (B,4096,320); Layer 6 -> feaL (B,4096,128)
  interp3_kernel<<<B * N0 / 256, 256, 0, stream>>>(xyz, xyz1, N0, N1, idxI0, wI0, B * N0);
  concat_kernel<<<B * N0 * 320 / 256, 256, 0, stream>>>(fea0, fea1b, idxI0, wI0, cat0, N0, N1,
                                                        64, 256, B * N0 * 320);
  gatherweight_kernel<<<B * N0, 64, 0, stream>>>(xyz, cat0, idxK0, A[6], wfb, N0, 320);
  gemm_kernel<<<dim3(2, B * N0 / 32), 256, 0, stream>>>(wfb, W[6], bi[6], feaL, 320, 128, 1);

  // ---- Final classifier -> out (B,13,4096)
  final_kernel<<<dim3(N0 / 256, 13, B), 256, 0, stream>>>(feaL, Wf, bf, out, N0);
}

// Round 2
// 2039.128 us; speedup vs baseline: 1.7839x; 1.7839x over previous
//
#include <hip/hip_runtime.h>
#include <math.h>

#define NBATCH 4

// branchless ascending compare-swap on u64 keys
#define CSWAP(a, b)                                          \
  {                                                          \
    unsigned long long _mn = (b < a) ? b : a;                \
    unsigned long long _mx = (b < a) ? a : b;                \
    a = _mn;                                                 \
    b = _mx;                                                 \
  }

// ---------------------------------------------------------------------------
// kNN-16, one wave per query. Key = (d2_bits << 32) | idx gives exact
// (d2, idx) lexicographic order (d2 >= 0 so fp bits are order-preserving),
// matching jax.lax.top_k's stable tie-break. Per-lane top-16 in named u64
// registers (no arrays -> no scratch), then 16-round pop-merge via LDS +
// wave-min butterfly. Output ascending = reference order.
// ---------------------------------------------------------------------------
__global__ __launch_bounds__(64) void knn16_wave(const float* __restrict__ xyz, int N,
                                                 float r2, int* __restrict__ idx_out) {
#pragma clang fp contract(off)
  int bn = blockIdx.x;
  int b = bn / N, n = bn - b * N;
  int lane = threadIdx.x;
  const float* xb = xyz + (size_t)b * N * 3;
  float qx = xb[n * 3 + 0], qy = xb[n * 3 + 1], qz = xb[n * 3 + 2];
  float qq = qx * qx + qy * qy + qz * qz;
  // sentinel: d2 bits = +inf, idx field = lane (keeps keys unique)
  const unsigned long long SENT = ((unsigned long long)0x7F800000u << 32) | (unsigned)lane;
  unsigned long long k0 = SENT, k1 = SENT, k2 = SENT, k3 = SENT, k4 = SENT, k5 = SENT,
                     k6 = SENT, k7 = SENT, k8 = SENT, k9 = SENT, k10 = SENT, k11 = SENT,
                     k12 = SENT, k13 = SENT, k14 = SENT, k15 = SENT;
  int rounds = N >> 6;
  for (int j = 0; j < rounds; ++j) {
    int m = j * 64 + lane;
    float cx = xb[m * 3 + 0], cy = xb[m * 3 + 1], cz = xb[m * 3 + 2];
    float cc = cx * cx + cy * cy + cz * cz;
    float ab = qx * cx + qy * cy + qz * cz;
    float d2 = fmaxf(qq + cc - 2.0f * ab, 0.0f);
    unsigned long long key = ((unsigned long long)__float_as_uint(d2) << 32) | (unsigned)m;
    if (key < k15) {
      k15 = key;
      CSWAP(k14, k15); CSWAP(k13, k14); CSWAP(k12, k13); CSWAP(k11, k12);
      CSWAP(k10, k11); CSWAP(k9, k10);  CSWAP(k8, k9);   CSWAP(k7, k8);
      CSWAP(k6, k7);   CSWAP(k5, k6);   CSWAP(k4, k5);   CSWAP(k3, k4);
      CSWAP(k2, k3);   CSWAP(k1, k2);   CSWAP(k0, k1);
    }
  }
  __shared__ unsigned long long lists[16 * 64];
  lists[0 * 64 + lane] = k0;   lists[1 * 64 + lane] = k1;
  lists[2 * 64 + lane] = k2;   lists[3 * 64 + lane] = k3;
  lists[4 * 64 + lane] = k4;   lists[5 * 64 + lane] = k5;
  lists[6 * 64 + lane] = k6;   lists[7 * 64 + lane] = k7;
  lists[8 * 64 + lane] = k8;   lists[9 * 64 + lane] = k9;
  lists[10 * 64 + lane] = k10; lists[11 * 64 + lane] = k11;
  lists[12 * 64 + lane] = k12; lists[13 * 64 + lane] = k13;
  lists[14 * 64 + lane] = k14; lists[15 * 64 + lane] = k15;
  __syncthreads();
  int head = 0;
  unsigned long long outk = 0;
  for (int r = 0; r < 16; ++r) {
    unsigned long long h = lists[head * 64 + lane];
    unsigned long long mn = h;
#pragma unroll
    for (int mask = 32; mask; mask >>= 1) {
      unsigned long long o = __shfl_xor(mn, mask);
      if (o < mn) mn = o;
    }
    if (h == mn) head++;   // keys unique -> exactly one winner advances
    if (lane == r) outk = mn;
  }
  if (lane < 16) {
    float d2 = __uint_as_float((unsigned)(outk >> 32));
    int m = (int)(outk & 0xFFFFFFFFu);
    idx_out[(size_t)bn * 16 + lane] = (d2 <= r2) ? m : n;
  }
}

// ---------------------------------------------------------------------------
// Furthest point sampling. One block per batch, NT threads, PTS points per
// thread (N == NT*PTS exactly for all uses). dist in registers; argmax tie ->
// lowest point index (matches jnp.argmax). Parity double-buffer for the
// cross-wave reduce -> one barrier per iteration.
// ---------------------------------------------------------------------------
template <int NT, int PTS>
__global__ __launch_bounds__(NT) void fps_kernel(const float* __restrict__ xyz, int N,
                                                 int npoint, int* __restrict__ idx_out,
                                                 float* __restrict__ xyz_out) {
#pragma clang fp contract(off)
  constexpr int NW = NT / 64;
  int b = blockIdx.x, tid = threadIdx.x;
  const float* xb = xyz + (size_t)b * N * 3;
  __shared__ float rv[2][NW];
  __shared__ int ri[2][NW];
  __shared__ int hist[512];
  float px[PTS], py[PTS], pz[PTS], dist[PTS];
#pragma unroll
  for (int p = 0; p < PTS; ++p) {
    int pt = tid + p * NT;
    px[p] = xb[pt * 3 + 0];
    py[p] = xb[pt * 3 + 1];
    pz[p] = xb[pt * 3 + 2];
    dist[p] = 1e10f;
  }
  int far = 0;
  for (int t = 0; t < npoint; ++t) {
    if (tid == 0) hist[t] = far;
    float cx = xb[far * 3 + 0], cy = xb[far * 3 + 1], cz = xb[far * 3 + 2];
    float best = -1.0f;
    int besti = N;
#pragma unroll
    for (int p = 0; p < PTS; ++p) {
      int pt = tid + p * NT;
      float dx = px[p] - cx, dy = py[p] - cy, dz = pz[p] - cz;
      float d = dx * dx + dy * dy + dz * dz;
      float nd = fminf(dist[p], d);
      dist[p] = nd;
      if (nd > best) { best = nd; besti = pt; }  // ascending pt: strict > keeps lowest idx
    }
#pragma unroll
    for (int off = 32; off; off >>= 1) {
      float ov = __shfl_down(best, off);
      int oi = __shfl_down(besti, off);
      if (ov > best || (ov == best && oi < besti)) { best = ov; besti = oi; }
    }
    int par = t & 1;
    if ((tid & 63) == 0) { rv[par][tid >> 6] = best; ri[par][tid >> 6] = besti; }
    __syncthreads();
    best = rv[par][0];
    besti = ri[par][0];
#pragma unroll
    for (int w = 1; w < NW; ++w) {
      float ov = rv[par][w];
      int oi = ri[par][w];
      if (ov > best || (ov == best && oi < besti)) { best = ov; besti = oi; }
    }
    far = besti;
  }
  __syncthreads();
  for (int s = tid; s < npoint; s += NT) {
    int idp = hist[s];
    idx_out[(size_t)b * npoint + s] = idp;
    xyz_out[((size_t)b * npoint + s) * 3 + 0] = xb[idp * 3 + 0];
    xyz_out[((size_t)b * npoint + s) * 3 + 1] = xb[idp * 3 + 1];
    xyz_out[((size_t)b * npoint + s) * 3 + 2] = xb[idp * 3 + 2];
  }
}

// ---------------------------------------------------------------------------
// Generic feature gather: dst[b][s][c] = src[b][idx[b][s]][c]
// ---------------------------------------------------------------------------
__global__ __launch_bounds__(256) void gather_kernel(const float* __restrict__ src,
                                                     const int* __restrict__ idx,
                                                     float* __restrict__ dst, int N, int S,
                                                     int C, int total) {
  int gid = blockIdx.x * 256 + threadIdx.x;
  if (gid >= total) return;
  int c = gid % C;
  int s = (gid / C) % S;
  int b = gid / (C * S);
  dst[gid] = src[((size_t)b * N + idx[b * S + s]) * C + c];
}

// ---------------------------------------------------------------------------
// LAE gather-weight: softmax attention over 16 neighbor coord offsets, then
// alpha-weighted feature sum (GEMM applied afterwards; softmax sums to 1).
// One wave per point; coalesced over Cin.
// ---------------------------------------------------------------------------
__global__ __launch_bounds__(64) void gatherweight_kernel(const float* __restrict__ xyz,
                                                          const float* __restrict__ fea,
                                                          const int* __restrict__ knn,
                                                          const float* __restrict__ A,
                                                          float* __restrict__ wf, int N,
                                                          int Cin) {
  int bn = blockIdx.x;
  int b = bn / N, n = bn - b * N;
  int lane = threadIdx.x;
  const float* xb = xyz + (size_t)b * N * 3;
  const int* kn = knn + (size_t)bn * 16;
  float ax = A[0], ay = A[1], az = A[2];
  float qx = xb[n * 3 + 0], qy = xb[n * 3 + 1], qz = xb[n * 3 + 2];
  int id[16];
  float al[16];
#pragma unroll
  for (int k = 0; k < 16; ++k) id[k] = kn[k];
  float mx = -3.0e38f;
#pragma unroll
  for (int k = 0; k < 16; ++k) {
    float gx = xb[id[k] * 3 + 0] - qx;
    float gy = xb[id[k] * 3 + 1] - qy;
    float gz = xb[id[k] * 3 + 2] - qz;
    float s = gx * ax + gy * ay + gz * az;
    al[k] = s;
    mx = fmaxf(mx, s);
  }
  float sum = 0.0f;
#pragma unroll
  for (int k = 0; k < 16; ++k) { al[k] = expf(al[k] - mx); sum += al[k]; }
#pragma unroll
  for (int k = 0; k < 16; ++k) al[k] = al[k] / sum;
  const float* fb = fea + (size_t)b * N * Cin;
  float* wo = wf + (size_t)bn * Cin;
  for (int c = lane; c < Cin; c += 64) {
    float acc = 0.0f;
#pragma unroll
    for (int k = 0; k < 16; ++k) acc += al[k] * fb[(size_t)id[k] * Cin + c];
    wo[c] = acc;
  }
}

// ---------------------------------------------------------------------------
// Tiled fp32 GEMM: out[r][co] = act(sum_k A[r][k]*W[k][co] + bias).
// Block 256 = 64 couts x 4 row-groups; tile 32 rows x 64 couts.
// ---------------------------------------------------------------------------
__global__ __launch_bounds__(256) void gemm_kernel(const float* __restrict__ Amat,
                                                   const float* __restrict__ W,
                                                   const float* __restrict__ bias,
                                                   float* __restrict__ out, int K, int Cout,
                                                   int relu) {
  __shared__ float lds_a[32 * 36];
  int co = blockIdx.x * 64 + (threadIdx.x & 63);
  int rg = threadIdx.x >> 6;
  int r0 = blockIdx.y * 32;
  float acc[8];
#pragma unroll
  for (int j = 0; j < 8; ++j) acc[j] = 0.0f;
  for (int k0 = 0; k0 < K; k0 += 32) {
    int row = threadIdx.x >> 3;
    int kq = (threadIdx.x & 7) * 4;
    int gk = k0 + kq;
    const float* ap = Amat + (size_t)(r0 + row) * K + gk;
    float a0 = 0.0f, a1 = 0.0f, a2 = 0.0f, a3 = 0.0f;
    if (gk + 3 < K) {
      float4 tv = *(const float4*)ap;
      a0 = tv.x; a1 = tv.y; a2 = tv.z; a3 = tv.w;
    } else {
      if (gk + 0 < K) a0 = ap[0];
      if (gk + 1 < K) a1 = ap[1];
      if (gk + 2 < K) a2 = ap[2];
    }
    __syncthreads();
    lds_a[(kq + 0) * 36 + row] = a0;
    lds_a[(kq + 1) * 36 + row] = a1;
    lds_a[(kq + 2) * 36 + row] = a2;
    lds_a[(kq + 3) * 36 + row] = a3;
    __syncthreads();
    int kmax = K - k0;
    if (kmax > 32) kmax = 32;
    if (kmax == 32) {
#pragma unroll
      for (int kk = 0; kk < 32; ++kk) {
        float w = W[(size_t)(k0 + kk) * Cout + co];
        const float* ar = &lds_a[kk * 36 + rg * 8];
        float4 x0 = *(const float4*)ar;
        float4 x1 = *(const float4*)(ar + 4);
        acc[0] += x0.x * w; acc[1] += x0.y * w; acc[2] += x0.z * w; acc[3] += x0.w * w;
        acc[4] += x1.x * w; acc[5] += x1.y * w; acc[6] += x1.z * w; acc[7] += x1.w * w;
      }
    } else {
      for (int kk = 0; kk < kmax; ++kk) {
        float w = W[(size_t)(k0 + kk) * Cout + co];
        const float* ar = &lds_a[kk * 36 + rg * 8];
        float4 x0 = *(const float4*)ar;
        float4 x1 = *(const float4*)(ar + 4);
        acc[0] += x0.x * w; acc[1] += x0.y * w; acc[2] += x0.z * w; acc[3] += x0.w * w;
        acc[4] += x1.x * w; acc[5] += x1.y * w; acc[6] += x1.z * w; acc[7] += x1.w * w;
      }
    }
  }
  float bb = bias ? bias[co] : 0.0f;
#pragma unroll
  for (int j = 0; j < 8; ++j) {
    float vv = acc[j] + bb;
    if (relu) vv = fmaxf(vv, 0.0f);
    out[(size_t)(r0 + rg * 8 + j) * Cout + co] = vv;
  }
}

// ---------------------------------------------------------------------------
// Self-attention mix: out[n] = softmax(q[n]·k^T) @ v + fea[n]. Block per (b,n).
// ---------------------------------------------------------------------------
__global__ __launch_bounds__(128) void attn_kernel(const float* __restrict__ q,
                                                   const float* __restrict__ k,
                                                   const float* __restrict__ v,
                                                   const float* __restrict__ fea,
                                                   float* __restrict__ out, int N, int C) {
  __shared__ float sa[128];
  __shared__ float sb[128];
  int b = blockIdx.y, n = blockIdx.x, t = threadIdx.x;
  const float* qn = q + ((size_t)b * N + n) * C;
  if (t < N) {
    const float* km = k + ((size_t)b * N + t) * C;
    float acc = 0.0f;
    for (int c = 0; c < C; ++c) acc += qn[c] * km[c];
    sa[t] = acc;
  }
  __syncthreads();
  float mx = -3.0e38f;
  for (int i = 0; i < N; ++i) mx = fmaxf(mx, sa[i]);
  if (t < N) sb[t] = expf(sa[t] - mx);
  __syncthreads();
  float sum = 0.0f;
  for (int i = 0; i < N; ++i) sum += sb[i];
  size_t rowo = ((size_t)b * N + n) * C;
  for (int c = t; c < C; c += 128) {
    float acc = 0.0f;
    for (int m = 0; m < N; ++m) acc += sb[m] * v[((size_t)b * N + m) * C + c];
    out[rowo + c] = acc / sum + fea[rowo + c];
  }
}

// ---------------------------------------------------------------------------
// 3-NN inverse-distance weights (pdist2 form, stable top-3).
// ---------------------------------------------------------------------------
__global__ __launch_bounds__(256) void interp3_kernel(const float* __restrict__ xd,
                                                      const float* __restrict__ xs, int Nd,
                                                      int Ns, int* __restrict__ idx3,
                                                      float* __restrict__ w3, int total) {
#pragma clang fp contract(off)
  int gid = blockIdx.x * 256 + threadIdx.x;
  if (gid >= total) return;
  int b = gid / Nd;
  const float* xb = xs + (size_t)b * Ns * 3;
  float qx = xd[gid * 3 + 0], qy = xd[gid * 3 + 1], qz = xd[gid * 3 + 2];
  float qq = qx * qx + qy * qy + qz * qz;
  float v0 = 3.0e38f, v1 = 3.0e38f, v2 = 3.0e38f;
  int i0 = 0, i1 = 0, i2 = 0;
  for (int m = 0; m < Ns; ++m) {
    float cx = xb[m * 3 + 0], cy = xb[m * 3 + 1], cz = xb[m * 3 + 2];
    float cc = cx * cx + cy * cy + cz * cz;
    float ab = qx * cx + qy * cy + qz * cz;
    float d2 = fmaxf(qq + cc - 2.0f * ab, 0.0f);
    if (d2 < v2) {
      if (d2 < v0) { v2 = v1; i2 = i1; v1 = v0; i1 = i0; v0 = d2; i0 = m; }
      else if (d2 < v1) { v2 = v1; i2 = i1; v1 = d2; i1 = m; }
      else { v2 = d2; i2 = m; }
    }
  }
  float w0 = 1.0f / fmaxf(v0, 1e-10f);
  float w1 = 1.0f / fmaxf(v1, 1e-10f);
  float w2 = 1.0f / fmaxf(v2, 1e-10f);
  float s = w0 + w1 + w2;
  idx3[gid * 3 + 0] = i0; idx3[gid * 3 + 1] = i1; idx3[gid * 3 + 2] = i2;
  w3[gid * 3 + 0] = w0 / s; w3[gid * 3 + 1] = w1 / s; w3[gid * 3 + 2] = w2 / s;
}

// ---------------------------------------------------------------------------
// Skip-concat + 3NN interpolation: out = [fea_d | sum_j w_j fea_s[idx_j]]
// ---------------------------------------------------------------------------
__global__ __launch_bounds__(256) void concat_kernel(const float* __restrict__ fd,
                                                     const float* __restrict__ fs,
                                                     const int* __restrict__ idx3,
                                                     const float* __restrict__ w3,
                                                     float* __restrict__ out, int Nd, int Ns,
                                                     int Cd, int Cs, int total) {
  int gid = blockIdx.x * 256 + threadIdx.x;
  if (gid >= total) return;
  int C = Cd + Cs;
  int c = gid % C;
  int bn = gid / C;
  int b = bn / Nd;
  if (c < Cd) {
    out[gid] = fd[(size_t)bn * Cd + c];
  } else {
    int cc = c - Cd;
    const int* ii = idx3 + (size_t)bn * 3;
    const float* ww = w3 + (size_t)bn * 3;
    const float* fb = fs + (size_t)b * Ns * Cs;
    out[gid] = ww[0] * fb[(size_t)ii[0] * Cs + cc] + ww[1] * fb[(size_t)ii[1] * Cs + cc] +
               ww[2] * fb[(size_t)ii[2] * Cs + cc];
  }
}

// ---------------------------------------------------------------------------
// Final classifier, writes transposed (B, 13, N).
// ---------------------------------------------------------------------------
__global__ __launch_bounds__(256) void final_kernel(const float* __restrict__ fea,
                                                    const float* __restrict__ Wf,
                                                    const float* __restrict__ bfv,
                                                    float* __restrict__ out, int N) {
  int n = blockIdx.x * 256 + threadIdx.x;
  int c = blockIdx.y;
  int b = blockIdx.z;
  const float* fr = fea + ((size_t)b * N + n) * 128;
  float acc = 0.0f;
#pragma unroll 8
  for (int k = 0; k < 128; ++k) acc += fr[k] * Wf[k * 13 + c];
  out[((size_t)b * 13 + c) * N + n] = acc + bfv[c];
}

// ---------------------------------------------------------------------------
extern "C" void kernel_launch(void* const* d_in, const int* in_sizes, int n_in,
                              void* d_out, int out_size, void* d_ws, size_t ws_size,
                              hipStream_t stream) {
  (void)in_sizes; (void)n_in; (void)out_size; (void)ws_size;
  const float* xyz = (const float*)d_in[0];
  const float* W[7]; const float* bi[7]; const float* A[7];
  for (int i = 0; i < 7; ++i) {
    W[i] = (const float*)d_in[1 + 3 * i];
    bi[i] = (const float*)d_in[2 + 3 * i];
    A[i] = (const float*)d_in[3 + 3 * i];
  }
  const float* Wq1 = (const float*)d_in[22];
  const float* Wk1 = (const float*)d_in[23];
  const float* Wv1 = (const float*)d_in[24];
  const float* Wq2 = (const float*)d_in[25];
  const float* Wk2 = (const float*)d_in[26];
  const float* Wv2 = (const float*)d_in[27];
  const float* Wq3 = (const float*)d_in[28];
  const float* Wk3 = (const float*)d_in[29];
  const float* Wv3 = (const float*)d_in[30];
  const float* Wf = (const float*)d_in[31];
  const float* bf = (const float*)d_in[32];
  float* out = (float*)d_out;

  const int B = NBATCH, N0 = 4096, N1 = 512, N2 = 128, N3 = 64;
  char* base = (char*)d_ws;
  size_t off = 0;
  auto alloc = [&](size_t bytes) -> void* {
    void* p = base + off;
    off += (bytes + 255) & ~(size_t)255;
    return p;
  };
  int* idxK0 = (int*)alloc((size_t)B * N0 * 16 * 4);
  int* idxK1 = (int*)alloc((size_t)B * N1 * 16 * 4);
  int* idxK2 = (int*)alloc((size_t)B * N2 * 16 * 4);
  int* idxK3 = (int*)alloc((size_t)B * N3 * 16 * 4);
  int* idx1 = (int*)alloc((size_t)B * N1 * 4);
  int* idx2 = (int*)alloc((size_t)B * N2 * 4);
  int* idx3 = (int*)alloc((size_t)B * N3 * 4);
  float* xyz1 = (float*)alloc((size_t)B * N1 * 3 * 4);
  float* xyz2 = (float*)alloc((size_t)B * N2 * 3 * 4);
  float* xyz3 = (float*)alloc((size_t)B * N3 * 3 * 4);
  float* fea0 = (float*)alloc((size_t)B * N0 * 64 * 4);
  float* fea1in = (float*)alloc((size_t)B * N1 * 64 * 4);
  float* fea1 = (float*)alloc((size_t)B * N1 * 128 * 4);
  float* fea1b = (float*)alloc((size_t)B * N1 * 256 * 4);
  float* fea2in = (float*)alloc((size_t)B * N2 * 128 * 4);
  float* fea2a = (float*)alloc((size_t)B * N2 * 256 * 4);
  float* fea2b = (float*)alloc((size_t)B * N2 * 256 * 4);
  float* fea2c = (float*)alloc((size_t)B * N2 * 256 * 4);
  float* fea2d = (float*)alloc((size_t)B * N2 * 256 * 4);
  float* fea3in = (float*)alloc((size_t)B * N3 * 256 * 4);
  float* fea3a = (float*)alloc((size_t)B * N3 * 512 * 4);
  float* fea3b = (float*)alloc((size_t)B * N3 * 512 * 4);
  float* qb = (float*)alloc((size_t)B * 32768 * 4);
  float* kb = (float*)alloc((size_t)B * 32768 * 4);
  float* vb = (float*)alloc((size_t)B * 32768 * 4);
  int* idxI2 = (int*)alloc((size_t)B * N2 * 3 * 4);
  float* wI2 = (float*)alloc((size_t)B * N2 * 3 * 4);
  int* idxI1 = (int*)alloc((size_t)B * N1 * 3 * 4);
  float* wI1 = (float*)alloc((size_t)B * N1 * 3 * 4);
  int* idxI0 = (int*)alloc((size_t)B * N0 * 3 * 4);
  float* wI0 = (float*)alloc((size_t)B * N0 * 3 * 4);
  float* cat2 = (float*)alloc((size_t)B * N2 * 768 * 4);
  float* cat1 = (float*)alloc((size_t)B * N1 * 384 * 4);
  float* cat0 = (float*)alloc((size_t)B * N0 * 320 * 4);
  float* feaL = (float*)alloc((size_t)B * N0 * 128 * 4);
  float* wfb = (float*)alloc((size_t)B * N0 * 320 * 4);

  float r2_0 = (float)(0.06 * 0.06);
  float r2_1 = (float)(0.12 * 0.12);
  float r2_2 = (float)(0.3 * 0.3);
  float r2_3 = (float)(0.5 * 0.5);

  // ---- Layer 0: lae_conv(xyz, xyz, W0) radius 0.06 -> fea0 (B,4096,64)
  knn16_wave<<<B * N0, 64, 0, stream>>>(xyz, N0, r2_0, idxK0);
  gatherweight_kernel<<<B * N0, 64, 0, stream>>>(xyz, xyz, idxK0, A[0], wfb, N0, 3);
  gemm_kernel<<<dim3(1, B * N0 / 32), 256, 0, stream>>>(wfb, W[0], bi[0], fea0, 3, 64, 1);

  // ---- FPS 4096 -> 512
  fps_kernel<512, 8><<<B, 512, 0, stream>>>(xyz, N0, N1, idx1, xyz1);
  gather_kernel<<<B * N1 * 64 / 256, 256, 0, stream>>>(fea0, idx1, fea1in, N0, N1, 64,
                                                       B * N1 * 64);
  // ---- Layer 1: radius 0.12 -> fea1 (B,512,128)
  knn16_wave<<<B * N1, 64, 0, stream>>>(xyz1, N1, r2_1, idxK1);
  gatherweight_kernel<<<B * N1, 64, 0, stream>>>(xyz1, fea1in, idxK1, A[1], wfb, N1, 64);
  gemm_kernel<<<dim3(2, B * N1 / 32), 256, 0, stream>>>(wfb, W[1], bi[1], fea1, 64, 128, 1);

  // ---- FPS 512 -> 128
  fps_kernel<512, 1><<<B, 512, 0, stream>>>(xyz1, N1, N2, idx2, xyz2);
  gather_kernel<<<B * N2 * 128 / 256, 256, 0, stream>>>(fea1, idx2, fea2in, N1, N2, 128,
                                                        B * N2 * 128);
  // ---- Layer 2: radius 0.3 -> fea2a (B,128,256), then self-attn 1
  knn16_wave<<<B * N2, 64, 0, stream>>>(xyz2, N2, r2_2, idxK2);
  gatherweight_kernel<<<B * N2, 64, 0, stream>>>(xyz2, fea2in, idxK2, A[2], wfb, N2, 128);
  gemm_kernel<<<dim3(4, B * N2 / 32), 256, 0, stream>>>(wfb, W[2], bi[2], fea2a, 128, 256, 1);
  gemm_kernel<<<dim3(4, B * N2 / 32), 256, 0, stream>>>(fea2a, Wq1, nullptr, qb, 256, 256, 0);
  gemm_kernel<<<dim3(4, B * N2 / 32), 256, 0, stream>>>(fea2a, Wk1, nullptr, kb, 256, 256, 0);
  gemm_kernel<<<dim3(4, B * N2 / 32), 256, 0, stream>>>(fea2a, Wv1, nullptr, vb, 256, 256, 0);
  attn_kernel<<<dim3(N2, B), 128, 0, stream>>>(qb, kb, vb, fea2a, fea2b, N2, 256);

  // ---- FPS 128 -> 64
  fps_kernel<128, 1><<<B, 128, 0, stream>>>(xyz2, N2, N3, idx3, xyz3);
  gather_kernel<<<B * N3 * 256 / 256, 256, 0, stream>>>(fea2b, idx3, fea3in, N2, N3, 256,
                                                        B * N3 * 256);
  // ---- Layer 3: radius 0.5 -> fea3a (B,64,512), then self-attn 2
  knn16_wave<<<B * N3, 64, 0, stream>>>(xyz3, N3, r2_3, idxK3);
  gatherweight_kernel<<<B * N3, 64, 0, stream>>>(xyz3, fea3in, idxK3, A[3], wfb, N3, 256);
  gemm_kernel<<<dim3(8, B * N3 / 32), 256, 0, stream>>>(wfb, W[3], bi[3], fea3a, 256, 512, 1);
  gemm_kernel<<<dim3(8, B * N3 / 32), 256, 0, stream>>>(fea3a, Wq2, nullptr, qb, 512, 512, 0);
  gemm_kernel<<<dim3(8, B * N3 / 32), 256, 0, stream>>>(fea3a, Wk2, nullptr, kb, 512, 512, 0);
  gemm_kernel<<<dim3(8, B * N3 / 32), 256, 0, stream>>>(fea3a, Wv2, nullptr, vb, 512, 512, 0);
  attn_kernel<<<dim3(N3, B), 128, 0, stream>>>(qb, kb, vb, fea3a, fea3b, N3, 512);

  // ---- FP-interp xyz2 <- xyz3, cat2 (B,128,768); Layer 4 -> fea2c; attn 3
  interp3_kernel<<<B * N2 / 256, 256, 0, stream>>>(xyz2, xyz3, N2, N3, idxI2, wI2, B * N2);
  concat_kernel<<<B * N2 * 768 / 256, 256, 0, stream>>>(fea2b, fea3b, idxI2, wI2, cat2, N2,
                                                        N3, 256, 512, B * N2 * 768);
  gatherweight_kernel<<<B * N2, 64, 0, stream>>>(xyz2, cat2, idxK2, A[4], wfb, N2, 768);
  gemm_kernel<<<dim3(4, B * N2 / 32), 256, 0, stream>>>(wfb, W[4], bi[4], fea2c, 768, 256, 1);
  gemm_kernel<<<dim3(4, B * N2 / 32), 256, 0, stream>>>(fea2c, Wq3, nullptr, qb, 256, 256, 0);
  gemm_kernel<<<dim3(4, B * N2 / 32), 256, 0, stream>>>(fea2c, Wk3, nullptr, kb, 256, 256, 0);
  gemm_kernel<<<dim3(4, B * N2 / 32), 256, 0, stream>>>(fea2c, Wv3, nullptr, vb, 256, 256, 0);
  attn_kernel<<<dim3(N2, B), 128, 0, stream>>>(qb, kb, vb, fea2c, fea2d, N2, 256);

  // ---- FP-interp xyz1 <- xyz2, cat1 (B,512,384); Layer 5 -> fea1b
  interp3_kernel<<<B * N1 / 256, 256, 0, stream>>>(xyz1, xyz2, N1, N2, idxI1, wI1, B * N1);
  concat_kernel<<<B * N1 * 384 / 256, 256, 0, stream>>>(fea1, fea2d, idxI1, wI1, cat1, N1, N2,
                                                        128, 256, B * N1 * 384);
  gatherweight_kernel<<<B * N1, 64, 0, stream>>>(xyz1, cat1, idxK1, A[5], wfb, N1, 384);
  gemm_kernel<<<dim3(4, B * N1 / 32), 256, 0, stream>>>(wfb, W[5], bi[5], fea1b, 384, 256, 1);

  // ---- FP-interp xyz <- xyz1, cat0 (B,4096,320); Layer 6 -> feaL (B,4096,128)
  interp3_kernel<<<B * N0 / 256, 256, 0, stream>>>(xyz, xyz1, N0, N1, idxI0, wI0, B * N0);
  concat_kernel<<<B * N0 * 320 / 256, 256, 0, stream>>>(fea0, fea1b, idxI0, wI0, cat0, N0, N1,
                                                        64, 256, B * N0 * 320);
  gatherweight_kernel<<<B * N0, 64, 0, stream>>>(xyz, cat0, idxK0, A[6], wfb, N0, 320);
  gemm_kernel<<<dim3(2, B * N0 / 32), 256, 0, stream>>>(wfb, W[6], bi[6], feaL, 320, 128, 1);

  // ---- Final classifier -> out (B,13,4096)
  final_kernel<<<dim3(N0 / 256, 13, B), 256, 0, stream>>>(feaL, Wf, bf, out, N0);
}

// Round 3
// 1519.413 us; speedup vs baseline: 2.3941x; 1.3420x over previous
//
#include <hip/hip_runtime.h>
#include <math.h>

#define NBATCH 4

// branchless ascending compare-swap on u64 keys
#define CSWAP(a, b)                                          \
  {                                                          \
    unsigned long long _mn = (b < a) ? b : a;                \
    unsigned long long _mx = (b < a) ? a : b;                \
    a = _mn;                                                 \
    b = _mx;                                                 \
  }

// ---------------------------------------------------------------------------
// kNN-16, one wave per query. Key = (d2_bits << 32) | idx gives exact
// (d2, idx) lexicographic order (d2 >= 0 so fp bits are order-preserving),
// matching jax.lax.top_k's stable tie-break. Per-lane top-16 in named u64
// registers (no arrays -> no scratch), then 16-round pop-merge via LDS +
// wave-min butterfly. Output ascending = reference order.
// ---------------------------------------------------------------------------
__global__ __launch_bounds__(64) void knn16_wave(const float* __restrict__ xyz, int N,
                                                 float r2, int* __restrict__ idx_out) {
#pragma clang fp contract(off)
  int bn = blockIdx.x;
  int b = bn / N, n = bn - b * N;
  int lane = threadIdx.x;
  const float* xb = xyz + (size_t)b * N * 3;
  float qx = xb[n * 3 + 0], qy = xb[n * 3 + 1], qz = xb[n * 3 + 2];
  float qq = qx * qx + qy * qy + qz * qz;
  // sentinel: d2 bits = +inf, idx field = lane (keeps keys unique)
  const unsigned long long SENT = ((unsigned long long)0x7F800000u << 32) | (unsigned)lane;
  unsigned long long k0 = SENT, k1 = SENT, k2 = SENT, k3 = SENT, k4 = SENT, k5 = SENT,
                     k6 = SENT, k7 = SENT, k8 = SENT, k9 = SENT, k10 = SENT, k11 = SENT,
                     k12 = SENT, k13 = SENT, k14 = SENT, k15 = SENT;
  int rounds = N >> 6;
  for (int j = 0; j < rounds; ++j) {
    int m = j * 64 + lane;
    float cx = xb[m * 3 + 0], cy = xb[m * 3 + 1], cz = xb[m * 3 + 2];
    float cc = cx * cx + cy * cy + cz * cz;
    float ab = qx * cx + qy * cy + qz * cz;
    float d2 = fmaxf(qq + cc - 2.0f * ab, 0.0f);
    unsigned long long key = ((unsigned long long)__float_as_uint(d2) << 32) | (unsigned)m;
    if (key < k15) {
      k15 = key;
      CSWAP(k14, k15); CSWAP(k13, k14); CSWAP(k12, k13); CSWAP(k11, k12);
      CSWAP(k10, k11); CSWAP(k9, k10);  CSWAP(k8, k9);   CSWAP(k7, k8);
      CSWAP(k6, k7);   CSWAP(k5, k6);   CSWAP(k4, k5);   CSWAP(k3, k4);
      CSWAP(k2, k3);   CSWAP(k1, k2);   CSWAP(k0, k1);
    }
  }
  __shared__ unsigned long long lists[16 * 64];
  lists[0 * 64 + lane] = k0;   lists[1 * 64 + lane] = k1;
  lists[2 * 64 + lane] = k2;   lists[3 * 64 + lane] = k3;
  lists[4 * 64 + lane] = k4;   lists[5 * 64 + lane] = k5;
  lists[6 * 64 + lane] = k6;   lists[7 * 64 + lane] = k7;
  lists[8 * 64 + lane] = k8;   lists[9 * 64 + lane] = k9;
  lists[10 * 64 + lane] = k10; lists[11 * 64 + lane] = k11;
  lists[12 * 64 + lane] = k12; lists[13 * 64 + lane] = k13;
  lists[14 * 64 + lane] = k14; lists[15 * 64 + lane] = k15;
  __syncthreads();
  int head = 0;
  unsigned long long outk = 0;
  for (int r = 0; r < 16; ++r) {
    unsigned long long h = lists[head * 64 + lane];
    unsigned long long mn = h;
#pragma unroll
    for (int mask = 32; mask; mask >>= 1) {
      unsigned long long o = __shfl_xor(mn, mask);
      if (o < mn) mn = o;
    }
    if (h == mn) head++;   // keys unique -> exactly one winner advances
    if (lane == r) outk = mn;
  }
  if (lane < 16) {
    float d2 = __uint_as_float((unsigned)(outk >> 32));
    int m = (int)(outk & 0xFFFFFFFFu);
    idx_out[(size_t)bn * 16 + lane] = (d2 <= r2) ? m : n;
  }
}

// ---------------------------------------------------------------------------
// Furthest point sampling, latency-optimized. One block per batch, NT threads,
// PTS points/thread, NPT = N (compile-time). xyz staged in LDS so the winner
// coord fetch is an LDS broadcast (no dependent global load). Argmax packed
// as u64 key = (dist_bits<<32) | ~pt : single-value max reduce, exact
// (max dist, tie -> lowest pt) matching jnp.argmax. One barrier per iteration
// (parity double-buffered cross-wave slot); zero barriers when NT==64.
// ---------------------------------------------------------------------------
template <int NT, int PTS, int NPT>
__global__ __launch_bounds__(NT) void fps_kernel(const float* __restrict__ xyz, int N,
                                                 int npoint, int* __restrict__ idx_out,
                                                 float* __restrict__ xyz_out) {
#pragma clang fp contract(off)
  constexpr int NW = NT / 64;
  int b = blockIdx.x, tid = threadIdx.x;
  const float* xb = xyz + (size_t)b * N * 3;
  __shared__ float sxyz[3 * NPT];
  __shared__ int hist[512];
  __shared__ unsigned long long rk[2][NW > 1 ? NW : 1];
  // stage coords into LDS (coalesced read, linear write)
  for (int i = tid; i < 3 * N; i += NT) sxyz[i] = xb[i];
  float px[PTS], py[PTS], pz[PTS], dist[PTS];
#pragma unroll
  for (int p = 0; p < PTS; ++p) {
    int pt = tid + p * NT;
    px[p] = xb[pt * 3 + 0];
    py[p] = xb[pt * 3 + 1];
    pz[p] = xb[pt * 3 + 2];
    dist[p] = 1e10f;
  }
  __syncthreads();
  int far = 0;
  float cx = sxyz[0], cy = sxyz[1], cz = sxyz[2];
  for (int t = 0; t < npoint; ++t) {
    if (tid == 0) hist[t] = far;
    float best = -1.0f;
    int bestp = 0;
#pragma unroll
    for (int p = 0; p < PTS; ++p) {
      float dx = px[p] - cx, dy = py[p] - cy, dz = pz[p] - cz;
      float d = dx * dx + dy * dy + dz * dz;
      float nd = fminf(dist[p], d);
      dist[p] = nd;
      if (nd > best) { best = nd; bestp = tid + p * NT; }  // ascending pt: keeps lowest
    }
    unsigned long long key =
        ((unsigned long long)__float_as_uint(best) << 32) | (unsigned)(~bestp);
#pragma unroll
    for (int m = 32; m; m >>= 1) {
      unsigned long long o = __shfl_xor(key, m);
      if (o > key) key = o;
    }
    if constexpr (NW > 1) {
      int par = t & 1;
      if ((tid & 63) == 0) rk[par][tid >> 6] = key;
      __syncthreads();
      key = rk[par][0];
#pragma unroll
      for (int w = 1; w < NW; ++w) {
        unsigned long long o = rk[par][w];
        if (o > key) key = o;
      }
    }
    far = (int)(~(unsigned)key);
    cx = sxyz[3 * far + 0];
    cy = sxyz[3 * far + 1];
    cz = sxyz[3 * far + 2];
  }
  __syncthreads();
  for (int s = tid; s < npoint; s += NT) {
    int idp = hist[s];
    idx_out[(size_t)b * npoint + s] = idp;
    xyz_out[((size_t)b * npoint + s) * 3 + 0] = sxyz[3 * idp + 0];
    xyz_out[((size_t)b * npoint + s) * 3 + 1] = sxyz[3 * idp + 1];
    xyz_out[((size_t)b * npoint + s) * 3 + 2] = sxyz[3 * idp + 2];
  }
}

// ---------------------------------------------------------------------------
// Generic feature gather: dst[b][s][c] = src[b][idx[b][s]][c]
// ---------------------------------------------------------------------------
__global__ __launch_bounds__(256) void gather_kernel(const float* __restrict__ src,
                                                     const int* __restrict__ idx,
                                                     float* __restrict__ dst, int N, int S,
                                                     int C, int total) {
  int gid = blockIdx.x * 256 + threadIdx.x;
  if (gid >= total) return;
  int c = gid % C;
  int s = (gid / C) % S;
  int b = gid / (C * S);
  dst[gid] = src[((size_t)b * N + idx[b * S + s]) * C + c];
}

// ---------------------------------------------------------------------------
// LAE gather-weight: softmax attention over 16 neighbor coord offsets, then
// alpha-weighted feature sum (GEMM applied afterwards; softmax sums to 1).
// One wave per point; coalesced over Cin.
// ---------------------------------------------------------------------------
__global__ __launch_bounds__(64) void gatherweight_kernel(const float* __restrict__ xyz,
                                                          const float* __restrict__ fea,
                                                          const int* __restrict__ knn,
                                                          const float* __restrict__ A,
                                                          float* __restrict__ wf, int N,
                                                          int Cin) {
  int bn = blockIdx.x;
  int b = bn / N, n = bn - b * N;
  int lane = threadIdx.x;
  const float* xb = xyz + (size_t)b * N * 3;
  const int* kn = knn + (size_t)bn * 16;
  float ax = A[0], ay = A[1], az = A[2];
  float qx = xb[n * 3 + 0], qy = xb[n * 3 + 1], qz = xb[n * 3 + 2];
  int id[16];
  float al[16];
#pragma unroll
  for (int k = 0; k < 16; ++k) id[k] = kn[k];
  float mx = -3.0e38f;
#pragma unroll
  for (int k = 0; k < 16; ++k) {
    float gx = xb[id[k] * 3 + 0] - qx;
    float gy = xb[id[k] * 3 + 1] - qy;
    float gz = xb[id[k] * 3 + 2] - qz;
    float s = gx * ax + gy * ay + gz * az;
    al[k] = s;
    mx = fmaxf(mx, s);
  }
  float sum = 0.0f;
#pragma unroll
  for (int k = 0; k < 16; ++k) { al[k] = expf(al[k] - mx); sum += al[k]; }
#pragma unroll
  for (int k = 0; k < 16; ++k) al[k] = al[k] / sum;
  const float* fb = fea + (size_t)b * N * Cin;
  float* wo = wf + (size_t)bn * Cin;
  for (int c = lane; c < Cin; c += 64) {
    float acc = 0.0f;
#pragma unroll
    for (int k = 0; k < 16; ++k) acc += al[k] * fb[(size_t)id[k] * Cin + c];
    wo[c] = acc;
  }
}

// ---------------------------------------------------------------------------
// Tiled fp32 GEMM: out[r][co] = act(sum_k A[r][k]*W[k][co] + bias).
// Block 256 = 64 couts x 4 row-groups; tile 32 rows x 64 couts.
// ---------------------------------------------------------------------------
__global__ __launch_bounds__(256) void gemm_kernel(const float* __restrict__ Amat,
                                                   const float* __restrict__ W,
                                                   const float* __restrict__ bias,
                                                   float* __restrict__ out, int K, int Cout,
                                                   int relu) {
  __shared__ float lds_a[32 * 36];
  int co = blockIdx.x * 64 + (threadIdx.x & 63);
  int rg = threadIdx.x >> 6;
  int r0 = blockIdx.y * 32;
  float acc[8];
#pragma unroll
  for (int j = 0; j < 8; ++j) acc[j] = 0.0f;
  for (int k0 = 0; k0 < K; k0 += 32) {
    int row = threadIdx.x >> 3;
    int kq = (threadIdx.x & 7) * 4;
    int gk = k0 + kq;
    const float* ap = Amat + (size_t)(r0 + row) * K + gk;
    float a0 = 0.0f, a1 = 0.0f, a2 = 0.0f, a3 = 0.0f;
    if (gk + 3 < K) {
      float4 tv = *(const float4*)ap;
      a0 = tv.x; a1 = tv.y; a2 = tv.z; a3 = tv.w;
    } else {
      if (gk + 0 < K) a0 = ap[0];
      if (gk + 1 < K) a1 = ap[1];
      if (gk + 2 < K) a2 = ap[2];
    }
    __syncthreads();
    lds_a[(kq + 0) * 36 + row] = a0;
    lds_a[(kq + 1) * 36 + row] = a1;
    lds_a[(kq + 2) * 36 + row] = a2;
    lds_a[(kq + 3) * 36 + row] = a3;
    __syncthreads();
    int kmax = K - k0;
    if (kmax > 32) kmax = 32;
    if (kmax == 32) {
#pragma unroll
      for (int kk = 0; kk < 32; ++kk) {
        float w = W[(size_t)(k0 + kk) * Cout + co];
        const float* ar = &lds_a[kk * 36 + rg * 8];
        float4 x0 = *(const float4*)ar;
        float4 x1 = *(const float4*)(ar + 4);
        acc[0] += x0.x * w; acc[1] += x0.y * w; acc[2] += x0.z * w; acc[3] += x0.w * w;
        acc[4] += x1.x * w; acc[5] += x1.y * w; acc[6] += x1.z * w; acc[7] += x1.w * w;
      }
    } else {
      for (int kk = 0; kk < kmax; ++kk) {
        float w = W[(size_t)(k0 + kk) * Cout + co];
        const float* ar = &lds_a[kk * 36 + rg * 8];
        float4 x0 = *(const float4*)ar;
        float4 x1 = *(const float4*)(ar + 4);
        acc[0] += x0.x * w; acc[1] += x0.y * w; acc[2] += x0.z * w; acc[3] += x0.w * w;
        acc[4] += x1.x * w; acc[5] += x1.y * w; acc[6] += x1.z * w; acc[7] += x1.w * w;
      }
    }
  }
  float bb = bias ? bias[co] : 0.0f;
#pragma unroll
  for (int j = 0; j < 8; ++j) {
    float vv = acc[j] + bb;
    if (relu) vv = fmaxf(vv, 0.0f);
    out[(size_t)(r0 + rg * 8 + j) * Cout + co] = vv;
  }
}

// ---------------------------------------------------------------------------
// Self-attention mix: out[n] = softmax(q[n]·k^T) @ v + fea[n]. Block per (b,n).
// ---------------------------------------------------------------------------
__global__ __launch_bounds__(128) void attn_kernel(const float* __restrict__ q,
                                                   const float* __restrict__ k,
                                                   const float* __restrict__ v,
                                                   const float* __restrict__ fea,
                                                   float* __restrict__ out, int N, int C) {
  __shared__ float sa[128];
  __shared__ float sb[128];
  int b = blockIdx.y, n = blockIdx.x, t = threadIdx.x;
  const float* qn = q + ((size_t)b * N + n) * C;
  if (t < N) {
    const float* km = k + ((size_t)b * N + t) * C;
    float acc = 0.0f;
    for (int c = 0; c < C; ++c) acc += qn[c] * km[c];
    sa[t] = acc;
  }
  __syncthreads();
  float mx = -3.0e38f;
  for (int i = 0; i < N; ++i) mx = fmaxf(mx, sa[i]);
  if (t < N) sb[t] = expf(sa[t] - mx);
  __syncthreads();
  float sum = 0.0f;
  for (int i = 0; i < N; ++i) sum += sb[i];
  size_t rowo = ((size_t)b * N + n) * C;
  for (int c = t; c < C; c += 128) {
    float acc = 0.0f;
    for (int m = 0; m < N; ++m) acc += sb[m] * v[((size_t)b * N + m) * C + c];
    out[rowo + c] = acc / sum + fea[rowo + c];
  }
}

// ---------------------------------------------------------------------------
// 3-NN inverse-distance weights (pdist2 form, stable top-3).
// ---------------------------------------------------------------------------
__global__ __launch_bounds__(256) void interp3_kernel(const float* __restrict__ xd,
                                                      const float* __restrict__ xs, int Nd,
                                                      int Ns, int* __restrict__ idx3,
                                                      float* __restrict__ w3, int total) {
#pragma clang fp contract(off)
  int gid = blockIdx.x * 256 + threadIdx.x;
  if (gid >= total) return;
  int b = gid / Nd;
  const float* xb = xs + (size_t)b * Ns * 3;
  float qx = xd[gid * 3 + 0], qy = xd[gid * 3 + 1], qz = xd[gid * 3 + 2];
  float qq = qx * qx + qy * qy + qz * qz;
  float v0 = 3.0e38f, v1 = 3.0e38f, v2 = 3.0e38f;
  int i0 = 0, i1 = 0, i2 = 0;
  for (int m = 0; m < Ns; ++m) {
    float cx = xb[m * 3 + 0], cy = xb[m * 3 + 1], cz = xb[m * 3 + 2];
    float cc = cx * cx + cy * cy + cz * cz;
    float ab = qx * cx + qy * cy + qz * cz;
    float d2 = fmaxf(qq + cc - 2.0f * ab, 0.0f);
    if (d2 < v2) {
      if (d2 < v0) { v2 = v1; i2 = i1; v1 = v0; i1 = i0; v0 = d2; i0 = m; }
      else if (d2 < v1) { v2 = v1; i2 = i1; v1 = d2; i1 = m; }
      else { v2 = d2; i2 = m; }
    }
  }
  float w0 = 1.0f / fmaxf(v0, 1e-10f);
  float w1 = 1.0f / fmaxf(v1, 1e-10f);
  float w2 = 1.0f / fmaxf(v2, 1e-10f);
  float s = w0 + w1 + w2;
  idx3[gid * 3 + 0] = i0; idx3[gid * 3 + 1] = i1; idx3[gid * 3 + 2] = i2;
  w3[gid * 3 + 0] = w0 / s; w3[gid * 3 + 1] = w1 / s; w3[gid * 3 + 2] = w2 / s;
}

// ---------------------------------------------------------------------------
// Skip-concat + 3NN interpolation: out = [fea_d | sum_j w_j fea_s[idx_j]]
// ---------------------------------------------------------------------------
__global__ __launch_bounds__(256) void concat_kernel(const float* __restrict__ fd,
                                                     const float* __restrict__ fs,
                                                     const int* __restrict__ idx3,
                                                     const float* __restrict__ w3,
                                                     float* __restrict__ out, int Nd, int Ns,
                                                     int Cd, int Cs, int total) {
  int gid = blockIdx.x * 256 + threadIdx.x;
  if (gid >= total) return;
  int C = Cd + Cs;
  int c = gid % C;
  int bn = gid / C;
  int b = bn / Nd;
  if (c < Cd) {
    out[gid] = fd[(size_t)bn * Cd + c];
  } else {
    int cc = c - Cd;
    const int* ii = idx3 + (size_t)bn * 3;
    const float* ww = w3 + (size_t)bn * 3;
    const float* fb = fs + (size_t)b * Ns * Cs;
    out[gid] = ww[0] * fb[(size_t)ii[0] * Cs + cc] + ww[1] * fb[(size_t)ii[1] * Cs + cc] +
               ww[2] * fb[(size_t)ii[2] * Cs + cc];
  }
}

// ---------------------------------------------------------------------------
// Final classifier, writes transposed (B, 13, N).
// ---------------------------------------------------------------------------
__global__ __launch_bounds__(256) void final_kernel(const float* __restrict__ fea,
                                                    const float* __restrict__ Wf,
                                                    const float* __restrict__ bfv,
                                                    float* __restrict__ out, int N) {
  int n = blockIdx.x * 256 + threadIdx.x;
  int c = blockIdx.y;
  int b = blockIdx.z;
  const float* fr = fea + ((size_t)b * N + n) * 128;
  float acc = 0.0f;
#pragma unroll 8
  for (int k = 0; k < 128; ++k) acc += fr[k] * Wf[k * 13 + c];
  out[((size_t)b * 13 + c) * N + n] = acc + bfv[c];
}

// ---------------------------------------------------------------------------
extern "C" void kernel_launch(void* const* d_in, const int* in_sizes, int n_in,
                              void* d_out, int out_size, void* d_ws, size_t ws_size,
                              hipStream_t stream) {
  (void)in_sizes; (void)n_in; (void)out_size; (void)ws_size;
  const float* xyz = (const float*)d_in[0];
  const float* W[7]; const float* bi[7]; const float* A[7];
  for (int i = 0; i < 7; ++i) {
    W[i] = (const float*)d_in[1 + 3 * i];
    bi[i] = (const float*)d_in[2 + 3 * i];
    A[i] = (const float*)d_in[3 + 3 * i];
  }
  const float* Wq1 = (const float*)d_in[22];
  const float* Wk1 = (const float*)d_in[23];
  const float* Wv1 = (const float*)d_in[24];
  const float* Wq2 = (const float*)d_in[25];
  const float* Wk2 = (const float*)d_in[26];
  const float* Wv2 = (const float*)d_in[27];
  const float* Wq3 = (const float*)d_in[28];
  const float* Wk3 = (const float*)d_in[29];
  const float* Wv3 = (const float*)d_in[30];
  const float* Wf = (const float*)d_in[31];
  const float* bf = (const float*)d_in[32];
  float* out = (float*)d_out;

  const int B = NBATCH, N0 = 4096, N1 = 512, N2 = 128, N3 = 64;
  char* base = (char*)d_ws;
  size_t off = 0;
  auto alloc = [&](size_t bytes) -> void* {
    void* p = base + off;
    off += (bytes + 255) & ~(size_t)255;
    return p;
  };
  int* idxK0 = (int*)alloc((size_t)B * N0 * 16 * 4);
  int* idxK1 = (int*)alloc((size_t)B * N1 * 16 * 4);
  int* idxK2 = (int*)alloc((size_t)B * N2 * 16 * 4);
  int* idxK3 = (int*)alloc((size_t)B * N3 * 16 * 4);
  int* idx1 = (int*)alloc((size_t)B * N1 * 4);
  int* idx2 = (int*)alloc((size_t)B * N2 * 4);
  int* idx3 = (int*)alloc((size_t)B * N3 * 4);
  float* xyz1 = (float*)alloc((size_t)B * N1 * 3 * 4);
  float* xyz2 = (float*)alloc((size_t)B * N2 * 3 * 4);
  float* xyz3 = (float*)alloc((size_t)B * N3 * 3 * 4);
  float* fea0 = (float*)alloc((size_t)B * N0 * 64 * 4);
  float* fea1in = (float*)alloc((size_t)B * N1 * 64 * 4);
  float* fea1 = (float*)alloc((size_t)B * N1 * 128 * 4);
  float* fea1b = (float*)alloc((size_t)B * N1 * 256 * 4);
  float* fea2in = (float*)alloc((size_t)B * N2 * 128 * 4);
  float* fea2a = (float*)alloc((size_t)B * N2 * 256 * 4);
  float* fea2b = (float*)alloc((size_t)B * N2 * 256 * 4);
  float* fea2c = (float*)alloc((size_t)B * N2 * 256 * 4);
  float* fea2d = (float*)alloc((size_t)B * N2 * 256 * 4);
  float* fea3in = (float*)alloc((size_t)B * N3 * 256 * 4);
  float* fea3a = (float*)alloc((size_t)B * N3 * 512 * 4);
  float* fea3b = (float*)alloc((size_t)B * N3 * 512 * 4);
  float* qb = (float*)alloc((size_t)B * 32768 * 4);
  float* kb = (float*)alloc((size_t)B * 32768 * 4);
  float* vb = (float*)alloc((size_t)B * 32768 * 4);
  int* idxI2 = (int*)alloc((size_t)B * N2 * 3 * 4);
  float* wI2 = (float*)alloc((size_t)B * N2 * 3 * 4);
  int* idxI1 = (int*)alloc((size_t)B * N1 * 3 * 4);
  float* wI1 = (float*)alloc((size_t)B * N1 * 3 * 4);
  int* idxI0 = (int*)alloc((size_t)B * N0 * 3 * 4);
  float* wI0 = (float*)alloc((size_t)B * N0 * 3 * 4);
  float* cat2 = (float*)alloc((size_t)B * N2 * 768 * 4);
  float* cat1 = (float*)alloc((size_t)B * N1 * 384 * 4);
  float* cat0 = (float*)alloc((size_t)B * N0 * 320 * 4);
  float* feaL = (float*)alloc((size_t)B * N0 * 128 * 4);
  float* wfb = (float*)alloc((size_t)B * N0 * 320 * 4);

  float r2_0 = (float)(0.06 * 0.06);
  float r2_1 = (float)(0.12 * 0.12);
  float r2_2 = (float)(0.3 * 0.3);
  float r2_3 = (float)(0.5 * 0.5);

  // ---- Layer 0: lae_conv(xyz, xyz, W0) radius 0.06 -> fea0 (B,4096,64)
  knn16_wave<<<B * N0, 64, 0, stream>>>(xyz, N0, r2_0, idxK0);
  gatherweight_kernel<<<B * N0, 64, 0, stream>>>(xyz, xyz, idxK0, A[0], wfb, N0, 3);
  gemm_kernel<<<dim3(1, B * N0 / 32), 256, 0, stream>>>(wfb, W[0], bi[0], fea0, 3, 64, 1);

  // ---- FPS 4096 -> 512
  fps_kernel<256, 16, 4096><<<B, 256, 0, stream>>>(xyz, N0, N1, idx1, xyz1);
  gather_kernel<<<B * N1 * 64 / 256, 256, 0, stream>>>(fea0, idx1, fea1in, N0, N1, 64,
                                                       B * N1 * 64);
  // ---- Layer 1: radius 0.12 -> fea1 (B,512,128)
  knn16_wave<<<B * N1, 64, 0, stream>>>(xyz1, N1, r2_1, idxK1);
  gatherweight_kernel<<<B * N1, 64, 0, stream>>>(xyz1, fea1in, idxK1, A[1], wfb, N1, 64);
  gemm_kernel<<<dim3(2, B * N1 / 32), 256, 0, stream>>>(wfb, W[1], bi[1], fea1, 64, 128, 1);

  // ---- FPS 512 -> 128
  fps_kernel<256, 2, 512><<<B, 256, 0, stream>>>(xyz1, N1, N2, idx2, xyz2);
  gather_kernel<<<B * N2 * 128 / 256, 256, 0, stream>>>(fea1, idx2, fea2in, N1, N2, 128,
                                                        B * N2 * 128);
  // ---- Layer 2: radius 0.3 -> fea2a (B,128,256), then self-attn 1
  knn16_wave<<<B * N2, 64, 0, stream>>>(xyz2, N2, r2_2, idxK2);
  gatherweight_kernel<<<B * N2, 64, 0, stream>>>(xyz2, fea2in, idxK2, A[2], wfb, N2, 128);
  gemm_kernel<<<dim3(4, B * N2 / 32), 256, 0, stream>>>(wfb, W[2], bi[2], fea2a, 128, 256, 1);
  gemm_kernel<<<dim3(4, B * N2 / 32), 256, 0, stream>>>(fea2a, Wq1, nullptr, qb, 256, 256, 0);
  gemm_kernel<<<dim3(4, B * N2 / 32), 256, 0, stream>>>(fea2a, Wk1, nullptr, kb, 256, 256, 0);
  gemm_kernel<<<dim3(4, B * N2 / 32), 256, 0, stream>>>(fea2a, Wv1, nullptr, vb, 256, 256, 0);
  attn_kernel<<<dim3(N2, B), 128, 0, stream>>>(qb, kb, vb, fea2a, fea2b, N2, 256);

  // ---- FPS 128 -> 64
  fps_kernel<64, 2, 128><<<B, 64, 0, stream>>>(xyz2, N2, N3, idx3, xyz3);
  gather_kernel<<<B * N3 * 256 / 256, 256, 0, stream>>>(fea2b, idx3, fea3in, N2, N3, 256,
                                                        B * N3 * 256);
  // ---- Layer 3: radius 0.5 -> fea3a (B,64,512), then self-attn 2
  knn16_wave<<<B * N3, 64, 0, stream>>>(xyz3, N3, r2_3, idxK3);
  gatherweight_kernel<<<B * N3, 64, 0, stream>>>(xyz3, fea3in, idxK3, A[3], wfb, N3, 256);
  gemm_kernel<<<dim3(8, B * N3 / 32), 256, 0, stream>>>(wfb, W[3], bi[3], fea3a, 256, 512, 1);
  gemm_kernel<<<dim3(8, B * N3 / 32), 256, 0, stream>>>(fea3a, Wq2, nullptr, qb, 512, 512, 0);
  gemm_kernel<<<dim3(8, B * N3 / 32), 256, 0, stream>>>(fea3a, Wk2, nullptr, kb, 512, 512, 0);
  gemm_kernel<<<dim3(8, B * N3 / 32), 256, 0, stream>>>(fea3a, Wv2, nullptr, vb, 512, 512, 0);
  attn_kernel<<<dim3(N3, B), 128, 0, stream>>>(qb, kb, vb, fea3a, fea3b, N3, 512);

  // ---- FP-interp xyz2 <- xyz3, cat2 (B,128,768); Layer 4 -> fea2c; attn 3
  interp3_kernel<<<B * N2 / 256, 256, 0, stream>>>(xyz2, xyz3, N2, N3, idxI2, wI2, B * N2);
  concat_kernel<<<B * N2 * 768 / 256, 256, 0, stream>>>(fea2b, fea3b, idxI2, wI2, cat2, N2,
                                                        N3, 256, 512, B * N2 * 768);
  gatherweight_kernel<<<B * N2, 64, 0, stream>>>(xyz2, cat2, idxK2, A[4], wfb, N2, 768);
  gemm_kernel<<<dim3(4, B * N2 / 32), 256, 0, stream>>>(wfb, W[4], bi[4], fea2c, 768, 256, 1);
  gemm_kernel<<<dim3(4, B * N2 / 32), 256, 0, stream>>>(fea2c, Wq3, nullptr, qb, 256, 256, 0);
  gemm_kernel<<<dim3(4, B * N2 / 32), 256, 0, stream>>>(fea2c, Wk3, nullptr, kb, 256, 256, 0);
  gemm_kernel<<<dim3(4, B * N2 / 32), 256, 0, stream>>>(fea2c, Wv3, nullptr, vb, 256, 256, 0);
  attn_kernel<<<dim3(N2, B), 128, 0, stream>>>(qb, kb, vb, fea2c, fea2d, N2, 256);

  // ---- FP-interp xyz1 <- xyz2, cat1 (B,512,384); Layer 5 -> fea1b
  interp3_kernel<<<B * N1 / 256, 256, 0, stream>>>(xyz1, xyz2, N1, N2, idxI1, wI1, B * N1);
  concat_kernel<<<B * N1 * 384 / 256, 256, 0, stream>>>(fea1, fea2d, idxI1, wI1, cat1, N1, N2,
                                                        128, 256, B * N1 * 384);
  gatherweight_kernel<<<B * N1, 64, 0, stream>>>(xyz1, cat1, idxK1, A[5], wfb, N1, 384);
  gemm_kernel<<<dim3(4, B * N1 / 32), 256, 0, stream>>>(wfb, W[5], bi[5], fea1b, 384, 256, 1);

  // ---- FP-interp xyz <- xyz1, cat0 (B,4096,320); Layer 6 -> feaL (B,4096,128)
  interp3_kernel<<<B * N0 / 256, 256, 0, stream>>>(xyz, xyz1, N0, N1, idxI0, wI0, B * N0);
  concat_kernel<<<B * N0 * 320 / 256, 256, 0, stream>>>(fea0, fea1b, idxI0, wI0, cat0, N0, N1,
                                                        64, 256, B * N0 * 320);
  gatherweight_kernel<<<B * N0, 64, 0, stream>>>(xyz, cat0, idxK0, A[6], wfb, N0, 320);
  gemm_kernel<<<dim3(2, B * N0 / 32), 256, 0, stream>>>(wfb, W[6], bi[6], feaL, 320, 128, 1);

  // ---- Final classifier -> out (B,13,4096)
  final_kernel<<<dim3(N0 / 256, 13, B), 256, 0, stream>>>(feaL, Wf, bf, out, N0);
}

// Round 4
// 1411.179 us; speedup vs baseline: 2.5777x; 1.0767x over previous
//
#include <hip/hip_runtime.h>
#include <math.h>

#define NBATCH 4

// branchless ascending compare-swap on u64 keys
#define CSWAP(a, b)                                          \
  {                                                          \
    unsigned long long _mn = (b < a) ? b : a;                \
    unsigned long long _mx = (b < a) ? a : b;                \
    a = _mn;                                                 \
    b = _mx;                                                 \
  }

// ---------------------------------------------------------------------------
// kNN-16, one wave per query. Key = (d2_bits << 32) | idx gives exact
// (d2, idx) lexicographic order, matching jax.lax.top_k's stable tie-break.
// ---------------------------------------------------------------------------
__global__ __launch_bounds__(64) void knn16_wave(const float* __restrict__ xyz, int N,
                                                 float r2, int* __restrict__ idx_out) {
#pragma clang fp contract(off)
  int bn = blockIdx.x;
  int b = bn / N, n = bn - b * N;
  int lane = threadIdx.x;
  const float* xb = xyz + (size_t)b * N * 3;
  float qx = xb[n * 3 + 0], qy = xb[n * 3 + 1], qz = xb[n * 3 + 2];
  float qq = qx * qx + qy * qy + qz * qz;
  const unsigned long long SENT = ((unsigned long long)0x7F800000u << 32) | (unsigned)lane;
  unsigned long long k0 = SENT, k1 = SENT, k2 = SENT, k3 = SENT, k4 = SENT, k5 = SENT,
                     k6 = SENT, k7 = SENT, k8 = SENT, k9 = SENT, k10 = SENT, k11 = SENT,
                     k12 = SENT, k13 = SENT, k14 = SENT, k15 = SENT;
  int rounds = N >> 6;
  for (int j = 0; j < rounds; ++j) {
    int m = j * 64 + lane;
    float cx = xb[m * 3 + 0], cy = xb[m * 3 + 1], cz = xb[m * 3 + 2];
    float cc = cx * cx + cy * cy + cz * cz;
    float ab = qx * cx + qy * cy + qz * cz;
    float d2 = fmaxf(qq + cc - 2.0f * ab, 0.0f);
    unsigned long long key = ((unsigned long long)__float_as_uint(d2) << 32) | (unsigned)m;
    if (key < k15) {
      k15 = key;
      CSWAP(k14, k15); CSWAP(k13, k14); CSWAP(k12, k13); CSWAP(k11, k12);
      CSWAP(k10, k11); CSWAP(k9, k10);  CSWAP(k8, k9);   CSWAP(k7, k8);
      CSWAP(k6, k7);   CSWAP(k5, k6);   CSWAP(k4, k5);   CSWAP(k3, k4);
      CSWAP(k2, k3);   CSWAP(k1, k2);   CSWAP(k0, k1);
    }
  }
  __shared__ unsigned long long lists[16 * 64];
  lists[0 * 64 + lane] = k0;   lists[1 * 64 + lane] = k1;
  lists[2 * 64 + lane] = k2;   lists[3 * 64 + lane] = k3;
  lists[4 * 64 + lane] = k4;   lists[5 * 64 + lane] = k5;
  lists[6 * 64 + lane] = k6;   lists[7 * 64 + lane] = k7;
  lists[8 * 64 + lane] = k8;   lists[9 * 64 + lane] = k9;
  lists[10 * 64 + lane] = k10; lists[11 * 64 + lane] = k11;
  lists[12 * 64 + lane] = k12; lists[13 * 64 + lane] = k13;
  lists[14 * 64 + lane] = k14; lists[15 * 64 + lane] = k15;
  __syncthreads();
  int head = 0;
  unsigned long long outk = 0;
  for (int r = 0; r < 16; ++r) {
    unsigned long long h = lists[head * 64 + lane];
    unsigned long long mn = h;
#pragma unroll
    for (int mask = 32; mask; mask >>= 1) {
      unsigned long long o = __shfl_xor(mn, mask);
      if (o < mn) mn = o;
    }
    if (h == mn) head++;
    if (lane == r) outk = mn;
  }
  if (lane < 16) {
    float d2 = __uint_as_float((unsigned)(outk >> 32));
    int m = (int)(outk & 0xFFFFFFFFu);
    idx_out[(size_t)bn * 16 + lane] = (d2 <= r2) ? m : n;
  }
}

// ---------------------------------------------------------------------------
// Furthest point sampling + fused output gather. Tree-reduced candidate keys
// (u64 = dist_bits<<32 | ~pt : max key == (max dist, tie -> lowest pt),
// associative so tree order is exact). One barrier/iter (none for NT=64).
// After sampling, also gathers features (C = 1<<C_LOG2) for the sampled set.
// ---------------------------------------------------------------------------
template <int NT, int PTS, int NPT, int C_LOG2>
__global__ __launch_bounds__(NT) void fps_kernel(const float* __restrict__ xyz, int N,
                                                 int npoint, int* __restrict__ idx_out,
                                                 float* __restrict__ xyz_out,
                                                 const float* __restrict__ fea,
                                                 float* __restrict__ fea_out) {
#pragma clang fp contract(off)
  constexpr int NW = NT / 64;
  int b = blockIdx.x, tid = threadIdx.x;
  const float* xb = xyz + (size_t)b * N * 3;
  __shared__ float sxyz[3 * NPT];
  __shared__ int hist[512];
  __shared__ unsigned long long rk[2][NW > 1 ? NW : 1];
  for (int i = tid; i < 3 * N; i += NT) sxyz[i] = xb[i];
  float px[PTS], py[PTS], pz[PTS], dist[PTS];
#pragma unroll
  for (int p = 0; p < PTS; ++p) {
    int pt = tid + p * NT;
    px[p] = xb[pt * 3 + 0];
    py[p] = xb[pt * 3 + 1];
    pz[p] = xb[pt * 3 + 2];
    dist[p] = 1e10f;
  }
  __syncthreads();
  int far = 0;
  float cx = sxyz[0], cy = sxyz[1], cz = sxyz[2];
  for (int t = 0; t < npoint; ++t) {
    if (tid == 0) hist[t] = far;
    unsigned long long K[PTS];
#pragma unroll
    for (int p = 0; p < PTS; ++p) {
      float dx = px[p] - cx, dy = py[p] - cy, dz = pz[p] - cz;
      float d = dx * dx + dy * dy + dz * dz;
      float nd = fminf(dist[p], d);
      dist[p] = nd;
      K[p] = ((unsigned long long)__float_as_uint(nd) << 32) | (unsigned)(~(tid + p * NT));
    }
#pragma unroll
    for (int s = PTS / 2; s >= 1; s >>= 1) {
#pragma unroll
      for (int i = 0; i < s; ++i)
        if (K[i + s] > K[i]) K[i] = K[i + s];
    }
    unsigned long long key = K[0];
#pragma unroll
    for (int m = 32; m; m >>= 1) {
      unsigned long long o = __shfl_xor(key, m);
      if (o > key) key = o;
    }
    if constexpr (NW > 1) {
      int par = t & 1;
      if ((tid & 63) == 0) rk[par][tid >> 6] = key;
      __syncthreads();
      key = rk[par][0];
#pragma unroll
      for (int w = 1; w < NW; ++w)
        if (rk[par][w] > key) key = rk[par][w];
    }
    far = (int)(~(unsigned)key);
    cx = sxyz[3 * far + 0];
    cy = sxyz[3 * far + 1];
    cz = sxyz[3 * far + 2];
  }
  __syncthreads();
  for (int s = tid; s < npoint; s += NT) {
    int idp = hist[s];
    idx_out[(size_t)b * npoint + s] = idp;
    xyz_out[((size_t)b * npoint + s) * 3 + 0] = sxyz[3 * idp + 0];
    xyz_out[((size_t)b * npoint + s) * 3 + 1] = sxyz[3 * idp + 1];
    xyz_out[((size_t)b * npoint + s) * 3 + 2] = sxyz[3 * idp + 2];
  }
  constexpr int C = 1 << C_LOG2;
  const float* fb = fea + (size_t)b * N * C;
  float* fo = fea_out + ((size_t)b * npoint << C_LOG2);
  for (int i = tid; i < (npoint << C_LOG2); i += NT) {
    int s = i >> C_LOG2, c = i & (C - 1);
    fo[i] = fb[(size_t)hist[s] * C + c];
  }
}

// ---------------------------------------------------------------------------
// LAE gather-weight (PRE-GEMM form, used when Cin < Cout): softmax attention
// over 16 neighbor coord offsets, alpha-weighted feature sum. Wave per point.
// ---------------------------------------------------------------------------
__global__ __launch_bounds__(64) void gatherweight_kernel(const float* __restrict__ xyz,
                                                          const float* __restrict__ fea,
                                                          const int* __restrict__ knn,
                                                          const float* __restrict__ A,
                                                          float* __restrict__ wf, int N,
                                                          int Cin) {
  int bn = blockIdx.x;
  int b = bn / N, n = bn - b * N;
  int lane = threadIdx.x;
  const float* xb = xyz + (size_t)b * N * 3;
  const int* kn = knn + (size_t)bn * 16;
  float ax = A[0], ay = A[1], az = A[2];
  float qx = xb[n * 3 + 0], qy = xb[n * 3 + 1], qz = xb[n * 3 + 2];
  int id[16];
  float al[16];
#pragma unroll
  for (int k = 0; k < 16; ++k) id[k] = kn[k];
  float mx = -3.0e38f;
#pragma unroll
  for (int k = 0; k < 16; ++k) {
    float gx = xb[id[k] * 3 + 0] - qx;
    float gy = xb[id[k] * 3 + 1] - qy;
    float gz = xb[id[k] * 3 + 2] - qz;
    float s = gx * ax + gy * ay + gz * az;
    al[k] = s;
    mx = fmaxf(mx, s);
  }
  float sum = 0.0f;
#pragma unroll
  for (int k = 0; k < 16; ++k) { al[k] = expf(al[k] - mx); sum += al[k]; }
#pragma unroll
  for (int k = 0; k < 16; ++k) al[k] = al[k] / sum;
  const float* fb = fea + (size_t)b * N * Cin;
  float* wo = wf + (size_t)bn * Cin;
  for (int c = lane; c < Cin; c += 64) {
    float acc = 0.0f;
#pragma unroll
    for (int k = 0; k < 16; ++k) acc += al[k] * fb[(size_t)id[k] * Cin + c];
    wo[c] = acc;
  }
}

// ---------------------------------------------------------------------------
// LAE gather-weight (POST-GEMM form, used when Cout <= Cin): Y = fea @ W
// already computed; out[n][c] = relu(sum_k alpha[n][k] * Y[idx[n][k]][c] + b[c])
// ---------------------------------------------------------------------------
__global__ __launch_bounds__(64) void gwpost_kernel(const float* __restrict__ xyz,
                                                    const float* __restrict__ Y,
                                                    const int* __restrict__ knn,
                                                    const float* __restrict__ A,
                                                    const float* __restrict__ bias,
                                                    float* __restrict__ out, int N, int C) {
  int bn = blockIdx.x;
  int b = bn / N, n = bn - b * N;
  int lane = threadIdx.x;
  const float* xb = xyz + (size_t)b * N * 3;
  const int* kn = knn + (size_t)bn * 16;
  float ax = A[0], ay = A[1], az = A[2];
  float qx = xb[n * 3 + 0], qy = xb[n * 3 + 1], qz = xb[n * 3 + 2];
  int id[16];
  float al[16];
#pragma unroll
  for (int k = 0; k < 16; ++k) id[k] = kn[k];
  float mx = -3.0e38f;
#pragma unroll
  for (int k = 0; k < 16; ++k) {
    float gx = xb[id[k] * 3 + 0] - qx;
    float gy = xb[id[k] * 3 + 1] - qy;
    float gz = xb[id[k] * 3 + 2] - qz;
    float s = gx * ax + gy * ay + gz * az;
    al[k] = s;
    mx = fmaxf(mx, s);
  }
  float sum = 0.0f;
#pragma unroll
  for (int k = 0; k < 16; ++k) { al[k] = expf(al[k] - mx); sum += al[k]; }
#pragma unroll
  for (int k = 0; k < 16; ++k) al[k] = al[k] / sum;
  const float* Yb = Y + (size_t)b * N * C;
  float* wo = out + (size_t)bn * C;
  for (int c = lane; c < C; c += 64) {
    float acc = 0.0f;
#pragma unroll
    for (int k = 0; k < 16; ++k) acc += al[k] * Yb[(size_t)id[k] * C + c];
    wo[c] = fmaxf(acc + bias[c], 0.0f);
  }
}

// ---------------------------------------------------------------------------
// Tiled fp32 GEMM body: out[r][co] = act(sum_k A[r][k]*W[k][co] + bias)
// with optional fused 3-NN interp epilogue (+ sum_j w3[r][j]*Zb[i3[r][j]][co]).
// Block 256 = 64 couts x 4 row-groups; tile 32 rows x 64 couts.
// ---------------------------------------------------------------------------
__device__ __forceinline__ void gemm_body(const float* __restrict__ Amat,
                                          const float* __restrict__ W,
                                          const float* __restrict__ bias,
                                          float* __restrict__ out, int K, int Cout, int relu,
                                          const int* __restrict__ i3,
                                          const float* __restrict__ w3,
                                          const float* __restrict__ Zb, int Nd, int Ns,
                                          float* lds_a) {
  int co = blockIdx.x * 64 + (threadIdx.x & 63);
  int rg = threadIdx.x >> 6;
  int r0 = blockIdx.y * 32;
  float acc[8];
#pragma unroll
  for (int j = 0; j < 8; ++j) acc[j] = 0.0f;
  for (int k0 = 0; k0 < K; k0 += 32) {
    int row = threadIdx.x >> 3;
    int kq = (threadIdx.x & 7) * 4;
    int gk = k0 + kq;
    const float* ap = Amat + (size_t)(r0 + row) * K + gk;
    float a0 = 0.0f, a1 = 0.0f, a2 = 0.0f, a3 = 0.0f;
    if (gk + 3 < K) {
      float4 tv = *(const float4*)ap;
      a0 = tv.x; a1 = tv.y; a2 = tv.z; a3 = tv.w;
    } else {
      if (gk + 0 < K) a0 = ap[0];
      if (gk + 1 < K) a1 = ap[1];
      if (gk + 2 < K) a2 = ap[2];
    }
    __syncthreads();
    lds_a[(kq + 0) * 36 + row] = a0;
    lds_a[(kq + 1) * 36 + row] = a1;
    lds_a[(kq + 2) * 36 + row] = a2;
    lds_a[(kq + 3) * 36 + row] = a3;
    __syncthreads();
    int kmax = K - k0;
    if (kmax > 32) kmax = 32;
    if (kmax == 32) {
#pragma unroll
      for (int kk = 0; kk < 32; ++kk) {
        float w = W[(size_t)(k0 + kk) * Cout + co];
        const float* ar = &lds_a[kk * 36 + rg * 8];
        float4 x0 = *(const float4*)ar;
        float4 x1 = *(const float4*)(ar + 4);
        acc[0] += x0.x * w; acc[1] += x0.y * w; acc[2] += x0.z * w; acc[3] += x0.w * w;
        acc[4] += x1.x * w; acc[5] += x1.y * w; acc[6] += x1.z * w; acc[7] += x1.w * w;
      }
    } else {
      for (int kk = 0; kk < kmax; ++kk) {
        float w = W[(size_t)(k0 + kk) * Cout + co];
        const float* ar = &lds_a[kk * 36 + rg * 8];
        float4 x0 = *(const float4*)ar;
        float4 x1 = *(const float4*)(ar + 4);
        acc[0] += x0.x * w; acc[1] += x0.y * w; acc[2] += x0.z * w; acc[3] += x0.w * w;
        acc[4] += x1.x * w; acc[5] += x1.y * w; acc[6] += x1.z * w; acc[7] += x1.w * w;
      }
    }
  }
  float bb = bias ? bias[co] : 0.0f;
#pragma unroll
  for (int j = 0; j < 8; ++j) {
    int r = r0 + rg * 8 + j;
    float vv = acc[j] + bb;
    if (i3) {
      int bidx = r / Nd;
      const int* ii = i3 + (size_t)r * 3;
      const float* ww = w3 + (size_t)r * 3;
      const float* zb = Zb + (size_t)bidx * Ns * Cout;
      vv += ww[0] * zb[(size_t)ii[0] * Cout + co] + ww[1] * zb[(size_t)ii[1] * Cout + co] +
            ww[2] * zb[(size_t)ii[2] * Cout + co];
    }
    if (relu) vv = fmaxf(vv, 0.0f);
    out[(size_t)r * Cout + co] = vv;
  }
}

__global__ __launch_bounds__(256) void gemm_kernel(const float* __restrict__ Amat,
                                                   const float* __restrict__ W,
                                                   const float* __restrict__ bias,
                                                   float* __restrict__ out, int K, int Cout,
                                                   int relu, const int* __restrict__ i3,
                                                   const float* __restrict__ w3,
                                                   const float* __restrict__ Zb, int Nd,
                                                   int Ns) {
  __shared__ float lds_a[32 * 36];
  gemm_body(Amat, W, bias, out, K, Cout, relu, i3, w3, Zb, Nd, Ns, lds_a);
}

// q/k/v in one launch (blockIdx.z selects the weight/output pair)
__global__ __launch_bounds__(256) void gemm_qkv_kernel(
    const float* __restrict__ Amat, const float* __restrict__ Wq,
    const float* __restrict__ Wk, const float* __restrict__ Wv, float* __restrict__ oq,
    float* __restrict__ ok, float* __restrict__ ov, int K, int Cout) {
  __shared__ float lds_a[32 * 36];
  const float* W = blockIdx.z == 0 ? Wq : (blockIdx.z == 1 ? Wk : Wv);
  float* o = blockIdx.z == 0 ? oq : (blockIdx.z == 1 ? ok : ov);
  gemm_body(Amat, W, nullptr, o, K, Cout, 0, nullptr, nullptr, nullptr, 0, 0, lds_a);
}

// ---------------------------------------------------------------------------
// Self-attention mix: out[n] = softmax(q[n]·k^T) @ v + fea[n]. Block per (b,n).
// ---------------------------------------------------------------------------
__global__ __launch_bounds__(128) void attn_kernel(const float* __restrict__ q,
                                                   const float* __restrict__ k,
                                                   const float* __restrict__ v,
                                                   const float* __restrict__ fea,
                                                   float* __restrict__ out, int N, int C) {
  __shared__ float sa[128];
  __shared__ float sb[128];
  int b = blockIdx.y, n = blockIdx.x, t = threadIdx.x;
  const float* qn = q + ((size_t)b * N + n) * C;
  if (t < N) {
    const float* km = k + ((size_t)b * N + t) * C;
    float acc = 0.0f;
    for (int c = 0; c < C; ++c) acc += qn[c] * km[c];
    sa[t] = acc;
  }
  __syncthreads();
  float mx = -3.0e38f;
  for (int i = 0; i < N; ++i) mx = fmaxf(mx, sa[i]);
  if (t < N) sb[t] = expf(sa[t] - mx);
  __syncthreads();
  float sum = 0.0f;
  for (int i = 0; i < N; ++i) sum += sb[i];
  size_t rowo = ((size_t)b * N + n) * C;
  for (int c = t; c < C; c += 128) {
    float acc = 0.0f;
    for (int m = 0; m < N; ++m) acc += sb[m] * v[((size_t)b * N + m) * C + c];
    out[rowo + c] = acc / sum + fea[rowo + c];
  }
}

// ---------------------------------------------------------------------------
// 3-NN inverse-distance weights (pdist2 form, stable top-3).
// ---------------------------------------------------------------------------
__global__ __launch_bounds__(256) void interp3_kernel(const float* __restrict__ xd,
                                                      const float* __restrict__ xs, int Nd,
                                                      int Ns, int* __restrict__ idx3,
                                                      float* __restrict__ w3, int total) {
#pragma clang fp contract(off)
  int gid = blockIdx.x * 256 + threadIdx.x;
  if (gid >= total) return;
  int b = gid / Nd;
  const float* xb = xs + (size_t)b * Ns * 3;
  float qx = xd[gid * 3 + 0], qy = xd[gid * 3 + 1], qz = xd[gid * 3 + 2];
  float qq = qx * qx + qy * qy + qz * qz;
  float v0 = 3.0e38f, v1 = 3.0e38f, v2 = 3.0e38f;
  int i0 = 0, i1 = 0, i2 = 0;
  for (int m = 0; m < Ns; ++m) {
    float cx = xb[m * 3 + 0], cy = xb[m * 3 + 1], cz = xb[m * 3 + 2];
    float cc = cx * cx + cy * cy + cz * cz;
    float ab = qx * cx + qy * cy + qz * cz;
    float d2 = fmaxf(qq + cc - 2.0f * ab, 0.0f);
    if (d2 < v2) {
      if (d2 < v0) { v2 = v1; i2 = i1; v1 = v0; i1 = i0; v0 = d2; i0 = m; }
      else if (d2 < v1) { v2 = v1; i2 = i1; v1 = d2; i1 = m; }
      else { v2 = d2; i2 = m; }
    }
  }
  float w0 = 1.0f / fmaxf(v0, 1e-10f);
  float w1 = 1.0f / fmaxf(v1, 1e-10f);
  float w2 = 1.0f / fmaxf(v2, 1e-10f);
  float s = w0 + w1 + w2;
  idx3[gid * 3 + 0] = i0; idx3[gid * 3 + 1] = i1; idx3[gid * 3 + 2] = i2;
  w3[gid * 3 + 0] = w0 / s; w3[gid * 3 + 1] = w1 / s; w3[gid * 3 + 2] = w2 / s;
}

// ---------------------------------------------------------------------------
// Final classifier, writes transposed (B, 13, N).
// ---------------------------------------------------------------------------
__global__ __launch_bounds__(256) void final_kernel(const float* __restrict__ fea,
                                                    const float* __restrict__ Wf,
                                                    const float* __restrict__ bfv,
                                                    float* __restrict__ out, int N) {
  int n = blockIdx.x * 256 + threadIdx.x;
  int c = blockIdx.y;
  int b = blockIdx.z;
  const float* fr = fea + ((size_t)b * N + n) * 128;
  float acc = 0.0f;
#pragma unroll 8
  for (int k = 0; k < 128; ++k) acc += fr[k] * Wf[k * 13 + c];
  out[((size_t)b * 13 + c) * N + n] = acc + bfv[c];
}

// ---------------------------------------------------------------------------
extern "C" void kernel_launch(void* const* d_in, const int* in_sizes, int n_in,
                              void* d_out, int out_size, void* d_ws, size_t ws_size,
                              hipStream_t stream) {
  (void)in_sizes; (void)n_in; (void)out_size; (void)ws_size;
  const float* xyz = (const float*)d_in[0];
  const float* W[7]; const float* bi[7]; const float* A[7];
  for (int i = 0; i < 7; ++i) {
    W[i] = (const float*)d_in[1 + 3 * i];
    bi[i] = (const float*)d_in[2 + 3 * i];
    A[i] = (const float*)d_in[3 + 3 * i];
  }
  const float* Wq1 = (const float*)d_in[22];
  const float* Wk1 = (const float*)d_in[23];
  const float* Wv1 = (const float*)d_in[24];
  const float* Wq2 = (const float*)d_in[25];
  const float* Wk2 = (const float*)d_in[26];
  const float* Wv2 = (const float*)d_in[27];
  const float* Wq3 = (const float*)d_in[28];
  const float* Wk3 = (const float*)d_in[29];
  const float* Wv3 = (const float*)d_in[30];
  const float* Wf = (const float*)d_in[31];
  const float* bf = (const float*)d_in[32];
  float* out = (float*)d_out;

  const int B = NBATCH, N0 = 4096, N1 = 512, N2 = 128, N3 = 64;
  char* base = (char*)d_ws;
  size_t off = 0;
  auto alloc = [&](size_t bytes) -> void* {
    void* p = base + off;
    off += (bytes + 255) & ~(size_t)255;
    return p;
  };
  int* idxK0 = (int*)alloc((size_t)B * N0 * 16 * 4);
  int* idxK1 = (int*)alloc((size_t)B * N1 * 16 * 4);
  int* idxK2 = (int*)alloc((size_t)B * N2 * 16 * 4);
  int* idxK3 = (int*)alloc((size_t)B * N3 * 16 * 4);
  int* idx1 = (int*)alloc((size_t)B * N1 * 4);
  int* idx2 = (int*)alloc((size_t)B * N2 * 4);
  int* idx3 = (int*)alloc((size_t)B * N3 * 4);
  float* xyz1 = (float*)alloc((size_t)B * N1 * 3 * 4);
  float* xyz2 = (float*)alloc((size_t)B * N2 * 3 * 4);
  float* xyz3 = (float*)alloc((size_t)B * N3 * 3 * 4);
  float* fea0 = (float*)alloc((size_t)B * N0 * 64 * 4);
  float* fea1in = (float*)alloc((size_t)B * N1 * 64 * 4);
  float* fea1 = (float*)alloc((size_t)B * N1 * 128 * 4);
  float* fea1b = (float*)alloc((size_t)B * N1 * 256 * 4);
  float* fea2in = (float*)alloc((size_t)B * N2 * 128 * 4);
  float* fea2a = (float*)alloc((size_t)B * N2 * 256 * 4);
  float* fea2b = (float*)alloc((size_t)B * N2 * 256 * 4);
  float* fea2c = (float*)alloc((size_t)B * N2 * 256 * 4);
  float* fea2d = (float*)alloc((size_t)B * N2 * 256 * 4);
  float* fea3in = (float*)alloc((size_t)B * N3 * 256 * 4);
  float* fea3a = (float*)alloc((size_t)B * N3 * 512 * 4);
  float* fea3b = (float*)alloc((size_t)B * N3 * 512 * 4);
  float* qb = (float*)alloc((size_t)B * 32768 * 4);
  float* kb = (float*)alloc((size_t)B * 32768 * 4);
  float* vb = (float*)alloc((size_t)B * 32768 * 4);
  int* idxI2 = (int*)alloc((size_t)B * N2 * 3 * 4);
  float* wI2 = (float*)alloc((size_t)B * N2 * 3 * 4);
  int* idxI1 = (int*)alloc((size_t)B * N1 * 3 * 4);
  float* wI1 = (float*)alloc((size_t)B * N1 * 3 * 4);
  int* idxI0 = (int*)alloc((size_t)B * N0 * 3 * 4);
  float* wI0 = (float*)alloc((size_t)B * N0 * 3 * 4);
  float* Zb4 = (float*)alloc((size_t)B * N3 * 256 * 4);
  float* Zb5 = (float*)alloc((size_t)B * N2 * 256 * 4);
  float* Zb6 = (float*)alloc((size_t)B * N1 * 128 * 4);
  float* Y4 = (float*)alloc((size_t)B * N2 * 256 * 4);
  float* Y5 = (float*)alloc((size_t)B * N1 * 256 * 4);
  float* Y6 = (float*)alloc((size_t)B * N0 * 128 * 4);
  float* feaL = (float*)alloc((size_t)B * N0 * 128 * 4);
  float* wfb = (float*)alloc((size_t)B * N0 * 320 * 4);

  float r2_0 = (float)(0.06 * 0.06);
  float r2_1 = (float)(0.12 * 0.12);
  float r2_2 = (float)(0.3 * 0.3);
  float r2_3 = (float)(0.5 * 0.5);

  // ---- Layer 0: lae_conv(xyz, xyz, W0) radius 0.06 -> fea0 (B,4096,64)
  knn16_wave<<<B * N0, 64, 0, stream>>>(xyz, N0, r2_0, idxK0);
  gatherweight_kernel<<<B * N0, 64, 0, stream>>>(xyz, xyz, idxK0, A[0], wfb, N0, 3);
  gemm_kernel<<<dim3(1, B * N0 / 32), 256, 0, stream>>>(wfb, W[0], bi[0], fea0, 3, 64, 1,
                                                        nullptr, nullptr, nullptr, 0, 0);

  // ---- FPS 4096 -> 512 (+ gather fea0 -> fea1in)
  fps_kernel<256, 16, 4096, 6><<<B, 256, 0, stream>>>(xyz, N0, N1, idx1, xyz1, fea0, fea1in);
  // ---- Layer 1: radius 0.12 -> fea1 (B,512,128)
  knn16_wave<<<B * N1, 64, 0, stream>>>(xyz1, N1, r2_1, idxK1);
  gatherweight_kernel<<<B * N1, 64, 0, stream>>>(xyz1, fea1in, idxK1, A[1], wfb, N1, 64);
  gemm_kernel<<<dim3(2, B * N1 / 32), 256, 0, stream>>>(wfb, W[1], bi[1], fea1, 64, 128, 1,
                                                        nullptr, nullptr, nullptr, 0, 0);

  // ---- FPS 512 -> 128 (+ gather fea1 -> fea2in)
  fps_kernel<256, 2, 512, 7><<<B, 256, 0, stream>>>(xyz1, N1, N2, idx2, xyz2, fea1, fea2in);
  // ---- Layer 2: radius 0.3 -> fea2a (B,128,256), then self-attn 1
  knn16_wave<<<B * N2, 64, 0, stream>>>(xyz2, N2, r2_2, idxK2);
  gatherweight_kernel<<<B * N2, 64, 0, stream>>>(xyz2, fea2in, idxK2, A[2], wfb, N2, 128);
  gemm_kernel<<<dim3(4, B * N2 / 32), 256, 0, stream>>>(wfb, W[2], bi[2], fea2a, 128, 256, 1,
                                                        nullptr, nullptr, nullptr, 0, 0);
  gemm_qkv_kernel<<<dim3(4, B * N2 / 32, 3), 256, 0, stream>>>(fea2a, Wq1, Wk1, Wv1, qb, kb,
                                                               vb, 256, 256);
  attn_kernel<<<dim3(N2, B), 128, 0, stream>>>(qb, kb, vb, fea2a, fea2b, N2, 256);

  // ---- FPS 128 -> 64 (+ gather fea2b -> fea3in)
  fps_kernel<64, 2, 128, 8><<<B, 64, 0, stream>>>(xyz2, N2, N3, idx3, xyz3, fea2b, fea3in);
  // ---- Layer 3: radius 0.5 -> fea3a (B,64,512), then self-attn 2
  knn16_wave<<<B * N3, 64, 0, stream>>>(xyz3, N3, r2_3, idxK3);
  gatherweight_kernel<<<B * N3, 64, 0, stream>>>(xyz3, fea3in, idxK3, A[3], wfb, N3, 256);
  gemm_kernel<<<dim3(8, B * N3 / 32), 256, 0, stream>>>(wfb, W[3], bi[3], fea3a, 256, 512, 1,
                                                        nullptr, nullptr, nullptr, 0, 0);
  gemm_qkv_kernel<<<dim3(8, B * N3 / 32, 3), 256, 0, stream>>>(fea3a, Wq2, Wk2, Wv2, qb, kb,
                                                               vb, 512, 512);
  attn_kernel<<<dim3(N3, B), 128, 0, stream>>>(qb, kb, vb, fea3a, fea3b, N3, 512);

  // ---- L4: Y4 = fea2b@W4a + interp(fea3b@W4b); gw_post -> fea2c; attn 3
  interp3_kernel<<<B * N2 / 256, 256, 0, stream>>>(xyz2, xyz3, N2, N3, idxI2, wI2, B * N2);
  gemm_kernel<<<dim3(4, B * N3 / 32), 256, 0, stream>>>(fea3b, W[4] + 256 * 256, nullptr, Zb4,
                                                        512, 256, 0, nullptr, nullptr,
                                                        nullptr, 0, 0);
  gemm_kernel<<<dim3(4, B * N2 / 32), 256, 0, stream>>>(fea2b, W[4], nullptr, Y4, 256, 256, 0,
                                                        idxI2, wI2, Zb4, N2, N3);
  gwpost_kernel<<<B * N2, 64, 0, stream>>>(xyz2, Y4, idxK2, A[4], bi[4], fea2c, N2, 256);
  gemm_qkv_kernel<<<dim3(4, B * N2 / 32, 3), 256, 0, stream>>>(fea2c, Wq3, Wk3, Wv3, qb, kb,
                                                               vb, 256, 256);
  attn_kernel<<<dim3(N2, B), 128, 0, stream>>>(qb, kb, vb, fea2c, fea2d, N2, 256);

  // ---- L5: Y5 = fea1@W5a + interp(fea2d@W5b); gw_post -> fea1b
  interp3_kernel<<<B * N1 / 256, 256, 0, stream>>>(xyz1, xyz2, N1, N2, idxI1, wI1, B * N1);
  gemm_kernel<<<dim3(4, B * N2 / 32), 256, 0, stream>>>(fea2d, W[5] + 128 * 256, nullptr, Zb5,
                                                        256, 256, 0, nullptr, nullptr,
                                                        nullptr, 0, 0);
  gemm_kernel<<<dim3(4, B * N1 / 32), 256, 0, stream>>>(fea1, W[5], nullptr, Y5, 128, 256, 0,
                                                        idxI1, wI1, Zb5, N1, N2);
  gwpost_kernel<<<B * N1, 64, 0, stream>>>(xyz1, Y5, idxK1, A[5], bi[5], fea1b, N1, 256);

  // ---- L6: Y6 = fea0@W6a + interp(fea1b@W6b); gw_post -> feaL
  interp3_kernel<<<B * N0 / 256, 256, 0, stream>>>(xyz, xyz1, N0, N1, idxI0, wI0, B * N0);
  gemm_kernel<<<dim3(2, B * N1 / 32), 256, 0, stream>>>(fea1b, W[6] + 64 * 128, nullptr, Zb6,
                                                        256, 128, 0, nullptr, nullptr,
                                                        nullptr, 0, 0);
  gemm_kernel<<<dim3(2, B * N0 / 32), 256, 0, stream>>>(fea0, W[6], nullptr, Y6, 64, 128, 0,
                                                        idxI0, wI0, Zb6, N0, N1);
  gwpost_kernel<<<B * N0, 64, 0, stream>>>(xyz, Y6, idxK0, A[6], bi[6], feaL, N0, 128);

  // ---- Final classifier -> out (B,13,4096)
  final_kernel<<<dim3(N0 / 256, 13, B), 256, 0, stream>>>(feaL, Wf, bf, out, N0);
}

// Round 5
// 1312.567 us; speedup vs baseline: 2.7713x; 1.0751x over previous
//
#include <hip/hip_runtime.h>
#include <math.h>

#define NBATCH 4

// branchless ascending compare-swap on u64 keys
#define CSWAP(a, b)                                          \
  {                                                          \
    unsigned long long _mn = (b < a) ? b : a;                \
    unsigned long long _mx = (b < a) ? a : b;                \
    a = _mn;                                                 \
    b = _mx;                                                 \
  }

// ---------------------------------------------------------------------------
// Shared kNN-16 top-16 search (per-wave). Key = (d2_bits<<32)|idx == exact
// (d2, idx) lexicographic order, matching jax.lax.top_k stable tie-break.
// Leaves winner r in outk of lane r (r<16) and all 16 winners in win[16].
// ---------------------------------------------------------------------------
__device__ __forceinline__ void knn16_search(const float* __restrict__ xb, int N, int n,
                                             int lane, unsigned long long* lists,
                                             unsigned long long* win,
                                             unsigned long long& outk) {
  float qx = xb[n * 3 + 0], qy = xb[n * 3 + 1], qz = xb[n * 3 + 2];
  float qq = qx * qx + qy * qy + qz * qz;
  const unsigned long long SENT = ((unsigned long long)0x7F800000u << 32) | (unsigned)lane;
  unsigned long long k0 = SENT, k1 = SENT, k2 = SENT, k3 = SENT, k4 = SENT, k5 = SENT,
                     k6 = SENT, k7 = SENT, k8 = SENT, k9 = SENT, k10 = SENT, k11 = SENT,
                     k12 = SENT, k13 = SENT, k14 = SENT, k15 = SENT;
  int rounds = N >> 6;
  for (int j = 0; j < rounds; ++j) {
    int m = j * 64 + lane;
    float cx = xb[m * 3 + 0], cy = xb[m * 3 + 1], cz = xb[m * 3 + 2];
    float cc = cx * cx + cy * cy + cz * cz;
    float ab = qx * cx + qy * cy + qz * cz;
    float d2 = fmaxf(qq + cc - 2.0f * ab, 0.0f);
    unsigned long long key = ((unsigned long long)__float_as_uint(d2) << 32) | (unsigned)m;
    if (key < k15) {
      k15 = key;
      CSWAP(k14, k15); CSWAP(k13, k14); CSWAP(k12, k13); CSWAP(k11, k12);
      CSWAP(k10, k11); CSWAP(k9, k10);  CSWAP(k8, k9);   CSWAP(k7, k8);
      CSWAP(k6, k7);   CSWAP(k5, k6);   CSWAP(k4, k5);   CSWAP(k3, k4);
      CSWAP(k2, k3);   CSWAP(k1, k2);   CSWAP(k0, k1);
    }
  }
  lists[0 * 64 + lane] = k0;   lists[1 * 64 + lane] = k1;
  lists[2 * 64 + lane] = k2;   lists[3 * 64 + lane] = k3;
  lists[4 * 64 + lane] = k4;   lists[5 * 64 + lane] = k5;
  lists[6 * 64 + lane] = k6;   lists[7 * 64 + lane] = k7;
  lists[8 * 64 + lane] = k8;   lists[9 * 64 + lane] = k9;
  lists[10 * 64 + lane] = k10; lists[11 * 64 + lane] = k11;
  lists[12 * 64 + lane] = k12; lists[13 * 64 + lane] = k13;
  lists[14 * 64 + lane] = k14; lists[15 * 64 + lane] = k15;
  __syncthreads();
  int head = 0;
  outk = 0;
  for (int r = 0; r < 16; ++r) {
    unsigned long long h = lists[head * 64 + lane];
    unsigned long long mn = h;
#pragma unroll
    for (int mask = 32; mask; mask >>= 1) {
      unsigned long long o = __shfl_xor(mn, mask);
      if (o < mn) mn = o;
    }
    if (h == mn) head++;
    if (lane == r) outk = mn;
  }
  if (lane < 16) win[lane] = outk;
  __syncthreads();
}

// softmax alphas over 16 neighbor coordinate offsets (all lanes redundant)
__device__ __forceinline__ void lae_alphas(const float* __restrict__ xb, int n,
                                           const int* idv, const float* __restrict__ A,
                                           float* al) {
  float ax = A[0], ay = A[1], az = A[2];
  float qx = xb[n * 3 + 0], qy = xb[n * 3 + 1], qz = xb[n * 3 + 2];
  float mx = -3.0e38f;
#pragma unroll
  for (int k = 0; k < 16; ++k) {
    float gx = xb[idv[k] * 3 + 0] - qx;
    float gy = xb[idv[k] * 3 + 1] - qy;
    float gz = xb[idv[k] * 3 + 2] - qz;
    float s = gx * ax + gy * ay + gz * az;
    al[k] = s;
    mx = fmaxf(mx, s);
  }
  float sum = 0.0f;
#pragma unroll
  for (int k = 0; k < 16; ++k) { al[k] = expf(al[k] - mx); sum += al[k]; }
#pragma unroll
  for (int k = 0; k < 16; ++k) al[k] = al[k] / sum;
}

// ---------------------------------------------------------------------------
// L0 fused: kNN + gather-weight (fea == xyz, Cin=3) + K=3 mini-GEMM.
// fea0[n][c] = relu(sum_d (sum_k al_k * xyz[id_k][d]) * W0[d][c] + b0[c])
// ---------------------------------------------------------------------------
__global__ __launch_bounds__(64) void knn_gw0_kernel(const float* __restrict__ xyz, int N,
                                                     float r2, int* __restrict__ idxK,
                                                     const float* __restrict__ W0,
                                                     const float* __restrict__ b0,
                                                     const float* __restrict__ A0,
                                                     float* __restrict__ fea0) {
#pragma clang fp contract(off)
  int bn = blockIdx.x;
  int b = bn / N, n = bn - b * N;
  int lane = threadIdx.x;
  const float* xb = xyz + (size_t)b * N * 3;
  __shared__ unsigned long long lists[16 * 64];
  __shared__ unsigned long long win[16];
  unsigned long long outk;
  knn16_search(xb, N, n, lane, lists, win, outk);
  if (lane < 16) {
    float d2 = __uint_as_float((unsigned)(outk >> 32));
    int m = (int)(outk & 0xFFFFFFFFu);
    idxK[(size_t)bn * 16 + lane] = (d2 <= r2) ? m : n;
  }
  int idv[16];
#pragma unroll
  for (int k = 0; k < 16; ++k) {
    unsigned long long kk = win[k];
    float d2 = __uint_as_float((unsigned)(kk >> 32));
    idv[k] = (d2 <= r2) ? (int)(kk & 0xFFFFFFFFu) : n;
  }
  float al[16];
  lae_alphas(xb, n, idv, A0, al);
  float w0 = 0.0f, w1 = 0.0f, w2 = 0.0f;
#pragma unroll
  for (int k = 0; k < 16; ++k) {
    w0 += al[k] * xb[idv[k] * 3 + 0];
    w1 += al[k] * xb[idv[k] * 3 + 1];
    w2 += al[k] * xb[idv[k] * 3 + 2];
  }
  float v = w0 * W0[0 * 64 + lane] + w1 * W0[1 * 64 + lane] + w2 * W0[2 * 64 + lane] +
            b0[lane];
  fea0[(size_t)bn * 64 + lane] = fmaxf(v, 0.0f);
}

// ---------------------------------------------------------------------------
// Generic fused kNN + gather-weight with source-row indirection:
// wf[n][c] = sum_k al_k * fea_src[srcmap[id_k]][c]   (GEMM applied after)
// ---------------------------------------------------------------------------
__global__ __launch_bounds__(64) void knn_gw_kernel(const float* __restrict__ xyz_s, int N,
                                                    float r2, int* __restrict__ idxK,
                                                    const int* __restrict__ srcmap,
                                                    const float* __restrict__ fea_src,
                                                    int Nsrc, int Cin,
                                                    const float* __restrict__ A,
                                                    float* __restrict__ wf) {
#pragma clang fp contract(off)
  int bn = blockIdx.x;
  int b = bn / N, n = bn - b * N;
  int lane = threadIdx.x;
  const float* xb = xyz_s + (size_t)b * N * 3;
  __shared__ unsigned long long lists[16 * 64];
  __shared__ unsigned long long win[16];
  unsigned long long outk;
  knn16_search(xb, N, n, lane, lists, win, outk);
  if (lane < 16) {
    float d2 = __uint_as_float((unsigned)(outk >> 32));
    int m = (int)(outk & 0xFFFFFFFFu);
    idxK[(size_t)bn * 16 + lane] = (d2 <= r2) ? m : n;
  }
  int idv[16];
#pragma unroll
  for (int k = 0; k < 16; ++k) {
    unsigned long long kk = win[k];
    float d2 = __uint_as_float((unsigned)(kk >> 32));
    idv[k] = (d2 <= r2) ? (int)(kk & 0xFFFFFFFFu) : n;
  }
  float al[16];
  lae_alphas(xb, n, idv, A, al);
  int row[16];
  const int* sm = srcmap + (size_t)b * N;
#pragma unroll
  for (int k = 0; k < 16; ++k) row[k] = sm[idv[k]];
  const float* fb = fea_src + (size_t)b * Nsrc * Cin;
  float* wo = wf + (size_t)bn * Cin;
  for (int c = lane; c < Cin; c += 64) {
    float acc = 0.0f;
#pragma unroll
    for (int k = 0; k < 16; ++k) acc += al[k] * fb[(size_t)row[k] * Cin + c];
    wo[c] = acc;
  }
}

// ---------------------------------------------------------------------------
// Furthest point sampling (pure). Tree-reduced u64 keys (dist_bits<<32 | ~pt).
// One barrier/iter for NT>64; zero barriers for NT==64.
// ---------------------------------------------------------------------------
template <int NT, int PTS, int NPT>
__global__ __launch_bounds__(NT) void fps_kernel(const float* __restrict__ xyz, int N,
                                                 int npoint, int* __restrict__ idx_out,
                                                 float* __restrict__ xyz_out) {
#pragma clang fp contract(off)
  constexpr int NW = NT / 64;
  int b = blockIdx.x, tid = threadIdx.x;
  const float* xb = xyz + (size_t)b * N * 3;
  __shared__ float sxyz[3 * NPT];
  __shared__ int hist[512];
  __shared__ unsigned long long rk[2][NW > 1 ? NW : 1];
  for (int i = tid; i < 3 * N; i += NT) sxyz[i] = xb[i];
  float px[PTS], py[PTS], pz[PTS], dist[PTS];
#pragma unroll
  for (int p = 0; p < PTS; ++p) {
    int pt = tid + p * NT;
    px[p] = xb[pt * 3 + 0];
    py[p] = xb[pt * 3 + 1];
    pz[p] = xb[pt * 3 + 2];
    dist[p] = 1e10f;
  }
  __syncthreads();
  int far = 0;
  float cx = sxyz[0], cy = sxyz[1], cz = sxyz[2];
  for (int t = 0; t < npoint; ++t) {
    if (tid == 0) hist[t] = far;
    unsigned long long K[PTS];
#pragma unroll
    for (int p = 0; p < PTS; ++p) {
      float dx = px[p] - cx, dy = py[p] - cy, dz = pz[p] - cz;
      float d = dx * dx + dy * dy + dz * dz;
      float nd = fminf(dist[p], d);
      dist[p] = nd;
      K[p] = ((unsigned long long)__float_as_uint(nd) << 32) | (unsigned)(~(tid + p * NT));
    }
#pragma unroll
    for (int s = PTS / 2; s >= 1; s >>= 1) {
#pragma unroll
      for (int i = 0; i < s; ++i)
        if (K[i + s] > K[i]) K[i] = K[i + s];
    }
    unsigned long long key = K[0];
#pragma unroll
    for (int m = 32; m; m >>= 1) {
      unsigned long long o = __shfl_xor(key, m);
      if (o > key) key = o;
    }
    if constexpr (NW > 1) {
      int par = t & 1;
      if ((tid & 63) == 0) rk[par][tid >> 6] = key;
      __syncthreads();
      key = rk[par][0];
#pragma unroll
      for (int w = 1; w < NW; ++w)
        if (rk[par][w] > key) key = rk[par][w];
    }
    far = (int)(~(unsigned)key);
    cx = sxyz[3 * far + 0];
    cy = sxyz[3 * far + 1];
    cz = sxyz[3 * far + 2];
  }
  __syncthreads();
  for (int s = tid; s < npoint; s += NT) {
    int idp = hist[s];
    idx_out[(size_t)b * npoint + s] = idp;
    xyz_out[((size_t)b * npoint + s) * 3 + 0] = sxyz[3 * idp + 0];
    xyz_out[((size_t)b * npoint + s) * 3 + 1] = sxyz[3 * idp + 1];
    xyz_out[((size_t)b * npoint + s) * 3 + 2] = sxyz[3 * idp + 2];
  }
}

// ---------------------------------------------------------------------------
// LAE gather-weight (POST-GEMM): out = relu(sum_k al_k Y[idx_k][c] + b[c])
// ---------------------------------------------------------------------------
__global__ __launch_bounds__(64) void gwpost_kernel(const float* __restrict__ xyz,
                                                    const float* __restrict__ Y,
                                                    const int* __restrict__ knn,
                                                    const float* __restrict__ A,
                                                    const float* __restrict__ bias,
                                                    float* __restrict__ out, int N, int C) {
  int bn = blockIdx.x;
  int b = bn / N, n = bn - b * N;
  int lane = threadIdx.x;
  const float* xb = xyz + (size_t)b * N * 3;
  const int* kn = knn + (size_t)bn * 16;
  int idv[16];
#pragma unroll
  for (int k = 0; k < 16; ++k) idv[k] = kn[k];
  float al[16];
  lae_alphas(xb, n, idv, A, al);
  const float* Yb = Y + (size_t)b * N * C;
  float* wo = out + (size_t)bn * C;
  for (int c = lane; c < C; c += 64) {
    float acc = 0.0f;
#pragma unroll
    for (int k = 0; k < 16; ++k) acc += al[k] * Yb[(size_t)idv[k] * C + c];
    wo[c] = fmaxf(acc + bias[c], 0.0f);
  }
}

// ---------------------------------------------------------------------------
// L6 gwpost fused with final classifier: feaL never materialized.
// out[b][cls][n] = sum_c feaL[n][c] * Wf[c][cls] + bf[cls], C=128 fixed.
// ---------------------------------------------------------------------------
__global__ __launch_bounds__(64) void gwpost_final_kernel(
    const float* __restrict__ xyz, const float* __restrict__ Y,
    const int* __restrict__ knn, const float* __restrict__ A,
    const float* __restrict__ bias, const float* __restrict__ Wf,
    const float* __restrict__ bfv, float* __restrict__ out, int N) {
  int bn = blockIdx.x;
  int b = bn / N, n = bn - b * N;
  int lane = threadIdx.x;
  const float* xb = xyz + (size_t)b * N * 3;
  const int* kn = knn + (size_t)bn * 16;
  int idv[16];
#pragma unroll
  for (int k = 0; k < 16; ++k) idv[k] = kn[k];
  float al[16];
  lae_alphas(xb, n, idv, A, al);
  const float* Yb = Y + (size_t)b * N * 128;
  float a0 = 0.0f, a1 = 0.0f;
#pragma unroll
  for (int k = 0; k < 16; ++k) {
    const float* yr = Yb + (size_t)idv[k] * 128;
    a0 += al[k] * yr[lane];
    a1 += al[k] * yr[lane + 64];
  }
  float v0 = fmaxf(a0 + bias[lane], 0.0f);
  float v1 = fmaxf(a1 + bias[lane + 64], 0.0f);
  float* ob = out + ((size_t)b * 13) * N + n;
#pragma unroll
  for (int cls = 0; cls < 13; ++cls) {
    float p = v0 * Wf[lane * 13 + cls] + v1 * Wf[(lane + 64) * 13 + cls];
#pragma unroll
    for (int m = 32; m; m >>= 1) p += __shfl_xor(p, m);
    if (lane == 0) ob[(size_t)cls * N] = p + bfv[cls];
  }
}

// ---------------------------------------------------------------------------
// Tiled fp32 GEMM body with optional fused 3-NN interp epilogue.
// ---------------------------------------------------------------------------
__device__ __forceinline__ void gemm_body(const float* __restrict__ Amat,
                                          const float* __restrict__ W,
                                          const float* __restrict__ bias,
                                          float* __restrict__ out, int K, int Cout, int relu,
                                          const int* __restrict__ i3,
                                          const float* __restrict__ w3,
                                          const float* __restrict__ Zb, int Nd, int Ns,
                                          float* lds_a) {
  int co = blockIdx.x * 64 + (threadIdx.x & 63);
  int rg = threadIdx.x >> 6;
  int r0 = blockIdx.y * 32;
  float acc[8];
#pragma unroll
  for (int j = 0; j < 8; ++j) acc[j] = 0.0f;
  for (int k0 = 0; k0 < K; k0 += 32) {
    int row = threadIdx.x >> 3;
    int kq = (threadIdx.x & 7) * 4;
    int gk = k0 + kq;
    const float* ap = Amat + (size_t)(r0 + row) * K + gk;
    float a0 = 0.0f, a1 = 0.0f, a2 = 0.0f, a3 = 0.0f;
    if (gk + 3 < K) {
      float4 tv = *(const float4*)ap;
      a0 = tv.x; a1 = tv.y; a2 = tv.z; a3 = tv.w;
    } else {
      if (gk + 0 < K) a0 = ap[0];
      if (gk + 1 < K) a1 = ap[1];
      if (gk + 2 < K) a2 = ap[2];
    }
    __syncthreads();
    lds_a[(kq + 0) * 36 + row] = a0;
    lds_a[(kq + 1) * 36 + row] = a1;
    lds_a[(kq + 2) * 36 + row] = a2;
    lds_a[(kq + 3) * 36 + row] = a3;
    __syncthreads();
    int kmax = K - k0;
    if (kmax > 32) kmax = 32;
    if (kmax == 32) {
#pragma unroll
      for (int kk = 0; kk < 32; ++kk) {
        float w = W[(size_t)(k0 + kk) * Cout + co];
        const float* ar = &lds_a[kk * 36 + rg * 8];
        float4 x0 = *(const float4*)ar;
        float4 x1 = *(const float4*)(ar + 4);
        acc[0] += x0.x * w; acc[1] += x0.y * w; acc[2] += x0.z * w; acc[3] += x0.w * w;
        acc[4] += x1.x * w; acc[5] += x1.y * w; acc[6] += x1.z * w; acc[7] += x1.w * w;
      }
    } else {
      for (int kk = 0; kk < kmax; ++kk) {
        float w = W[(size_t)(k0 + kk) * Cout + co];
        const float* ar = &lds_a[kk * 36 + rg * 8];
        float4 x0 = *(const float4*)ar;
        float4 x1 = *(const float4*)(ar + 4);
        acc[0] += x0.x * w; acc[1] += x0.y * w; acc[2] += x0.z * w; acc[3] += x0.w * w;
        acc[4] += x1.x * w; acc[5] += x1.y * w; acc[6] += x1.z * w; acc[7] += x1.w * w;
      }
    }
  }
  float bb = bias ? bias[co] : 0.0f;
#pragma unroll
  for (int j = 0; j < 8; ++j) {
    int r = r0 + rg * 8 + j;
    float vv = acc[j] + bb;
    if (i3) {
      int bidx = r / Nd;
      const int* ii = i3 + (size_t)r * 3;
      const float* ww = w3 + (size_t)r * 3;
      const float* zb = Zb + (size_t)bidx * Ns * Cout;
      vv += ww[0] * zb[(size_t)ii[0] * Cout + co] + ww[1] * zb[(size_t)ii[1] * Cout + co] +
            ww[2] * zb[(size_t)ii[2] * Cout + co];
    }
    if (relu) vv = fmaxf(vv, 0.0f);
    out[(size_t)r * Cout + co] = vv;
  }
}

__global__ __launch_bounds__(256) void gemm_kernel(const float* __restrict__ Amat,
                                                   const float* __restrict__ W,
                                                   const float* __restrict__ bias,
                                                   float* __restrict__ out, int K, int Cout,
                                                   int relu, const int* __restrict__ i3,
                                                   const float* __restrict__ w3,
                                                   const float* __restrict__ Zb, int Nd,
                                                   int Ns) {
  __shared__ float lds_a[32 * 36];
  gemm_body(Amat, W, bias, out, K, Cout, relu, i3, w3, Zb, Nd, Ns, lds_a);
}

__global__ __launch_bounds__(256) void gemm_qkv_kernel(
    const float* __restrict__ Amat, const float* __restrict__ Wq,
    const float* __restrict__ Wk, const float* __restrict__ Wv, float* __restrict__ oq,
    float* __restrict__ ok, float* __restrict__ ov, int K, int Cout) {
  __shared__ float lds_a[32 * 36];
  const float* W = blockIdx.z == 0 ? Wq : (blockIdx.z == 1 ? Wk : Wv);
  float* o = blockIdx.z == 0 ? oq : (blockIdx.z == 1 ? ok : ov);
  gemm_body(Amat, W, nullptr, o, K, Cout, 0, nullptr, nullptr, nullptr, 0, 0, lds_a);
}

// ---------------------------------------------------------------------------
// 3-NN inverse-distance body (pdist2 form, stable top-3).
// ---------------------------------------------------------------------------
__device__ __forceinline__ void interp3_body(const float* __restrict__ xd,
                                             const float* __restrict__ xs, int Nd, int Ns,
                                             int* __restrict__ idx3,
                                             float* __restrict__ w3, int gid) {
#pragma clang fp contract(off)
  int b = gid / Nd;
  const float* xb = xs + (size_t)b * Ns * 3;
  float qx = xd[gid * 3 + 0], qy = xd[gid * 3 + 1], qz = xd[gid * 3 + 2];
  float qq = qx * qx + qy * qy + qz * qz;
  float v0 = 3.0e38f, v1 = 3.0e38f, v2 = 3.0e38f;
  int i0 = 0, i1 = 0, i2 = 0;
  for (int m = 0; m < Ns; ++m) {
    float cx = xb[m * 3 + 0], cy = xb[m * 3 + 1], cz = xb[m * 3 + 2];
    float cc = cx * cx + cy * cy + cz * cz;
    float ab = qx * cx + qy * cy + qz * cz;
    float d2 = fmaxf(qq + cc - 2.0f * ab, 0.0f);
    if (d2 < v2) {
      if (d2 < v0) { v2 = v1; i2 = i1; v1 = v0; i1 = i0; v0 = d2; i0 = m; }
      else if (d2 < v1) { v2 = v1; i2 = i1; v1 = d2; i1 = m; }
      else { v2 = d2; i2 = m; }
    }
  }
  float w0 = 1.0f / fmaxf(v0, 1e-10f);
  float w1 = 1.0f / fmaxf(v1, 1e-10f);
  float w2 = 1.0f / fmaxf(v2, 1e-10f);
  float s = w0 + w1 + w2;
  idx3[gid * 3 + 0] = i0; idx3[gid * 3 + 1] = i1; idx3[gid * 3 + 2] = i2;
  w3[gid * 3 + 0] = w0 / s; w3[gid * 3 + 1] = w1 / s; w3[gid * 3 + 2] = w2 / s;
}

// Combined launch: z==0 blocks run the Zb GEMM, z==1 blocks run interp3.
__global__ __launch_bounds__(256) void zb_interp_kernel(
    const float* __restrict__ Amat, const float* __restrict__ W, float* __restrict__ Zout,
    int K, int Cout, const float* __restrict__ xd, const float* __restrict__ xs, int Nd,
    int Ns, int* __restrict__ idx3, float* __restrict__ w3, int total) {
  __shared__ float lds_a[32 * 36];
  if (blockIdx.z == 0) {
    gemm_body(Amat, W, nullptr, Zout, K, Cout, 0, nullptr, nullptr, nullptr, 0, 0, lds_a);
  } else {
    int flat = blockIdx.y * gridDim.x + blockIdx.x;
    int gid = flat * 256 + threadIdx.x;
    if (gid < total) interp3_body(xd, xs, Nd, Ns, idx3, w3, gid);
  }
}

// ---------------------------------------------------------------------------
// Self-attention mix: out[n] = softmax(q[n]·k^T) @ v + fea[n]. Block per (b,n).
// ---------------------------------------------------------------------------
__global__ __launch_bounds__(128) void attn_kernel(const float* __restrict__ q,
                                                   const float* __restrict__ k,
                                                   const float* __restrict__ v,
                                                   const float* __restrict__ fea,
                                                   float* __restrict__ out, int N, int C) {
  __shared__ float sa[128];
  __shared__ float sb[128];
  int b = blockIdx.y, n = blockIdx.x, t = threadIdx.x;
  const float* qn = q + ((size_t)b * N + n) * C;
  if (t < N) {
    const float* km = k + ((size_t)b * N + t) * C;
    float acc = 0.0f;
    for (int c = 0; c < C; ++c) acc += qn[c] * km[c];
    sa[t] = acc;
  }
  __syncthreads();
  float mx = -3.0e38f;
  for (int i = 0; i < N; ++i) mx = fmaxf(mx, sa[i]);
  if (t < N) sb[t] = expf(sa[t] - mx);
  __syncthreads();
  float sum = 0.0f;
  for (int i = 0; i < N; ++i) sum += sb[i];
  size_t rowo = ((size_t)b * N + n) * C;
  for (int c = t; c < C; c += 128) {
    float acc = 0.0f;
    for (int m = 0; m < N; ++m) acc += sb[m] * v[((size_t)b * N + m) * C + c];
    out[rowo + c] = acc / sum + fea[rowo + c];
  }
}

// ---------------------------------------------------------------------------
extern "C" void kernel_launch(void* const* d_in, const int* in_sizes, int n_in,
                              void* d_out, int out_size, void* d_ws, size_t ws_size,
                              hipStream_t stream) {
  (void)in_sizes; (void)n_in; (void)out_size; (void)ws_size;
  const float* xyz = (const float*)d_in[0];
  const float* W[7]; const float* bi[7]; const float* A[7];
  for (int i = 0; i < 7; ++i) {
    W[i] = (const float*)d_in[1 + 3 * i];
    bi[i] = (const float*)d_in[2 + 3 * i];
    A[i] = (const float*)d_in[3 + 3 * i];
  }
  const float* Wq1 = (const float*)d_in[22];
  const float* Wk1 = (const float*)d_in[23];
  const float* Wv1 = (const float*)d_in[24];
  const float* Wq2 = (const float*)d_in[25];
  const float* Wk2 = (const float*)d_in[26];
  const float* Wv2 = (const float*)d_in[27];
  const float* Wq3 = (const float*)d_in[28];
  const float* Wk3 = (const float*)d_in[29];
  const float* Wv3 = (const float*)d_in[30];
  const float* Wf = (const float*)d_in[31];
  const float* bf = (const float*)d_in[32];
  float* out = (float*)d_out;

  const int B = NBATCH, N0 = 4096, N1 = 512, N2 = 128, N3 = 64;
  char* base = (char*)d_ws;
  size_t off = 0;
  auto alloc = [&](size_t bytes) -> void* {
    void* p = base + off;
    off += (bytes + 255) & ~(size_t)255;
    return p;
  };
  int* idxK0 = (int*)alloc((size_t)B * N0 * 16 * 4);
  int* idxK1 = (int*)alloc((size_t)B * N1 * 16 * 4);
  int* idxK2 = (int*)alloc((size_t)B * N2 * 16 * 4);
  int* idxK3 = (int*)alloc((size_t)B * N3 * 16 * 4);
  int* idx1 = (int*)alloc((size_t)B * N1 * 4);
  int* idx2 = (int*)alloc((size_t)B * N2 * 4);
  int* idx3 = (int*)alloc((size_t)B * N3 * 4);
  float* xyz1 = (float*)alloc((size_t)B * N1 * 3 * 4);
  float* xyz2 = (float*)alloc((size_t)B * N2 * 3 * 4);
  float* xyz3 = (float*)alloc((size_t)B * N3 * 3 * 4);
  float* fea0 = (float*)alloc((size_t)B * N0 * 64 * 4);
  float* fea1 = (float*)alloc((size_t)B * N1 * 128 * 4);
  float* fea1b = (float*)alloc((size_t)B * N1 * 256 * 4);
  float* fea2a = (float*)alloc((size_t)B * N2 * 256 * 4);
  float* fea2b = (float*)alloc((size_t)B * N2 * 256 * 4);
  float* fea2c = (float*)alloc((size_t)B * N2 * 256 * 4);
  float* fea2d = (float*)alloc((size_t)B * N2 * 256 * 4);
  float* fea3a = (float*)alloc((size_t)B * N3 * 512 * 4);
  float* fea3b = (float*)alloc((size_t)B * N3 * 512 * 4);
  float* qb = (float*)alloc((size_t)B * 32768 * 4);
  float* kb = (float*)alloc((size_t)B * 32768 * 4);
  float* vb = (float*)alloc((size_t)B * 32768 * 4);
  int* idxI2 = (int*)alloc((size_t)B * N2 * 3 * 4);
  float* wI2 = (float*)alloc((size_t)B * N2 * 3 * 4);
  int* idxI1 = (int*)alloc((size_t)B * N1 * 3 * 4);
  float* wI1 = (float*)alloc((size_t)B * N1 * 3 * 4);
  int* idxI0 = (int*)alloc((size_t)B * N0 * 3 * 4);
  float* wI0 = (float*)alloc((size_t)B * N0 * 3 * 4);
  float* Zb4 = (float*)alloc((size_t)B * N3 * 256 * 4);
  float* Zb5 = (float*)alloc((size_t)B * N2 * 256 * 4);
  float* Zb6 = (float*)alloc((size_t)B * N1 * 128 * 4);
  float* Y4 = (float*)alloc((size_t)B * N2 * 256 * 4);
  float* Y5 = (float*)alloc((size_t)B * N1 * 256 * 4);
  float* Y6 = (float*)alloc((size_t)B * N0 * 128 * 4);
  float* wfb = (float*)alloc((size_t)B * N0 * 320 * 4);

  float r2_0 = (float)(0.06 * 0.06);
  float r2_1 = (float)(0.12 * 0.12);
  float r2_2 = (float)(0.3 * 0.3);
  float r2_3 = (float)(0.5 * 0.5);

  // ---- L0: fused knn + gatherweight + K=3 gemm -> fea0 (B,4096,64)
  knn_gw0_kernel<<<B * N0, 64, 0, stream>>>(xyz, N0, r2_0, idxK0, W[0], bi[0], A[0], fea0);

  // ---- FPS 4096 -> 512
  fps_kernel<256, 16, 4096><<<B, 256, 0, stream>>>(xyz, N0, N1, idx1, xyz1);
  // ---- L1: fused knn + gatherweight (fea0 via idx1), then gemm -> fea1
  knn_gw_kernel<<<B * N1, 64, 0, stream>>>(xyz1, N1, r2_1, idxK1, idx1, fea0, N0, 64, A[1],
                                           wfb);
  gemm_kernel<<<dim3(2, B * N1 / 32), 256, 0, stream>>>(wfb, W[1], bi[1], fea1, 64, 128, 1,
                                                        nullptr, nullptr, nullptr, 0, 0);

  // ---- FPS 512 -> 128
  fps_kernel<64, 8, 512><<<B, 64, 0, stream>>>(xyz1, N1, N2, idx2, xyz2);
  // ---- L2: fused knn + gatherweight (fea1 via idx2), gemm -> fea2a, attn1
  knn_gw_kernel<<<B * N2, 64, 0, stream>>>(xyz2, N2, r2_2, idxK2, idx2, fea1, N1, 128, A[2],
                                           wfb);
  gemm_kernel<<<dim3(4, B * N2 / 32), 256, 0, stream>>>(wfb, W[2], bi[2], fea2a, 128, 256, 1,
                                                        nullptr, nullptr, nullptr, 0, 0);
  gemm_qkv_kernel<<<dim3(4, B * N2 / 32, 3), 256, 0, stream>>>(fea2a, Wq1, Wk1, Wv1, qb, kb,
                                                               vb, 256, 256);
  attn_kernel<<<dim3(N2, B), 128, 0, stream>>>(qb, kb, vb, fea2a, fea2b, N2, 256);

  // ---- FPS 128 -> 64
  fps_kernel<64, 2, 128><<<B, 64, 0, stream>>>(xyz2, N2, N3, idx3, xyz3);
  // ---- L3: fused knn + gatherweight (fea2b via idx3), gemm -> fea3a, attn2
  knn_gw_kernel<<<B * N3, 64, 0, stream>>>(xyz3, N3, r2_3, idxK3, idx3, fea2b, N2, 256, A[3],
                                           wfb);
  gemm_kernel<<<dim3(8, B * N3 / 32), 256, 0, stream>>>(wfb, W[3], bi[3], fea3a, 256, 512, 1,
                                                        nullptr, nullptr, nullptr, 0, 0);
  gemm_qkv_kernel<<<dim3(8, B * N3 / 32, 3), 256, 0, stream>>>(fea3a, Wq2, Wk2, Wv2, qb, kb,
                                                               vb, 512, 512);
  attn_kernel<<<dim3(N3, B), 128, 0, stream>>>(qb, kb, vb, fea3a, fea3b, N3, 512);

  // ---- L4: Zb4 = fea3b@W4b (+ interp2 in same launch); Y4 = fea2b@W4a + interp
  zb_interp_kernel<<<dim3(4, B * N3 / 32, 2), 256, 0, stream>>>(
      fea3b, W[4] + 256 * 256, Zb4, 512, 256, xyz2, xyz3, N2, N3, idxI2, wI2, B * N2);
  gemm_kernel<<<dim3(4, B * N2 / 32), 256, 0, stream>>>(fea2b, W[4], nullptr, Y4, 256, 256, 0,
                                                        idxI2, wI2, Zb4, N2, N3);
  gwpost_kernel<<<B * N2, 64, 0, stream>>>(xyz2, Y4, idxK2, A[4], bi[4], fea2c, N2, 256);
  gemm_qkv_kernel<<<dim3(4, B * N2 / 32, 3), 256, 0, stream>>>(fea2c, Wq3, Wk3, Wv3, qb, kb,
                                                               vb, 256, 256);
  attn_kernel<<<dim3(N2, B), 128, 0, stream>>>(qb, kb, vb, fea2c, fea2d, N2, 256);

  // ---- L5: Zb5 = fea2d@W5b (+ interp1); Y5 = fea1@W5a + interp; gwpost
  zb_interp_kernel<<<dim3(4, B * N2 / 32, 2), 256, 0, stream>>>(
      fea2d, W[5] + 128 * 256, Zb5, 256, 256, xyz1, xyz2, N1, N2, idxI1, wI1, B * N1);
  gemm_kernel<<<dim3(4, B * N1 / 32), 256, 0, stream>>>(fea1, W[5], nullptr, Y5, 128, 256, 0,
                                                        idxI1, wI1, Zb5, N1, N2);
  gwpost_kernel<<<B * N1, 64, 0, stream>>>(xyz1, Y5, idxK1, A[5], bi[5], fea1b, N1, 256);

  // ---- L6: Zb6 = fea1b@W6b (+ interp0); Y6 = fea0@W6a + interp; gwpost+final
  zb_interp_kernel<<<dim3(2, B * N1 / 32, 2), 256, 0, stream>>>(
      fea1b, W[6] + 64 * 128, Zb6, 256, 128, xyz, xyz1, N0, N1, idxI0, wI0, B * N0);
  gemm_kernel<<<dim3(2, B * N0 / 32), 256, 0, stream>>>(fea0, W[6], nullptr, Y6, 64, 128, 0,
                                                        idxI0, wI0, Zb6, N0, N1);
  gwpost_final_kernel<<<B * N0, 64, 0, stream>>>(xyz, Y6, idxK0, A[6], bi[6], Wf, bf, out,
                                                 N0);
}

// Round 6
// 1044.519 us; speedup vs baseline: 3.4825x; 1.2566x over previous
//
#include <hip/hip_runtime.h>
#include <math.h>

#define NB 4  // batch

typedef unsigned long long u64;

// branchless ascending compare-swap on u64 keys
#define CSWAP(a, b)                                          \
  {                                                          \
    u64 _mn = (b < a) ? b : a;                               \
    u64 _mx = (b < a) ? a : b;                               \
    a = _mn;                                                 \
    b = _mx;                                                 \
  }

// ---------------------------------------------------------------------------
// kNN-16 top-16 search (per-wave). Key = (d2_bits<<32)|idx == exact (d2, idx)
// lexicographic order, matching jax.lax.top_k stable tie-break. Winners left
// in win[0..15] (ascending). lists = per-wave 1024-u64 LDS slice.
// ---------------------------------------------------------------------------
__device__ __forceinline__ void knn16_search(const float* __restrict__ xb, int N, int n,
                                             int lane, u64* lists, u64* win) {
#pragma clang fp contract(off)
  float qx = xb[n * 3 + 0], qy = xb[n * 3 + 1], qz = xb[n * 3 + 2];
  float qq = qx * qx + qy * qy + qz * qz;
  const u64 SENT = ((u64)0x7F800000u << 32) | (unsigned)lane;
  u64 k0 = SENT, k1 = SENT, k2 = SENT, k3 = SENT, k4 = SENT, k5 = SENT, k6 = SENT,
      k7 = SENT, k8 = SENT, k9 = SENT, k10 = SENT, k11 = SENT, k12 = SENT, k13 = SENT,
      k14 = SENT, k15 = SENT;
  int rounds = N >> 6;
  for (int j = 0; j < rounds; ++j) {
    int m = j * 64 + lane;
    float cx = xb[m * 3 + 0], cy = xb[m * 3 + 1], cz = xb[m * 3 + 2];
    float cc = cx * cx + cy * cy + cz * cz;
    float ab = qx * cx + qy * cy + qz * cz;
    float d2 = fmaxf(qq + cc - 2.0f * ab, 0.0f);
    u64 key = ((u64)__float_as_uint(d2) << 32) | (unsigned)m;
    if (key < k15) {
      k15 = key;
      CSWAP(k14, k15); CSWAP(k13, k14); CSWAP(k12, k13); CSWAP(k11, k12);
      CSWAP(k10, k11); CSWAP(k9, k10);  CSWAP(k8, k9);   CSWAP(k7, k8);
      CSWAP(k6, k7);   CSWAP(k5, k6);   CSWAP(k4, k5);   CSWAP(k3, k4);
      CSWAP(k2, k3);   CSWAP(k1, k2);   CSWAP(k0, k1);
    }
  }
  lists[0 * 64 + lane] = k0;   lists[1 * 64 + lane] = k1;
  lists[2 * 64 + lane] = k2;   lists[3 * 64 + lane] = k3;
  lists[4 * 64 + lane] = k4;   lists[5 * 64 + lane] = k5;
  lists[6 * 64 + lane] = k6;   lists[7 * 64 + lane] = k7;
  lists[8 * 64 + lane] = k8;   lists[9 * 64 + lane] = k9;
  lists[10 * 64 + lane] = k10; lists[11 * 64 + lane] = k11;
  lists[12 * 64 + lane] = k12; lists[13 * 64 + lane] = k13;
  lists[14 * 64 + lane] = k14; lists[15 * 64 + lane] = k15;
  __syncthreads();
  int head = 0;
  u64 outk = 0;
  for (int r = 0; r < 16; ++r) {
    u64 h = lists[head * 64 + lane];
    u64 mn = h;
#pragma unroll
    for (int mask = 32; mask; mask >>= 1) {
      u64 o = __shfl_xor(mn, mask);
      if (o < mn) mn = o;
    }
    if (h == mn) head++;
    if (lane == r) outk = mn;
  }
  if (lane < 16) win[lane] = outk;
  __syncthreads();
}

// softmax alphas over 16 neighbor coordinate offsets (all lanes redundant)
__device__ __forceinline__ void lae_alphas(const float* __restrict__ xb, int n,
                                           const int* idv, const float* __restrict__ A,
                                           float* al) {
  float ax = A[0], ay = A[1], az = A[2];
  float qx = xb[n * 3 + 0], qy = xb[n * 3 + 1], qz = xb[n * 3 + 2];
  float mx = -3.0e38f;
#pragma unroll
  for (int k = 0; k < 16; ++k) {
    float gx = xb[idv[k] * 3 + 0] - qx;
    float gy = xb[idv[k] * 3 + 1] - qy;
    float gz = xb[idv[k] * 3 + 2] - qz;
    float s = gx * ax + gy * ay + gz * az;
    al[k] = s;
    mx = fmaxf(mx, s);
  }
  float sum = 0.0f;
#pragma unroll
  for (int k = 0; k < 16; ++k) { al[k] = expf(al[k] - mx); sum += al[k]; }
#pragma unroll
  for (int k = 0; k < 16; ++k) al[k] = al[k] / sum;
}

// ---------------------------------------------------------------------------
// FPS body. Per-thread tree reduce of PTS u64 keys (dist_bits<<32 | ~pt) ->
// 4 xor-shuffle levels (1,2,4,8; DPP-friendly) -> 16-lane group winners to
// LDS (NG slots, parity double-buffered) -> scalar tree over NG slots.
// Exact (max dist, tie -> lowest pt) == jnp.argmax semantics.
// ---------------------------------------------------------------------------
template <int NT, int PTS, int NPT>
__device__ __forceinline__ void fps_body(const float* __restrict__ xyz, int N, int npoint,
                                         int* __restrict__ idx_out,
                                         float* __restrict__ xyz_out, u64* smem, int b,
                                         int tid) {
#pragma clang fp contract(off)
  constexpr int NW = NT / 64;
  constexpr int NG = NT / 16;
  u64* rk = smem;
  int* hist = (int*)(smem + 2 * NG);
  float* sxyz = (float*)(hist + 512);
  const float* xb = xyz + (size_t)b * N * 3;
  for (int i = tid; i < 3 * N; i += NT) sxyz[i] = xb[i];
  float px[PTS], py[PTS], pz[PTS], dist[PTS];
#pragma unroll
  for (int p = 0; p < PTS; ++p) {
    int pt = tid + p * NT;
    px[p] = xb[pt * 3 + 0];
    py[p] = xb[pt * 3 + 1];
    pz[p] = xb[pt * 3 + 2];
    dist[p] = 1e10f;
  }
  __syncthreads();
  int far = 0;
  float cx = sxyz[0], cy = sxyz[1], cz = sxyz[2];
  for (int t = 0; t < npoint; ++t) {
    if (tid == 0) hist[t] = far;
    u64 K[PTS];
#pragma unroll
    for (int p = 0; p < PTS; ++p) {
      float dx = px[p] - cx, dy = py[p] - cy, dz = pz[p] - cz;
      float d = dx * dx + dy * dy + dz * dz;
      float nd = fminf(dist[p], d);
      dist[p] = nd;
      K[p] = ((u64)__float_as_uint(nd) << 32) | (unsigned)(~(tid + p * NT));
    }
#pragma unroll
    for (int s = PTS / 2; s >= 1; s >>= 1) {
#pragma unroll
      for (int i = 0; i < s; ++i)
        if (K[i + s] > K[i]) K[i] = K[i + s];
    }
    u64 key = K[0];
#pragma unroll
    for (int m = 1; m <= 8; m <<= 1) {
      u64 o = __shfl_xor(key, m);
      if (o > key) key = o;
    }
    int par = (t & 1) * NG;
    if ((tid & 15) == 0) rk[par + (tid >> 4)] = key;
    if constexpr (NW > 1) __syncthreads();
    u64 kk = rk[par + 0];
#pragma unroll
    for (int g = 1; g < NG; ++g) {
      u64 o = rk[par + g];
      if (o > kk) kk = o;
    }
    far = (int)(~(unsigned)kk);
    cx = sxyz[3 * far + 0];
    cy = sxyz[3 * far + 1];
    cz = sxyz[3 * far + 2];
  }
  __syncthreads();
  for (int s = tid; s < npoint; s += NT) {
    int idp = hist[s];
    idx_out[(size_t)b * npoint + s] = idp;
    xyz_out[((size_t)b * npoint + s) * 3 + 0] = sxyz[3 * idp + 0];
    xyz_out[((size_t)b * npoint + s) * 3 + 1] = sxyz[3 * idp + 1];
    xyz_out[((size_t)b * npoint + s) * 3 + 2] = sxyz[3 * idp + 2];
  }
}

// ---------------------------------------------------------------------------
// knn_gw body: kNN + ball filter + softmax-weighted feature sum with source
// row indirection. One wave per query.
// ---------------------------------------------------------------------------
__device__ __forceinline__ void knn_gw_body(const float* __restrict__ xyz_s, int N, float r2,
                                            int* __restrict__ idxK,
                                            const int* __restrict__ srcmap,
                                            const float* __restrict__ fea_src, int Nsrc,
                                            int Cin, const float* __restrict__ A,
                                            float* __restrict__ wf, int bn, int lane,
                                            u64* lists, u64* win) {
  int b = bn / N, n = bn - b * N;
  const float* xb = xyz_s + (size_t)b * N * 3;
  knn16_search(xb, N, n, lane, lists, win);
  int idv[16];
#pragma unroll
  for (int k = 0; k < 16; ++k) {
    u64 kk = win[k];
    float d2 = __uint_as_float((unsigned)(kk >> 32));
    idv[k] = (d2 <= r2) ? (int)(kk & 0xFFFFFFFFu) : n;
  }
  if (lane < 16) idxK[(size_t)bn * 16 + lane] = idv[lane];
  float al[16];
  lae_alphas(xb, n, idv, A, al);
  int row[16];
  const int* sm = srcmap + (size_t)b * N;
#pragma unroll
  for (int k = 0; k < 16; ++k) row[k] = sm[idv[k]];
  const float* fb = fea_src + (size_t)b * Nsrc * Cin;
  float* wo = wf + (size_t)bn * Cin;
  for (int c = lane; c < Cin; c += 64) {
    float acc = 0.0f;
#pragma unroll
    for (int k = 0; k < 16; ++k) acc += al[k] * fb[(size_t)row[k] * Cin + c];
    wo[c] = acc;
  }
}

// L0 variant: fea == xyz (Cin=3) with fused K=3 mini-GEMM -> fea0 (Cout=64)
__device__ __forceinline__ void knn_gw0_body(const float* __restrict__ xyz, int N, float r2,
                                             int* __restrict__ idxK,
                                             const float* __restrict__ W0,
                                             const float* __restrict__ b0,
                                             const float* __restrict__ A0,
                                             float* __restrict__ fea0, int bn, int lane,
                                             u64* lists, u64* win) {
  int b = bn / N, n = bn - b * N;
  const float* xb = xyz + (size_t)b * N * 3;
  knn16_search(xb, N, n, lane, lists, win);
  int idv[16];
#pragma unroll
  for (int k = 0; k < 16; ++k) {
    u64 kk = win[k];
    float d2 = __uint_as_float((unsigned)(kk >> 32));
    idv[k] = (d2 <= r2) ? (int)(kk & 0xFFFFFFFFu) : n;
  }
  if (lane < 16) idxK[(size_t)bn * 16 + lane] = idv[lane];
  float al[16];
  lae_alphas(xb, n, idv, A0, al);
  float w0 = 0.0f, w1 = 0.0f, w2 = 0.0f;
#pragma unroll
  for (int k = 0; k < 16; ++k) {
    w0 += al[k] * xb[idv[k] * 3 + 0];
    w1 += al[k] * xb[idv[k] * 3 + 1];
    w2 += al[k] * xb[idv[k] * 3 + 2];
  }
  float v = w0 * W0[0 * 64 + lane] + w1 * W0[1 * 64 + lane] + w2 * W0[2 * 64 + lane] +
            b0[lane];
  fea0[(size_t)bn * 64 + lane] = fmaxf(v, 0.0f);
}

// ---------------------------------------------------------------------------
// 3-NN inverse-distance body (pdist2 form, stable top-3).
// ---------------------------------------------------------------------------
__device__ __forceinline__ void interp3_body(const float* __restrict__ xd,
                                             const float* __restrict__ xs, int Nd, int Ns,
                                             int* __restrict__ idx3, float* __restrict__ w3,
                                             int gid) {
#pragma clang fp contract(off)
  int b = gid / Nd;
  const float* xb = xs + (size_t)b * Ns * 3;
  float qx = xd[gid * 3 + 0], qy = xd[gid * 3 + 1], qz = xd[gid * 3 + 2];
  float qq = qx * qx + qy * qy + qz * qz;
  float v0 = 3.0e38f, v1 = 3.0e38f, v2 = 3.0e38f;
  int i0 = 0, i1 = 0, i2 = 0;
  for (int m = 0; m < Ns; ++m) {
    float cx = xb[m * 3 + 0], cy = xb[m * 3 + 1], cz = xb[m * 3 + 2];
    float cc = cx * cx + cy * cy + cz * cz;
    float ab = qx * cx + qy * cy + qz * cz;
    float d2 = fmaxf(qq + cc - 2.0f * ab, 0.0f);
    if (d2 < v2) {
      if (d2 < v0) { v2 = v1; i2 = i1; v1 = v0; i1 = i0; v0 = d2; i0 = m; }
      else if (d2 < v1) { v2 = v1; i2 = i1; v1 = d2; i1 = m; }
      else { v2 = d2; i2 = m; }
    }
  }
  float w0 = 1.0f / fmaxf(v0, 1e-10f);
  float w1 = 1.0f / fmaxf(v1, 1e-10f);
  float w2 = 1.0f / fmaxf(v2, 1e-10f);
  float s = w0 + w1 + w2;
  idx3[gid * 3 + 0] = i0; idx3[gid * 3 + 1] = i1; idx3[gid * 3 + 2] = i2;
  w3[gid * 3 + 0] = w0 / s; w3[gid * 3 + 1] = w1 / s; w3[gid * 3 + 2] = w2 / s;
}

// ---------------------------------------------------------------------------
// Combined launches (fps blocks FIRST so they are resident from t=0).
// ---------------------------------------------------------------------------
// A: fps 4096->512 (4 blocks, 256 thr) || knn_gw0 (4096 blocks x 4 queries)
__global__ __launch_bounds__(256) void combo_A_kernel(
    const float* __restrict__ xyz, float r2, int* __restrict__ idxK0,
    const float* __restrict__ W0, const float* __restrict__ b0,
    const float* __restrict__ A0, float* __restrict__ fea0, int* __restrict__ idx1,
    float* __restrict__ xyz1) {
  __shared__ u64 smem[6432];  // max(fps 51456B, knn 33280B)
  if (blockIdx.x < NB) {
    fps_body<256, 16, 4096>(xyz, 4096, 512, idx1, xyz1, smem, blockIdx.x, threadIdx.x);
  } else {
    int wave = threadIdx.x >> 6, lane = threadIdx.x & 63;
    int bn = (blockIdx.x - NB) * 4 + wave;
    knn_gw0_body(xyz, 4096, r2, idxK0, W0, b0, A0, fea0, bn, lane, smem + (size_t)wave * 1024,
                 smem + 4096 + wave * 16);
  }
}

// B: fps 512->128 (4 blocks) || knn_gw L1 (2048 blocks) || interp0 (256 blocks)
__global__ __launch_bounds__(64) void combo_B_kernel(
    const float* __restrict__ xyz, const float* __restrict__ xyz1, float r2,
    int* __restrict__ idxK1, const int* __restrict__ idx1, const float* __restrict__ fea0,
    const float* __restrict__ A1, float* __restrict__ wf, int* __restrict__ idx2,
    float* __restrict__ xyz2, int* __restrict__ idxI0, float* __restrict__ wI0) {
  __shared__ u64 smem[1040];
  int bid = blockIdx.x;
  if (bid < NB) {
    fps_body<64, 8, 512>(xyz1, 512, 128, idx2, xyz2, smem, bid, threadIdx.x);
  } else if (bid < NB + NB * 512) {
    knn_gw_body(xyz1, 512, r2, idxK1, idx1, fea0, 4096, 64, A1, wf, bid - NB, threadIdx.x,
                smem, smem + 1024);
  } else {
    int gid = (bid - NB - NB * 512) * 64 + threadIdx.x;
    interp3_body(xyz, xyz1, 4096, 512, idxI0, wI0, gid);
  }
}

// D: fps 128->64 (4 blocks) || knn_gw L2 (512 blocks) || interp1 (32 blocks)
__global__ __launch_bounds__(64) void combo_D_kernel(
    const float* __restrict__ xyz1, const float* __restrict__ xyz2, float r2,
    int* __restrict__ idxK2, const int* __restrict__ idx2, const float* __restrict__ fea1,
    const float* __restrict__ A2, float* __restrict__ wf, int* __restrict__ idx3,
    float* __restrict__ xyz3, int* __restrict__ idxI1, float* __restrict__ wI1) {
  __shared__ u64 smem[1040];
  int bid = blockIdx.x;
  if (bid < NB) {
    fps_body<64, 2, 128>(xyz2, 128, 64, idx3, xyz3, smem, bid, threadIdx.x);
  } else if (bid < NB + NB * 128) {
    knn_gw_body(xyz2, 128, r2, idxK2, idx2, fea1, 512, 128, A2, wf, bid - NB, threadIdx.x,
                smem, smem + 1024);
  } else {
    int gid = (bid - NB - NB * 128) * 64 + threadIdx.x;
    interp3_body(xyz1, xyz2, 512, 128, idxI1, wI1, gid);
  }
}

// H: knn_gw L3 (256 blocks) || interp2 (8 blocks)
__global__ __launch_bounds__(64) void combo_H_kernel(
    const float* __restrict__ xyz2, const float* __restrict__ xyz3, float r2,
    int* __restrict__ idxK3, const int* __restrict__ idx3, const float* __restrict__ fea2b,
    const float* __restrict__ A3, float* __restrict__ wf, int* __restrict__ idxI2,
    float* __restrict__ wI2) {
  __shared__ u64 smem[1040];
  int bid = blockIdx.x;
  if (bid < NB * 64) {
    knn_gw_body(xyz3, 64, r2, idxK3, idx3, fea2b, 128, 256, A3, wf, bid, threadIdx.x, smem,
                smem + 1024);
  } else {
    int gid = (bid - NB * 64) * 64 + threadIdx.x;
    interp3_body(xyz2, xyz3, 128, 64, idxI2, wI2, gid);
  }
}

// ---------------------------------------------------------------------------
// LAE gather-weight (POST-GEMM): out = relu(sum_k al_k Y[idx_k][c] + b[c])
// ---------------------------------------------------------------------------
__global__ __launch_bounds__(64) void gwpost_kernel(const float* __restrict__ xyz,
                                                    const float* __restrict__ Y,
                                                    const int* __restrict__ knn,
                                                    const float* __restrict__ A,
                                                    const float* __restrict__ bias,
                                                    float* __restrict__ out, int N, int C) {
  int bn = blockIdx.x;
  int b = bn / N, n = bn - b * N;
  int lane = threadIdx.x;
  const float* xb = xyz + (size_t)b * N * 3;
  const int* kn = knn + (size_t)bn * 16;
  int idv[16];
#pragma unroll
  for (int k = 0; k < 16; ++k) idv[k] = kn[k];
  float al[16];
  lae_alphas(xb, n, idv, A, al);
  const float* Yb = Y + (size_t)b * N * C;
  float* wo = out + (size_t)bn * C;
  for (int c = lane; c < C; c += 64) {
    float acc = 0.0f;
#pragma unroll
    for (int k = 0; k < 16; ++k) acc += al[k] * Yb[(size_t)idv[k] * C + c];
    wo[c] = fmaxf(acc + bias[c], 0.0f);
  }
}

// L6 gwpost fused with final classifier (C=128 fixed), out (B,13,N)
__global__ __launch_bounds__(64) void gwpost_final_kernel(
    const float* __restrict__ xyz, const float* __restrict__ Y, const int* __restrict__ knn,
    const float* __restrict__ A, const float* __restrict__ bias,
    const float* __restrict__ Wf, const float* __restrict__ bfv, float* __restrict__ out,
    int N) {
  int bn = blockIdx.x;
  int b = bn / N, n = bn - b * N;
  int lane = threadIdx.x;
  const float* xb = xyz + (size_t)b * N * 3;
  const int* kn = knn + (size_t)bn * 16;
  int idv[16];
#pragma unroll
  for (int k = 0; k < 16; ++k) idv[k] = kn[k];
  float al[16];
  lae_alphas(xb, n, idv, A, al);
  const float* Yb = Y + (size_t)b * N * 128;
  float a0 = 0.0f, a1 = 0.0f;
#pragma unroll
  for (int k = 0; k < 16; ++k) {
    const float* yr = Yb + (size_t)idv[k] * 128;
    a0 += al[k] * yr[lane];
    a1 += al[k] * yr[lane + 64];
  }
  float v0 = fmaxf(a0 + bias[lane], 0.0f);
  float v1 = fmaxf(a1 + bias[lane + 64], 0.0f);
  float* ob = out + ((size_t)b * 13) * N + n;
#pragma unroll
  for (int cls = 0; cls < 13; ++cls) {
    float p = v0 * Wf[lane * 13 + cls] + v1 * Wf[(lane + 64) * 13 + cls];
#pragma unroll
    for (int m = 32; m; m >>= 1) p += __shfl_xor(p, m);
    if (lane == 0) ob[(size_t)cls * N] = p + bfv[cls];
  }
}

// ---------------------------------------------------------------------------
// Tiled fp32 GEMM body with optional fused 3-NN interp epilogue.
// ---------------------------------------------------------------------------
__device__ __forceinline__ void gemm_body(const float* __restrict__ Amat,
                                          const float* __restrict__ W,
                                          const float* __restrict__ bias,
                                          float* __restrict__ out, int K, int Cout, int relu,
                                          const int* __restrict__ i3,
                                          const float* __restrict__ w3,
                                          const float* __restrict__ Zb, int Nd, int Ns,
                                          float* lds_a) {
  int co = blockIdx.x * 64 + (threadIdx.x & 63);
  int rg = threadIdx.x >> 6;
  int r0 = blockIdx.y * 32;
  float acc[8];
#pragma unroll
  for (int j = 0; j < 8; ++j) acc[j] = 0.0f;
  for (int k0 = 0; k0 < K; k0 += 32) {
    int row = threadIdx.x >> 3;
    int kq = (threadIdx.x & 7) * 4;
    int gk = k0 + kq;
    const float* ap = Amat + (size_t)(r0 + row) * K + gk;
    float a0 = 0.0f, a1 = 0.0f, a2 = 0.0f, a3 = 0.0f;
    if (gk + 3 < K) {
      float4 tv = *(const float4*)ap;
      a0 = tv.x; a1 = tv.y; a2 = tv.z; a3 = tv.w;
    } else {
      if (gk + 0 < K) a0 = ap[0];
      if (gk + 1 < K) a1 = ap[1];
      if (gk + 2 < K) a2 = ap[2];
    }
    __syncthreads();
    lds_a[(kq + 0) * 36 + row] = a0;
    lds_a[(kq + 1) * 36 + row] = a1;
    lds_a[(kq + 2) * 36 + row] = a2;
    lds_a[(kq + 3) * 36 + row] = a3;
    __syncthreads();
    int kmax = K - k0;
    if (kmax > 32) kmax = 32;
    if (kmax == 32) {
#pragma unroll
      for (int kk = 0; kk < 32; ++kk) {
        float w = W[(size_t)(k0 + kk) * Cout + co];
        const float* ar = &lds_a[kk * 36 + rg * 8];
        float4 x0 = *(const float4*)ar;
        float4 x1 = *(const float4*)(ar + 4);
        acc[0] += x0.x * w; acc[1] += x0.y * w; acc[2] += x0.z * w; acc[3] += x0.w * w;
        acc[4] += x1.x * w; acc[5] += x1.y * w; acc[6] += x1.z * w; acc[7] += x1.w * w;
      }
    } else {
      for (int kk = 0; kk < kmax; ++kk) {
        float w = W[(size_t)(k0 + kk) * Cout + co];
        const float* ar = &lds_a[kk * 36 + rg * 8];
        float4 x0 = *(const float4*)ar;
        float4 x1 = *(const float4*)(ar + 4);
        acc[0] += x0.x * w; acc[1] += x0.y * w; acc[2] += x0.z * w; acc[3] += x0.w * w;
        acc[4] += x1.x * w; acc[5] += x1.y * w; acc[6] += x1.z * w; acc[7] += x1.w * w;
      }
    }
  }
  float bb = bias ? bias[co] : 0.0f;
#pragma unroll
  for (int j = 0; j < 8; ++j) {
    int r = r0 + rg * 8 + j;
    float vv = acc[j] + bb;
    if (i3) {
      int bidx = r / Nd;
      const int* ii = i3 + (size_t)r * 3;
      const float* ww = w3 + (size_t)r * 3;
      const float* zb = Zb + (size_t)bidx * Ns * Cout;
      vv += ww[0] * zb[(size_t)ii[0] * Cout + co] + ww[1] * zb[(size_t)ii[1] * Cout + co] +
            ww[2] * zb[(size_t)ii[2] * Cout + co];
    }
    if (relu) vv = fmaxf(vv, 0.0f);
    out[(size_t)r * Cout + co] = vv;
  }
}

__global__ __launch_bounds__(256) void gemm_kernel(const float* __restrict__ Amat,
                                                   const float* __restrict__ W,
                                                   const float* __restrict__ bias,
                                                   float* __restrict__ out, int K, int Cout,
                                                   int relu, const int* __restrict__ i3,
                                                   const float* __restrict__ w3,
                                                   const float* __restrict__ Zb, int Nd,
                                                   int Ns) {
  __shared__ float lds_a[32 * 36];
  gemm_body(Amat, W, bias, out, K, Cout, relu, i3, w3, Zb, Nd, Ns, lds_a);
}

__global__ __launch_bounds__(256) void gemm_qkv_kernel(
    const float* __restrict__ Amat, const float* __restrict__ Wq,
    const float* __restrict__ Wk, const float* __restrict__ Wv, float* __restrict__ oq,
    float* __restrict__ ok, float* __restrict__ ov, int K, int Cout) {
  __shared__ float lds_a[32 * 36];
  const float* W = blockIdx.z == 0 ? Wq : (blockIdx.z == 1 ? Wk : Wv);
  float* o = blockIdx.z == 0 ? oq : (blockIdx.z == 1 ? ok : ov);
  gemm_body(Amat, W, nullptr, o, K, Cout, 0, nullptr, nullptr, nullptr, 0, 0, lds_a);
}

// ---------------------------------------------------------------------------
// Self-attention mix: out[n] = softmax(q[n]·k^T) @ v + fea[n]. Block per (b,n).
// ---------------------------------------------------------------------------
__global__ __launch_bounds__(128) void attn_kernel(const float* __restrict__ q,
                                                   const float* __restrict__ k,
                                                   const float* __restrict__ v,
                                                   const float* __restrict__ fea,
                                                   float* __restrict__ out, int N, int C) {
  __shared__ float sa[128];
  __shared__ float sb[128];
  int b = blockIdx.y, n = blockIdx.x, t = threadIdx.x;
  const float* qn = q + ((size_t)b * N + n) * C;
  if (t < N) {
    const float* km = k + ((size_t)b * N + t) * C;
    float acc = 0.0f;
    for (int c = 0; c < C; ++c) acc += qn[c] * km[c];
    sa[t] = acc;
  }
  __syncthreads();
  float mx = -3.0e38f;
  for (int i = 0; i < N; ++i) mx = fmaxf(mx, sa[i]);
  if (t < N) sb[t] = expf(sa[t] - mx);
  __syncthreads();
  float sum = 0.0f;
  for (int i = 0; i < N; ++i) sum += sb[i];
  size_t rowo = ((size_t)b * N + n) * C;
  for (int c = t; c < C; c += 128) {
    float acc = 0.0f;
    for (int m = 0; m < N; ++m) acc += sb[m] * v[((size_t)b * N + m) * C + c];
    out[rowo + c] = acc / sum + fea[rowo + c];
  }
}

// ---------------------------------------------------------------------------
extern "C" void kernel_launch(void* const* d_in, const int* in_sizes, int n_in,
                              void* d_out, int out_size, void* d_ws, size_t ws_size,
                              hipStream_t stream) {
  (void)in_sizes; (void)n_in; (void)out_size; (void)ws_size;
  const float* xyz = (const float*)d_in[0];
  const float* W[7]; const float* bi[7]; const float* A[7];
  for (int i = 0; i < 7; ++i) {
    W[i] = (const float*)d_in[1 + 3 * i];
    bi[i] = (const float*)d_in[2 + 3 * i];
    A[i] = (const float*)d_in[3 + 3 * i];
  }
  const float* Wq1 = (const float*)d_in[22];
  const float* Wk1 = (const float*)d_in[23];
  const float* Wv1 = (const float*)d_in[24];
  const float* Wq2 = (const float*)d_in[25];
  const float* Wk2 = (const float*)d_in[26];
  const float* Wv2 = (const float*)d_in[27];
  const float* Wq3 = (const float*)d_in[28];
  const float* Wk3 = (const float*)d_in[29];
  const float* Wv3 = (const float*)d_in[30];
  const float* Wf = (const float*)d_in[31];
  const float* bf = (const float*)d_in[32];
  float* out = (float*)d_out;

  const int B = NB, N0 = 4096, N1 = 512, N2 = 128, N3 = 64;
  char* base = (char*)d_ws;
  size_t off = 0;
  auto alloc = [&](size_t bytes) -> void* {
    void* p = base + off;
    off += (bytes + 255) & ~(size_t)255;
    return p;
  };
  int* idxK0 = (int*)alloc((size_t)B * N0 * 16 * 4);
  int* idxK1 = (int*)alloc((size_t)B * N1 * 16 * 4);
  int* idxK2 = (int*)alloc((size_t)B * N2 * 16 * 4);
  int* idxK3 = (int*)alloc((size_t)B * N3 * 16 * 4);
  int* idx1 = (int*)alloc((size_t)B * N1 * 4);
  int* idx2 = (int*)alloc((size_t)B * N2 * 4);
  int* idx3 = (int*)alloc((size_t)B * N3 * 4);
  float* xyz1 = (float*)alloc((size_t)B * N1 * 3 * 4);
  float* xyz2 = (float*)alloc((size_t)B * N2 * 3 * 4);
  float* xyz3 = (float*)alloc((size_t)B * N3 * 3 * 4);
  float* fea0 = (float*)alloc((size_t)B * N0 * 64 * 4);
  float* fea1 = (float*)alloc((size_t)B * N1 * 128 * 4);
  float* fea1b = (float*)alloc((size_t)B * N1 * 256 * 4);
  float* fea2a = (float*)alloc((size_t)B * N2 * 256 * 4);
  float* fea2b = (float*)alloc((size_t)B * N2 * 256 * 4);
  float* fea2c = (float*)alloc((size_t)B * N2 * 256 * 4);
  float* fea2d = (float*)alloc((size_t)B * N2 * 256 * 4);
  float* fea3a = (float*)alloc((size_t)B * N3 * 512 * 4);
  float* fea3b = (float*)alloc((size_t)B * N3 * 512 * 4);
  float* qb = (float*)alloc((size_t)B * 32768 * 4);
  float* kb = (float*)alloc((size_t)B * 32768 * 4);
  float* vb = (float*)alloc((size_t)B * 32768 * 4);
  int* idxI2 = (int*)alloc((size_t)B * N2 * 3 * 4);
  float* wI2 = (float*)alloc((size_t)B * N2 * 3 * 4);
  int* idxI1 = (int*)alloc((size_t)B * N1 * 3 * 4);
  float* wI1 = (float*)alloc((size_t)B * N1 * 3 * 4);
  int* idxI0 = (int*)alloc((size_t)B * N0 * 3 * 4);
  float* wI0 = (float*)alloc((size_t)B * N0 * 3 * 4);
  float* Zb4 = (float*)alloc((size_t)B * N3 * 256 * 4);
  float* Zb5 = (float*)alloc((size_t)B * N2 * 256 * 4);
  float* Zb6 = (float*)alloc((size_t)B * N1 * 128 * 4);
  float* Y4 = (float*)alloc((size_t)B * N2 * 256 * 4);
  float* Y5 = (float*)alloc((size_t)B * N1 * 256 * 4);
  float* Y6 = (float*)alloc((size_t)B * N0 * 128 * 4);
  float* wfb = (float*)alloc((size_t)B * N0 * 320 * 4);

  float r2_0 = (float)(0.06 * 0.06);
  float r2_1 = (float)(0.12 * 0.12);
  float r2_2 = (float)(0.3 * 0.3);
  float r2_3 = (float)(0.5 * 0.5);

  // A: fps(4096->512) || L0 knn+gw+gemm -> fea0, idxK0, idx1, xyz1
  combo_A_kernel<<<B + B * N0 / 4, 256, 0, stream>>>(xyz, r2_0, idxK0, W[0], bi[0], A[0],
                                                     fea0, idx1, xyz1);
  // B: fps(512->128) || L1 knn+gw -> wfb || interp0
  combo_B_kernel<<<B + B * N1 + B * N0 / 64, 64, 0, stream>>>(
      xyz, xyz1, r2_1, idxK1, idx1, fea0, A[1], wfb, idx2, xyz2, idxI0, wI0);
  // C: gemm L1 -> fea1
  gemm_kernel<<<dim3(2, B * N1 / 32), 256, 0, stream>>>(wfb, W[1], bi[1], fea1, 64, 128, 1,
                                                        nullptr, nullptr, nullptr, 0, 0);
  // D: fps(128->64) || L2 knn+gw -> wfb || interp1
  combo_D_kernel<<<B + B * N2 + B * N1 / 64, 64, 0, stream>>>(
      xyz1, xyz2, r2_2, idxK2, idx2, fea1, A[2], wfb, idx3, xyz3, idxI1, wI1);
  // E: gemm L2 -> fea2a; qkv1; attn1 -> fea2b
  gemm_kernel<<<dim3(4, B * N2 / 32), 256, 0, stream>>>(wfb, W[2], bi[2], fea2a, 128, 256, 1,
                                                        nullptr, nullptr, nullptr, 0, 0);
  gemm_qkv_kernel<<<dim3(4, B * N2 / 32, 3), 256, 0, stream>>>(fea2a, Wq1, Wk1, Wv1, qb, kb,
                                                               vb, 256, 256);
  attn_kernel<<<dim3(N2, B), 128, 0, stream>>>(qb, kb, vb, fea2a, fea2b, N2, 256);

  // H: L3 knn+gw -> wfb || interp2
  combo_H_kernel<<<B * N3 + B * N2 / 64, 64, 0, stream>>>(xyz2, xyz3, r2_3, idxK3, idx3,
                                                          fea2b, A[3], wfb, idxI2, wI2);
  // I: gemm L3 -> fea3a; qkv2; attn2 -> fea3b
  gemm_kernel<<<dim3(8, B * N3 / 32), 256, 0, stream>>>(wfb, W[3], bi[3], fea3a, 256, 512, 1,
                                                        nullptr, nullptr, nullptr, 0, 0);
  gemm_qkv_kernel<<<dim3(8, B * N3 / 32, 3), 256, 0, stream>>>(fea3a, Wq2, Wk2, Wv2, qb, kb,
                                                               vb, 512, 512);
  attn_kernel<<<dim3(N3, B), 128, 0, stream>>>(qb, kb, vb, fea3a, fea3b, N3, 512);

  // L4: Zb4 = fea3b@W4b; Y4 = fea2b@W4a + interp; gwpost -> fea2c; qkv3; attn3
  gemm_kernel<<<dim3(4, B * N3 / 32), 256, 0, stream>>>(fea3b, W[4] + 256 * 256, nullptr, Zb4,
                                                        512, 256, 0, nullptr, nullptr,
                                                        nullptr, 0, 0);
  gemm_kernel<<<dim3(4, B * N2 / 32), 256, 0, stream>>>(fea2b, W[4], nullptr, Y4, 256, 256, 0,
                                                        idxI2, wI2, Zb4, N2, N3);
  gwpost_kernel<<<B * N2, 64, 0, stream>>>(xyz2, Y4, idxK2, A[4], bi[4], fea2c, N2, 256);
  gemm_qkv_kernel<<<dim3(4, B * N2 / 32, 3), 256, 0, stream>>>(fea2c, Wq3, Wk3, Wv3, qb, kb,
                                                               vb, 256, 256);
  attn_kernel<<<dim3(N2, B), 128, 0, stream>>>(qb, kb, vb, fea2c, fea2d, N2, 256);

  // L5: Zb5 = fea2d@W5b; Y5 = fea1@W5a + interp; gwpost -> fea1b
  gemm_kernel<<<dim3(4, B * N2 / 32), 256, 0, stream>>>(fea2d, W[5] + 128 * 256, nullptr, Zb5,
                                                        256, 256, 0, nullptr, nullptr,
                                                        nullptr, 0, 0);
  gemm_kernel<<<dim3(4, B * N1 / 32), 256, 0, stream>>>(fea1, W[5], nullptr, Y5, 128, 256, 0,
                                                        idxI1, wI1, Zb5, N1, N2);
  gwpost_kernel<<<B * N1, 64, 0, stream>>>(xyz1, Y5, idxK1, A[5], bi[5], fea1b, N1, 256);

  // L6: Zb6 = fea1b@W6b; Y6 = fea0@W6a + interp; gwpost+final -> out
  gemm_kernel<<<dim3(2, B * N1 / 32), 256, 0, stream>>>(fea1b, W[6] + 64 * 128, nullptr, Zb6,
                                                        256, 128, 0, nullptr, nullptr,
                                                        nullptr, 0, 0);
  gemm_kernel<<<dim3(2, B * N0 / 32), 256, 0, stream>>>(fea0, W[6], nullptr, Y6, 64, 128, 0,
                                                        idxI0, wI0, Zb6, N0, N1);
  gwpost_final_kernel<<<B * N0, 64, 0, stream>>>(xyz, Y6, idxK0, A[6], bi[6], Wf, bf, out,
                                                 N0);
}

// Round 7
// 916.225 us; speedup vs baseline: 3.9702x; 1.1400x over previous
//
#include <hip/hip_runtime.h>
#include <math.h>

#define NB 4  // batch

typedef unsigned long long u64;

// branchless ascending compare-swap on u64 keys
#define CSWAP(a, b)                                          \
  {                                                          \
    u64 _mn = (b < a) ? b : a;                               \
    u64 _mx = (b < a) ? a : b;                               \
    a = _mn;                                                 \
    b = _mx;                                                 \
  }

// ---------------------------------------------------------------------------
// Pack xyz (stride 3) -> xyzw float4 with norm. Norm expression must stay
// left-assoc (x*x + y*y + z*z) with contract off: bit-identical to the
// previous in-kernel computation, so all selections are unchanged.
// ---------------------------------------------------------------------------
__global__ __launch_bounds__(256) void norms_kernel(const float* __restrict__ xyz,
                                                    float4* __restrict__ xw, int total) {
#pragma clang fp contract(off)
  int i = blockIdx.x * 256 + threadIdx.x;
  if (i >= total) return;
  float x = xyz[3 * i + 0], y = xyz[3 * i + 1], z = xyz[3 * i + 2];
  xw[i] = make_float4(x, y, z, x * x + y * y + z * z);
}

// ---------------------------------------------------------------------------
// kNN-16 top-16 search (per-wave) on packed float4 coords. Key =
// (d2_bits<<32)|idx == exact (d2, idx) lexicographic order, matching
// jax.lax.top_k stable tie-break. Winners in win[0..15] ascending.
// ---------------------------------------------------------------------------
__device__ __forceinline__ void knn16_search(const float4* __restrict__ xwb, int N, int n,
                                             int lane, u64* lists, u64* win) {
#pragma clang fp contract(off)
  float4 q = xwb[n];
  float qq = q.w;
  const u64 SENT = ((u64)0x7F800000u << 32) | (unsigned)lane;
  u64 k0 = SENT, k1 = SENT, k2 = SENT, k3 = SENT, k4 = SENT, k5 = SENT, k6 = SENT,
      k7 = SENT, k8 = SENT, k9 = SENT, k10 = SENT, k11 = SENT, k12 = SENT, k13 = SENT,
      k14 = SENT, k15 = SENT;
  int rounds = N >> 6;
  for (int j = 0; j < rounds; ++j) {
    int m = j * 64 + lane;
    float4 p = xwb[m];
    float ab = q.x * p.x + q.y * p.y + q.z * p.z;
    float d2 = fmaxf((qq + p.w) - 2.0f * ab, 0.0f);
    u64 key = ((u64)__float_as_uint(d2) << 32) | (unsigned)m;
    if (key < k15) {
      k15 = key;
      CSWAP(k14, k15); CSWAP(k13, k14); CSWAP(k12, k13); CSWAP(k11, k12);
      CSWAP(k10, k11); CSWAP(k9, k10);  CSWAP(k8, k9);   CSWAP(k7, k8);
      CSWAP(k6, k7);   CSWAP(k5, k6);   CSWAP(k4, k5);   CSWAP(k3, k4);
      CSWAP(k2, k3);   CSWAP(k1, k2);   CSWAP(k0, k1);
    }
  }
  lists[0 * 64 + lane] = k0;   lists[1 * 64 + lane] = k1;
  lists[2 * 64 + lane] = k2;   lists[3 * 64 + lane] = k3;
  lists[4 * 64 + lane] = k4;   lists[5 * 64 + lane] = k5;
  lists[6 * 64 + lane] = k6;   lists[7 * 64 + lane] = k7;
  lists[8 * 64 + lane] = k8;   lists[9 * 64 + lane] = k9;
  lists[10 * 64 + lane] = k10; lists[11 * 64 + lane] = k11;
  lists[12 * 64 + lane] = k12; lists[13 * 64 + lane] = k13;
  lists[14 * 64 + lane] = k14; lists[15 * 64 + lane] = k15;
  __syncthreads();
  int head = 0;
  u64 outk = 0;
  for (int r = 0; r < 16; ++r) {
    u64 h = lists[head * 64 + lane];
    u64 mn = h;
#pragma unroll
    for (int mask = 32; mask; mask >>= 1) {
      u64 o = __shfl_xor(mn, mask);
      if (o < mn) mn = o;
    }
    if (h == mn) head++;
    if (lane == r) outk = mn;
  }
  if (lane < 16) win[lane] = outk;
  __syncthreads();
}

// softmax alphas over 16 neighbor coordinate offsets (all lanes redundant)
__device__ __forceinline__ void lae_alphas(const float4* __restrict__ xwb, int n,
                                           const int* idv, const float* __restrict__ A,
                                           float* al) {
  float ax = A[0], ay = A[1], az = A[2];
  float4 q = xwb[n];
  float mx = -3.0e38f;
#pragma unroll
  for (int k = 0; k < 16; ++k) {
    float4 p = xwb[idv[k]];
    float gx = p.x - q.x, gy = p.y - q.y, gz = p.z - q.z;
    float s = gx * ax + gy * ay + gz * az;
    al[k] = s;
    mx = fmaxf(mx, s);
  }
  float sum = 0.0f;
#pragma unroll
  for (int k = 0; k < 16; ++k) { al[k] = expf(al[k] - mx); sum += al[k]; }
#pragma unroll
  for (int k = 0; k < 16; ++k) al[k] = al[k] / sum;
}

// ---------------------------------------------------------------------------
// FPS body (packed float4 input). Per-thread tree reduce of PTS u64 keys
// (dist_bits<<32 | ~pt) -> 6 xor-shuffle levels (wave winner) -> NW LDS slots
// (parity double-buffered) -> scalar scan. Exact jnp.argmax semantics.
// Output xw_out rows are exact copies of input rows (norm included).
// ---------------------------------------------------------------------------
template <int NT, int PTS, int NPT>
__device__ __forceinline__ void fps_body(const float4* __restrict__ xw, int N, int npoint,
                                         int* __restrict__ idx_out,
                                         float4* __restrict__ xw_out, u64* smem, int b,
                                         int tid) {
#pragma clang fp contract(off)
  constexpr int NW = NT / 64;
  u64* rk = smem;
  int* hist = (int*)(smem + 2 * NW);
  float* sxyz = (float*)(hist + 512);
  const float4* xb = xw + (size_t)b * N;
  for (int i = tid; i < N; i += NT) {
    float4 p = xb[i];
    sxyz[3 * i + 0] = p.x;
    sxyz[3 * i + 1] = p.y;
    sxyz[3 * i + 2] = p.z;
  }
  float px[PTS], py[PTS], pz[PTS], dist[PTS];
#pragma unroll
  for (int p = 0; p < PTS; ++p) {
    float4 v = xb[tid + p * NT];
    px[p] = v.x;
    py[p] = v.y;
    pz[p] = v.z;
    dist[p] = 1e10f;
  }
  __syncthreads();
  int far = 0;
  float cx = sxyz[0], cy = sxyz[1], cz = sxyz[2];
  for (int t = 0; t < npoint; ++t) {
    if (tid == 0) hist[t] = far;
    u64 K[PTS];
#pragma unroll
    for (int p = 0; p < PTS; ++p) {
      float dx = px[p] - cx, dy = py[p] - cy, dz = pz[p] - cz;
      float d = dx * dx + dy * dy + dz * dz;
      float nd = fminf(dist[p], d);
      dist[p] = nd;
      K[p] = ((u64)__float_as_uint(nd) << 32) | (unsigned)(~(tid + p * NT));
    }
#pragma unroll
    for (int s = PTS / 2; s >= 1; s >>= 1) {
#pragma unroll
      for (int i = 0; i < s; ++i)
        if (K[i + s] > K[i]) K[i] = K[i + s];
    }
    u64 key = K[0];
#pragma unroll
    for (int m = 1; m <= 32; m <<= 1) {
      u64 o = __shfl_xor(key, m);
      if (o > key) key = o;
    }
    if constexpr (NW > 1) {
      int par = (t & 1) * NW;
      if ((tid & 63) == 0) rk[par + (tid >> 6)] = key;
      __syncthreads();
      key = rk[par + 0];
#pragma unroll
      for (int w = 1; w < NW; ++w)
        if (rk[par + w] > key) key = rk[par + w];
    }
    far = (int)(~(unsigned)key);
    cx = sxyz[3 * far + 0];
    cy = sxyz[3 * far + 1];
    cz = sxyz[3 * far + 2];
  }
  __syncthreads();
  for (int s = tid; s < npoint; s += NT) {
    int idp = hist[s];
    idx_out[(size_t)b * npoint + s] = idp;
    xw_out[(size_t)b * npoint + s] = xb[idp];
  }
}

// ---------------------------------------------------------------------------
// knn_gw body: kNN + ball filter + softmax-weighted feature sum with source
// row indirection. One wave per query.
// ---------------------------------------------------------------------------
__device__ __forceinline__ void knn_gw_body(const float4* __restrict__ xw_s, int N, float r2,
                                            int* __restrict__ idxK,
                                            const int* __restrict__ srcmap,
                                            const float* __restrict__ fea_src, int Nsrc,
                                            int Cin, const float* __restrict__ A,
                                            float* __restrict__ wf, int bn, int lane,
                                            u64* lists, u64* win) {
  int b = bn / N, n = bn - b * N;
  const float4* xb = xw_s + (size_t)b * N;
  knn16_search(xb, N, n, lane, lists, win);
  int idv[16];
#pragma unroll
  for (int k = 0; k < 16; ++k) {
    u64 kk = win[k];
    float d2 = __uint_as_float((unsigned)(kk >> 32));
    idv[k] = (d2 <= r2) ? (int)(kk & 0xFFFFFFFFu) : n;
  }
  if (lane < 16) idxK[(size_t)bn * 16 + lane] = idv[lane];
  float al[16];
  lae_alphas(xb, n, idv, A, al);
  int row[16];
  const int* sm = srcmap + (size_t)b * N;
#pragma unroll
  for (int k = 0; k < 16; ++k) row[k] = sm[idv[k]];
  const float* fb = fea_src + (size_t)b * Nsrc * Cin;
  float* wo = wf + (size_t)bn * Cin;
  for (int c = lane; c < Cin; c += 64) {
    float acc = 0.0f;
#pragma unroll
    for (int k = 0; k < 16; ++k) acc += al[k] * fb[(size_t)row[k] * Cin + c];
    wo[c] = acc;
  }
}

// L0 variant: fea == xyz (Cin=3) with fused K=3 mini-GEMM -> fea0 (Cout=64)
__device__ __forceinline__ void knn_gw0_body(const float4* __restrict__ xw, int N, float r2,
                                             int* __restrict__ idxK,
                                             const float* __restrict__ W0,
                                             const float* __restrict__ b0,
                                             const float* __restrict__ A0,
                                             float* __restrict__ fea0, int bn, int lane,
                                             u64* lists, u64* win) {
  int b = bn / N, n = bn - b * N;
  const float4* xb = xw + (size_t)b * N;
  knn16_search(xb, N, n, lane, lists, win);
  int idv[16];
#pragma unroll
  for (int k = 0; k < 16; ++k) {
    u64 kk = win[k];
    float d2 = __uint_as_float((unsigned)(kk >> 32));
    idv[k] = (d2 <= r2) ? (int)(kk & 0xFFFFFFFFu) : n;
  }
  if (lane < 16) idxK[(size_t)bn * 16 + lane] = idv[lane];
  float al[16];
  lae_alphas(xb, n, idv, A0, al);
  float w0 = 0.0f, w1 = 0.0f, w2 = 0.0f;
#pragma unroll
  for (int k = 0; k < 16; ++k) {
    float4 p = xb[idv[k]];
    w0 += al[k] * p.x;
    w1 += al[k] * p.y;
    w2 += al[k] * p.z;
  }
  float v = w0 * W0[0 * 64 + lane] + w1 * W0[1 * 64 + lane] + w2 * W0[2 * 64 + lane] +
            b0[lane];
  fea0[(size_t)bn * 64 + lane] = fmaxf(v, 0.0f);
}

// ---------------------------------------------------------------------------
// 3-NN inverse-distance body (pdist2 form, stable top-3), packed coords.
// ---------------------------------------------------------------------------
__device__ __forceinline__ void interp3_body(const float4* __restrict__ xd,
                                             const float4* __restrict__ xs, int Nd, int Ns,
                                             int* __restrict__ idx3, float* __restrict__ w3,
                                             int gid) {
#pragma clang fp contract(off)
  int b = gid / Nd;
  const float4* xb = xs + (size_t)b * Ns;
  float4 q = xd[gid];
  float qq = q.w;
  float v0 = 3.0e38f, v1 = 3.0e38f, v2 = 3.0e38f;
  int i0 = 0, i1 = 0, i2 = 0;
  for (int m = 0; m < Ns; ++m) {
    float4 p = xb[m];
    float ab = q.x * p.x + q.y * p.y + q.z * p.z;
    float d2 = fmaxf((qq + p.w) - 2.0f * ab, 0.0f);
    if (d2 < v2) {
      if (d2 < v0) { v2 = v1; i2 = i1; v1 = v0; i1 = i0; v0 = d2; i0 = m; }
      else if (d2 < v1) { v2 = v1; i2 = i1; v1 = d2; i1 = m; }
      else { v2 = d2; i2 = m; }
    }
  }
  float w0 = 1.0f / fmaxf(v0, 1e-10f);
  float w1 = 1.0f / fmaxf(v1, 1e-10f);
  float w2 = 1.0f / fmaxf(v2, 1e-10f);
  float s = w0 + w1 + w2;
  idx3[gid * 3 + 0] = i0; idx3[gid * 3 + 1] = i1; idx3[gid * 3 + 2] = i2;
  w3[gid * 3 + 0] = w0 / s; w3[gid * 3 + 1] = w1 / s; w3[gid * 3 + 2] = w2 / s;
}

// ---------------------------------------------------------------------------
// Combined launches (fps blocks FIRST so they are resident from t=0).
// ---------------------------------------------------------------------------
// A: fps 4096->512 (4 blocks, 256 thr) || knn_gw0 (4096 blocks x 4 queries)
__global__ __launch_bounds__(256) void combo_A_kernel(
    const float4* __restrict__ xw0, float r2, int* __restrict__ idxK0,
    const float* __restrict__ W0, const float* __restrict__ b0,
    const float* __restrict__ A0, float* __restrict__ fea0, int* __restrict__ idx1,
    float4* __restrict__ xw1) {
  __shared__ u64 smem[6432];  // fps: 51328B; knn: 4160 u64
  if (blockIdx.x < NB) {
    fps_body<256, 16, 4096>(xw0, 4096, 512, idx1, xw1, smem, blockIdx.x, threadIdx.x);
  } else {
    int wave = threadIdx.x >> 6, lane = threadIdx.x & 63;
    int bn = (blockIdx.x - NB) * 4 + wave;
    knn_gw0_body(xw0, 4096, r2, idxK0, W0, b0, A0, fea0, bn, lane, smem + (size_t)wave * 1024,
                 smem + 4096 + wave * 16);
  }
}

// B: fps 512->128 (4 blocks) || knn_gw L1 (2048 blocks) || interp0 (256 blocks)
__global__ __launch_bounds__(64) void combo_B_kernel(
    const float4* __restrict__ xw0, const float4* __restrict__ xw1, float r2,
    int* __restrict__ idxK1, const int* __restrict__ idx1, const float* __restrict__ fea0,
    const float* __restrict__ A1, float* __restrict__ wf, int* __restrict__ idx2,
    float4* __restrict__ xw2, int* __restrict__ idxI0, float* __restrict__ wI0) {
  __shared__ u64 smem[1056];
  int bid = blockIdx.x;
  if (bid < NB) {
    fps_body<64, 8, 512>(xw1, 512, 128, idx2, xw2, smem, bid, threadIdx.x);
  } else if (bid < NB + NB * 512) {
    knn_gw_body(xw1, 512, r2, idxK1, idx1, fea0, 4096, 64, A1, wf, bid - NB, threadIdx.x,
                smem, smem + 1024);
  } else {
    int gid = (bid - NB - NB * 512) * 64 + threadIdx.x;
    interp3_body(xw0, xw1, 4096, 512, idxI0, wI0, gid);
  }
}

// D: fps 128->64 (4 blocks) || knn_gw L2 (512 blocks) || interp1 (32 blocks)
__global__ __launch_bounds__(64) void combo_D_kernel(
    const float4* __restrict__ xw1, const float4* __restrict__ xw2, float r2,
    int* __restrict__ idxK2, const int* __restrict__ idx2, const float* __restrict__ fea1,
    const float* __restrict__ A2, float* __restrict__ wf, int* __restrict__ idx3,
    float4* __restrict__ xw3, int* __restrict__ idxI1, float* __restrict__ wI1) {
  __shared__ u64 smem[1056];
  int bid = blockIdx.x;
  if (bid < NB) {
    fps_body<64, 2, 128>(xw2, 128, 64, idx3, xw3, smem, bid, threadIdx.x);
  } else if (bid < NB + NB * 128) {
    knn_gw_body(xw2, 128, r2, idxK2, idx2, fea1, 512, 128, A2, wf, bid - NB, threadIdx.x,
                smem, smem + 1024);
  } else {
    int gid = (bid - NB - NB * 128) * 64 + threadIdx.x;
    interp3_body(xw1, xw2, 512, 128, idxI1, wI1, gid);
  }
}

// H: knn_gw L3 (256 blocks) || interp2 (8 blocks)
__global__ __launch_bounds__(64) void combo_H_kernel(
    const float4* __restrict__ xw2, const float4* __restrict__ xw3, float r2,
    int* __restrict__ idxK3, const int* __restrict__ idx3, const float* __restrict__ fea2b,
    const float* __restrict__ A3, float* __restrict__ wf, int* __restrict__ idxI2,
    float* __restrict__ wI2) {
  __shared__ u64 smem[1056];
  int bid = blockIdx.x;
  if (bid < NB * 64) {
    knn_gw_body(xw3, 64, r2, idxK3, idx3, fea2b, 128, 256, A3, wf, bid, threadIdx.x, smem,
                smem + 1024);
  } else {
    int gid = (bid - NB * 64) * 64 + threadIdx.x;
    interp3_body(xw2, xw3, 128, 64, idxI2, wI2, gid);
  }
}

// ---------------------------------------------------------------------------
// LAE gather-weight (POST-GEMM): out = relu(sum_k al_k Y[idx_k][c] + b[c])
// ---------------------------------------------------------------------------
__global__ __launch_bounds__(64) void gwpost_kernel(const float4* __restrict__ xw,
                                                    const float* __restrict__ Y,
                                                    const int* __restrict__ knn,
                                                    const float* __restrict__ A,
                                                    const float* __restrict__ bias,
                                                    float* __restrict__ out, int N, int C) {
  int bn = blockIdx.x;
  int b = bn / N, n = bn - b * N;
  int lane = threadIdx.x;
  const float4* xb = xw + (size_t)b * N;
  const int* kn = knn + (size_t)bn * 16;
  int idv[16];
#pragma unroll
  for (int k = 0; k < 16; ++k) idv[k] = kn[k];
  float al[16];
  lae_alphas(xb, n, idv, A, al);
  const float* Yb = Y + (size_t)b * N * C;
  float* wo = out + (size_t)bn * C;
  for (int c = lane; c < C; c += 64) {
    float acc = 0.0f;
#pragma unroll
    for (int k = 0; k < 16; ++k) acc += al[k] * Yb[(size_t)idv[k] * C + c];
    wo[c] = fmaxf(acc + bias[c], 0.0f);
  }
}

// L6 gwpost fused with final classifier (C=128 fixed), out (B,13,N)
__global__ __launch_bounds__(64) void gwpost_final_kernel(
    const float4* __restrict__ xw, const float* __restrict__ Y, const int* __restrict__ knn,
    const float* __restrict__ A, const float* __restrict__ bias,
    const float* __restrict__ Wf, const float* __restrict__ bfv, float* __restrict__ out,
    int N) {
  int bn = blockIdx.x;
  int b = bn / N, n = bn - b * N;
  int lane = threadIdx.x;
  const float4* xb = xw + (size_t)b * N;
  const int* kn = knn + (size_t)bn * 16;
  int idv[16];
#pragma unroll
  for (int k = 0; k < 16; ++k) idv[k] = kn[k];
  float al[16];
  lae_alphas(xb, n, idv, A, al);
  const float* Yb = Y + (size_t)b * N * 128;
  float a0 = 0.0f, a1 = 0.0f;
#pragma unroll
  for (int k = 0; k < 16; ++k) {
    const float* yr = Yb + (size_t)idv[k] * 128;
    a0 += al[k] * yr[lane];
    a1 += al[k] * yr[lane + 64];
  }
  float v0 = fmaxf(a0 + bias[lane], 0.0f);
  float v1 = fmaxf(a1 + bias[lane + 64], 0.0f);
  float* ob = out + ((size_t)b * 13) * N + n;
#pragma unroll
  for (int cls = 0; cls < 13; ++cls) {
    float p = v0 * Wf[lane * 13 + cls] + v1 * Wf[(lane + 64) * 13 + cls];
#pragma unroll
    for (int m = 32; m; m >>= 1) p += __shfl_xor(p, m);
    if (lane == 0) ob[(size_t)cls * N] = p + bfv[cls];
  }
}

// ---------------------------------------------------------------------------
// Tiled fp32 GEMM body with optional fused 3-NN interp epilogue.
// ---------------------------------------------------------------------------
__device__ __forceinline__ void gemm_body(const float* __restrict__ Amat,
                                          const float* __restrict__ W,
                                          const float* __restrict__ bias,
                                          float* __restrict__ out, int K, int Cout, int relu,
                                          const int* __restrict__ i3,
                                          const float* __restrict__ w3,
                                          const float* __restrict__ Zb, int Nd, int Ns,
                                          float* lds_a) {
  int co = blockIdx.x * 64 + (threadIdx.x & 63);
  int rg = threadIdx.x >> 6;
  int r0 = blockIdx.y * 32;
  float acc[8];
#pragma unroll
  for (int j = 0; j < 8; ++j) acc[j] = 0.0f;
  for (int k0 = 0; k0 < K; k0 += 32) {
    int row = threadIdx.x >> 3;
    int kq = (threadIdx.x & 7) * 4;
    int gk = k0 + kq;
    const float* ap = Amat + (size_t)(r0 + row) * K + gk;
    float a0 = 0.0f, a1 = 0.0f, a2 = 0.0f, a3 = 0.0f;
    if (gk + 3 < K) {
      float4 tv = *(const float4*)ap;
      a0 = tv.x; a1 = tv.y; a2 = tv.z; a3 = tv.w;
    } else {
      if (gk + 0 < K) a0 = ap[0];
      if (gk + 1 < K) a1 = ap[1];
      if (gk + 2 < K) a2 = ap[2];
    }
    __syncthreads();
    lds_a[(kq + 0) * 36 + row] = a0;
    lds_a[(kq + 1) * 36 + row] = a1;
    lds_a[(kq + 2) * 36 + row] = a2;
    lds_a[(kq + 3) * 36 + row] = a3;
    __syncthreads();
    int kmax = K - k0;
    if (kmax > 32) kmax = 32;
    if (kmax == 32) {
#pragma unroll
      for (int kk = 0; kk < 32; ++kk) {
        float w = W[(size_t)(k0 + kk) * Cout + co];
        const float* ar = &lds_a[kk * 36 + rg * 8];
        float4 x0 = *(const float4*)ar;
        float4 x1 = *(const float4*)(ar + 4);
        acc[0] += x0.x * w; acc[1] += x0.y * w; acc[2] += x0.z * w; acc[3] += x0.w * w;
        acc[4] += x1.x * w; acc[5] += x1.y * w; acc[6] += x1.z * w; acc[7] += x1.w * w;
      }
    } else {
      for (int kk = 0; kk < kmax; ++kk) {
        float w = W[(size_t)(k0 + kk) * Cout + co];
        const float* ar = &lds_a[kk * 36 + rg * 8];
        float4 x0 = *(const float4*)ar;
        float4 x1 = *(const float4*)(ar + 4);
        acc[0] += x0.x * w; acc[1] += x0.y * w; acc[2] += x0.z * w; acc[3] += x0.w * w;
        acc[4] += x1.x * w; acc[5] += x1.y * w; acc[6] += x1.z * w; acc[7] += x1.w * w;
      }
    }
  }
  float bb = bias ? bias[co] : 0.0f;
#pragma unroll
  for (int j = 0; j < 8; ++j) {
    int r = r0 + rg * 8 + j;
    float vv = acc[j] + bb;
    if (i3) {
      int bidx = r / Nd;
      const int* ii = i3 + (size_t)r * 3;
      const float* ww = w3 + (size_t)r * 3;
      const float* zb = Zb + (size_t)bidx * Ns * Cout;
      vv += ww[0] * zb[(size_t)ii[0] * Cout + co] + ww[1] * zb[(size_t)ii[1] * Cout + co] +
            ww[2] * zb[(size_t)ii[2] * Cout + co];
    }
    if (relu) vv = fmaxf(vv, 0.0f);
    out[(size_t)r * Cout + co] = vv;
  }
}

__global__ __launch_bounds__(256) void gemm_kernel(const float* __restrict__ Amat,
                                                   const float* __restrict__ W,
                                                   const float* __restrict__ bias,
                                                   float* __restrict__ out, int K, int Cout,
                                                   int relu, const int* __restrict__ i3,
                                                   const float* __restrict__ w3,
                                                   const float* __restrict__ Zb, int Nd,
                                                   int Ns) {
  __shared__ float lds_a[32 * 36];
  gemm_body(Amat, W, bias, out, K, Cout, relu, i3, w3, Zb, Nd, Ns, lds_a);
}

__global__ __launch_bounds__(256) void gemm_qkv_kernel(
    const float* __restrict__ Amat, const float* __restrict__ Wq,
    const float* __restrict__ Wk, const float* __restrict__ Wv, float* __restrict__ oq,
    float* __restrict__ ok, float* __restrict__ ov, int K, int Cout) {
  __shared__ float lds_a[32 * 36];
  const float* W = blockIdx.z == 0 ? Wq : (blockIdx.z == 1 ? Wk : Wv);
  float* o = blockIdx.z == 0 ? oq : (blockIdx.z == 1 ? ok : ov);
  gemm_body(Amat, W, nullptr, o, K, Cout, 0, nullptr, nullptr, nullptr, 0, 0, lds_a);
}

// ---------------------------------------------------------------------------
// Self-attention mix: out[n] = softmax(q[n]·k^T) @ v + fea[n]. Block per (b,n).
// k-row dot vectorized with float4 (per-thread rows are uncoalesced).
// ---------------------------------------------------------------------------
__global__ __launch_bounds__(128) void attn_kernel(const float* __restrict__ q,
                                                   const float* __restrict__ k,
                                                   const float* __restrict__ v,
                                                   const float* __restrict__ fea,
                                                   float* __restrict__ out, int N, int C) {
  __shared__ float sa[128];
  __shared__ float sb[128];
  int b = blockIdx.y, n = blockIdx.x, t = threadIdx.x;
  const float* qn = q + ((size_t)b * N + n) * C;
  if (t < N) {
    const float4* km = (const float4*)(k + ((size_t)b * N + t) * C);
    const float4* q4 = (const float4*)qn;
    float acc = 0.0f;
    int C4 = C >> 2;
    for (int c = 0; c < C4; ++c) {
      float4 kv = km[c];
      float4 qv = q4[c];
      acc += qv.x * kv.x + qv.y * kv.y + qv.z * kv.z + qv.w * kv.w;
    }
    sa[t] = acc;
  }
  __syncthreads();
  float mx = -3.0e38f;
  for (int i = 0; i < N; ++i) mx = fmaxf(mx, sa[i]);
  if (t < N) sb[t] = expf(sa[t] - mx);
  __syncthreads();
  float sum = 0.0f;
  for (int i = 0; i < N; ++i) sum += sb[i];
  size_t rowo = ((size_t)b * N + n) * C;
  for (int c = t; c < C; c += 128) {
    float acc = 0.0f;
    for (int m = 0; m < N; ++m) acc += sb[m] * v[((size_t)b * N + m) * C + c];
    out[rowo + c] = acc / sum + fea[rowo + c];
  }
}

// ---------------------------------------------------------------------------
extern "C" void kernel_launch(void* const* d_in, const int* in_sizes, int n_in,
                              void* d_out, int out_size, void* d_ws, size_t ws_size,
                              hipStream_t stream) {
  (void)in_sizes; (void)n_in; (void)out_size; (void)ws_size;
  const float* xyz = (const float*)d_in[0];
  const float* W[7]; const float* bi[7]; const float* A[7];
  for (int i = 0; i < 7; ++i) {
    W[i] = (const float*)d_in[1 + 3 * i];
    bi[i] = (const float*)d_in[2 + 3 * i];
    A[i] = (const float*)d_in[3 + 3 * i];
  }
  const float* Wq1 = (const float*)d_in[22];
  const float* Wk1 = (const float*)d_in[23];
  const float* Wv1 = (const float*)d_in[24];
  const float* Wq2 = (const float*)d_in[25];
  const float* Wk2 = (const float*)d_in[26];
  const float* Wv2 = (const float*)d_in[27];
  const float* Wq3 = (const float*)d_in[28];
  const float* Wk3 = (const float*)d_in[29];
  const float* Wv3 = (const float*)d_in[30];
  const float* Wf = (const float*)d_in[31];
  const float* bf = (const float*)d_in[32];
  float* out = (float*)d_out;

  const int B = NB, N0 = 4096, N1 = 512, N2 = 128, N3 = 64;
  char* base = (char*)d_ws;
  size_t off = 0;
  auto alloc = [&](size_t bytes) -> void* {
    void* p = base + off;
    off += (bytes + 255) & ~(size_t)255;
    return p;
  };
  float4* xw0 = (float4*)alloc((size_t)B * N0 * 16);
  float4* xw1 = (float4*)alloc((size_t)B * N1 * 16);
  float4* xw2 = (float4*)alloc((size_t)B * N2 * 16);
  float4* xw3 = (float4*)alloc((size_t)B * N3 * 16);
  int* idxK0 = (int*)alloc((size_t)B * N0 * 16 * 4);
  int* idxK1 = (int*)alloc((size_t)B * N1 * 16 * 4);
  int* idxK2 = (int*)alloc((size_t)B * N2 * 16 * 4);
  int* idxK3 = (int*)alloc((size_t)B * N3 * 16 * 4);
  int* idx1 = (int*)alloc((size_t)B * N1 * 4);
  int* idx2 = (int*)alloc((size_t)B * N2 * 4);
  int* idx3 = (int*)alloc((size_t)B * N3 * 4);
  float* fea0 = (float*)alloc((size_t)B * N0 * 64 * 4);
  float* fea1 = (float*)alloc((size_t)B * N1 * 128 * 4);
  float* fea1b = (float*)alloc((size_t)B * N1 * 256 * 4);
  float* fea2a = (float*)alloc((size_t)B * N2 * 256 * 4);
  float* fea2b = (float*)alloc((size_t)B * N2 * 256 * 4);
  float* fea2c = (float*)alloc((size_t)B * N2 * 256 * 4);
  float* fea2d = (float*)alloc((size_t)B * N2 * 256 * 4);
  float* fea3a = (float*)alloc((size_t)B * N3 * 512 * 4);
  float* fea3b = (float*)alloc((size_t)B * N3 * 512 * 4);
  float* qb = (float*)alloc((size_t)B * 32768 * 4);
  float* kb = (float*)alloc((size_t)B * 32768 * 4);
  float* vb = (float*)alloc((size_t)B * 32768 * 4);
  int* idxI2 = (int*)alloc((size_t)B * N2 * 3 * 4);
  float* wI2 = (float*)alloc((size_t)B * N2 * 3 * 4);
  int* idxI1 = (int*)alloc((size_t)B * N1 * 3 * 4);
  float* wI1 = (float*)alloc((size_t)B * N1 * 3 * 4);
  int* idxI0 = (int*)alloc((size_t)B * N0 * 3 * 4);
  float* wI0 = (float*)alloc((size_t)B * N0 * 3 * 4);
  float* Zb4 = (float*)alloc((size_t)B * N3 * 256 * 4);
  float* Zb5 = (float*)alloc((size_t)B * N2 * 256 * 4);
  float* Zb6 = (float*)alloc((size_t)B * N1 * 128 * 4);
  float* Y4 = (float*)alloc((size_t)B * N2 * 256 * 4);
  float* Y5 = (float*)alloc((size_t)B * N1 * 256 * 4);
  float* Y6 = (float*)alloc((size_t)B * N0 * 128 * 4);
  float* wfb = (float*)alloc((size_t)B * N0 * 320 * 4);

  float r2_0 = (float)(0.06 * 0.06);
  float r2_1 = (float)(0.12 * 0.12);
  float r2_2 = (float)(0.3 * 0.3);
  float r2_3 = (float)(0.5 * 0.5);

  // 0: pack coords + norms
  norms_kernel<<<B * N0 / 256, 256, 0, stream>>>(xyz, xw0, B * N0);

  // A: fps(4096->512) || L0 knn+gw+gemm -> fea0, idxK0, idx1, xw1
  combo_A_kernel<<<B + B * N0 / 4, 256, 0, stream>>>(xw0, r2_0, idxK0, W[0], bi[0], A[0],
                                                     fea0, idx1, xw1);
  // B: fps(512->128) || L1 knn+gw -> wfb || interp0
  combo_B_kernel<<<B + B * N1 + B * N0 / 64, 64, 0, stream>>>(
      xw0, xw1, r2_1, idxK1, idx1, fea0, A[1], wfb, idx2, xw2, idxI0, wI0);
  // C: gemm L1 -> fea1
  gemm_kernel<<<dim3(2, B * N1 / 32), 256, 0, stream>>>(wfb, W[1], bi[1], fea1, 64, 128, 1,
                                                        nullptr, nullptr, nullptr, 0, 0);
  // D: fps(128->64) || L2 knn+gw -> wfb || interp1
  combo_D_kernel<<<B + B * N2 + B * N1 / 64, 64, 0, stream>>>(
      xw1, xw2, r2_2, idxK2, idx2, fea1, A[2], wfb, idx3, xw3, idxI1, wI1);
  // E: gemm L2 -> fea2a; qkv1; attn1 -> fea2b
  gemm_kernel<<<dim3(4, B * N2 / 32), 256, 0, stream>>>(wfb, W[2], bi[2], fea2a, 128, 256, 1,
                                                        nullptr, nullptr, nullptr, 0, 0);
  gemm_qkv_kernel<<<dim3(4, B * N2 / 32, 3), 256, 0, stream>>>(fea2a, Wq1, Wk1, Wv1, qb, kb,
                                                               vb, 256, 256);
  attn_kernel<<<dim3(N2, B), 128, 0, stream>>>(qb, kb, vb, fea2a, fea2b, N2, 256);

  // H: L3 knn+gw -> wfb || interp2
  combo_H_kernel<<<B * N3 + B * N2 / 64, 64, 0, stream>>>(xw2, xw3, r2_3, idxK3, idx3, fea2b,
                                                          A[3], wfb, idxI2, wI2);
  // I: gemm L3 -> fea3a; qkv2; attn2 -> fea3b
  gemm_kernel<<<dim3(8, B * N3 / 32), 256, 0, stream>>>(wfb, W[3], bi[3], fea3a, 256, 512, 1,
                                                        nullptr, nullptr, nullptr, 0, 0);
  gemm_qkv_kernel<<<dim3(8, B * N3 / 32, 3), 256, 0, stream>>>(fea3a, Wq2, Wk2, Wv2, qb, kb,
                                                               vb, 512, 512);
  attn_kernel<<<dim3(N3, B), 128, 0, stream>>>(qb, kb, vb, fea3a, fea3b, N3, 512);

  // L4: Zb4 = fea3b@W4b; Y4 = fea2b@W4a + interp; gwpost -> fea2c; qkv3; attn3
  gemm_kernel<<<dim3(4, B * N3 / 32), 256, 0, stream>>>(fea3b, W[4] + 256 * 256, nullptr, Zb4,
                                                        512, 256, 0, nullptr, nullptr,
                                                        nullptr, 0, 0);
  gemm_kernel<<<dim3(4, B * N2 / 32), 256, 0, stream>>>(fea2b, W[4], nullptr, Y4, 256, 256, 0,
                                                        idxI2, wI2, Zb4, N2, N3);
  gwpost_kernel<<<B * N2, 64, 0, stream>>>(xw2, Y4, idxK2, A[4], bi[4], fea2c, N2, 256);
  gemm_qkv_kernel<<<dim3(4, B * N2 / 32, 3), 256, 0, stream>>>(fea2c, Wq3, Wk3, Wv3, qb, kb,
                                                               vb, 256, 256);
  attn_kernel<<<dim3(N2, B), 128, 0, stream>>>(qb, kb, vb, fea2c, fea2d, N2, 256);

  // L5: Zb5 = fea2d@W5b; Y5 = fea1@W5a + interp; gwpost -> fea1b
  gemm_kernel<<<dim3(4, B * N2 / 32), 256, 0, stream>>>(fea2d, W[5] + 128 * 256, nullptr, Zb5,
                                                        256, 256, 0, nullptr, nullptr,
                                                        nullptr, 0, 0);
  gemm_kernel<<<dim3(4, B * N1 / 32), 256, 0, stream>>>(fea1, W[5], nullptr, Y5, 128, 256, 0,
                                                        idxI1, wI1, Zb5, N1, N2);
  gwpost_kernel<<<B * N1, 64, 0, stream>>>(xw1, Y5, idxK1, A[5], bi[5], fea1b, N1, 256);

  // L6: Zb6 = fea1b@W6b; Y6 = fea0@W6a + interp; gwpost+final -> out
  gemm_kernel<<<dim3(2, B * N1 / 32), 256, 0, stream>>>(fea1b, W[6] + 64 * 128, nullptr, Zb6,
                                                        256, 128, 0, nullptr, nullptr,
                                                        nullptr, 0, 0);
  gemm_kernel<<<dim3(2, B * N0 / 32), 256, 0, stream>>>(fea0, W[6], nullptr, Y6, 64, 128, 0,
                                                        idxI0, wI0, Zb6, N0, N1);
  gwpost_final_kernel<<<B * N0, 64, 0, stream>>>(xw0, Y6, idxK0, A[6], bi[6], Wf, bf, out,
                                                 N0);
}

// Round 8
// 861.235 us; speedup vs baseline: 4.2236x; 1.0638x over previous
//
#include <hip/hip_runtime.h>
#include <math.h>

#define NB 4  // batch

typedef unsigned long long u64;

// branchless ascending compare-swap on u64 keys
#define CSWAP(a, b)                                          \
  {                                                          \
    u64 _mn = (b < a) ? b : a;                               \
    u64 _mx = (b < a) ? a : b;                               \
    a = _mn;                                                 \
    b = _mx;                                                 \
  }

// ---------------------------------------------------------------------------
// Pack xyz (stride 3) -> xyzw float4 with norm (left-assoc, contract off:
// bit-identical to reference pdist2 norms).
// ---------------------------------------------------------------------------
__global__ __launch_bounds__(256) void norms_kernel(const float* __restrict__ xyz,
                                                    float4* __restrict__ xw, int total) {
#pragma clang fp contract(off)
  int i = blockIdx.x * 256 + threadIdx.x;
  if (i >= total) return;
  float x = xyz[3 * i + 0], y = xyz[3 * i + 1], z = xyz[3 * i + 2];
  xw[i] = make_float4(x, y, z, x * x + y * y + z * z);
}

// ---------------------------------------------------------------------------
// kNN-16 top-16 search (per-wave) on packed float4 coords. Key =
// (d2_bits<<32)|idx == exact (d2, idx) lexicographic order == stable top_k.
// ---------------------------------------------------------------------------
__device__ __forceinline__ void knn16_search(const float4* __restrict__ xwb, int N, int n,
                                             int lane, u64* lists, u64* win) {
#pragma clang fp contract(off)
  float4 q = xwb[n];
  float qq = q.w;
  const u64 SENT = ((u64)0x7F800000u << 32) | (unsigned)lane;
  u64 k0 = SENT, k1 = SENT, k2 = SENT, k3 = SENT, k4 = SENT, k5 = SENT, k6 = SENT,
      k7 = SENT, k8 = SENT, k9 = SENT, k10 = SENT, k11 = SENT, k12 = SENT, k13 = SENT,
      k14 = SENT, k15 = SENT;
  int rounds = N >> 6;
  for (int j = 0; j < rounds; ++j) {
    int m = j * 64 + lane;
    float4 p = xwb[m];
    float ab = q.x * p.x + q.y * p.y + q.z * p.z;
    float d2 = fmaxf((qq + p.w) - 2.0f * ab, 0.0f);
    u64 key = ((u64)__float_as_uint(d2) << 32) | (unsigned)m;
    if (key < k15) {
      k15 = key;
      CSWAP(k14, k15); CSWAP(k13, k14); CSWAP(k12, k13); CSWAP(k11, k12);
      CSWAP(k10, k11); CSWAP(k9, k10);  CSWAP(k8, k9);   CSWAP(k7, k8);
      CSWAP(k6, k7);   CSWAP(k5, k6);   CSWAP(k4, k5);   CSWAP(k3, k4);
      CSWAP(k2, k3);   CSWAP(k1, k2);   CSWAP(k0, k1);
    }
  }
  lists[0 * 64 + lane] = k0;   lists[1 * 64 + lane] = k1;
  lists[2 * 64 + lane] = k2;   lists[3 * 64 + lane] = k3;
  lists[4 * 64 + lane] = k4;   lists[5 * 64 + lane] = k5;
  lists[6 * 64 + lane] = k6;   lists[7 * 64 + lane] = k7;
  lists[8 * 64 + lane] = k8;   lists[9 * 64 + lane] = k9;
  lists[10 * 64 + lane] = k10; lists[11 * 64 + lane] = k11;
  lists[12 * 64 + lane] = k12; lists[13 * 64 + lane] = k13;
  lists[14 * 64 + lane] = k14; lists[15 * 64 + lane] = k15;
  __syncthreads();
  int head = 0;
  u64 outk = 0;
  for (int r = 0; r < 16; ++r) {
    u64 h = lists[head * 64 + lane];
    u64 mn = h;
#pragma unroll
    for (int mask = 32; mask; mask >>= 1) {
      u64 o = __shfl_xor(mn, mask);
      if (o < mn) mn = o;
    }
    if (h == mn) head++;
    if (lane == r) outk = mn;
  }
  if (lane < 16) win[lane] = outk;
  __syncthreads();
}

// softmax alphas over 16 neighbor coordinate offsets (all lanes redundant)
__device__ __forceinline__ void lae_alphas(const float4* __restrict__ xwb, int n,
                                           const int* idv, const float* __restrict__ A,
                                           float* al) {
  float ax = A[0], ay = A[1], az = A[2];
  float4 q = xwb[n];
  float mx = -3.0e38f;
#pragma unroll
  for (int k = 0; k < 16; ++k) {
    float4 p = xwb[idv[k]];
    float gx = p.x - q.x, gy = p.y - q.y, gz = p.z - q.z;
    float s = gx * ax + gy * ay + gz * az;
    al[k] = s;
    mx = fmaxf(mx, s);
  }
  float sum = 0.0f;
#pragma unroll
  for (int k = 0; k < 16; ++k) { al[k] = expf(al[k] - mx); sum += al[k]; }
#pragma unroll
  for (int k = 0; k < 16; ++k) al[k] = al[k] / sum;
}

// ---------------------------------------------------------------------------
// FPS body. Contiguous per-thread point chunks (pt = tid*PTS + p) so lane
// order == point order. Per-iter: dist update + local argmax (strict > keeps
// lowest p) -> f32 6-level shuffle max -> ballot+ffsll picks lowest tied lane
// -> shfl extracts its point idx -> cross-wave u64 (dist_bits<<32 | ~idx)
// compare (max dist, tie -> lowest idx). Exact jnp.argmax semantics.
// ---------------------------------------------------------------------------
template <int NT, int PTS, int NPT>
__device__ __forceinline__ void fps_body(const float4* __restrict__ xw, int N, int npoint,
                                         int* __restrict__ idx_out,
                                         float4* __restrict__ xw_out, u64* smem, int b,
                                         int tid) {
#pragma clang fp contract(off)
  constexpr int NW = NT / 64;
  constexpr bool FULL = (NT * PTS == NPT);
  u64* rk = smem;
  int* hist = (int*)(smem + 2 * NW);
  float* sxyz = (float*)(hist + 512);
  const float4* xb = xw + (size_t)b * N;
  for (int i = tid; i < N; i += NT) {
    float4 p = xb[i];
    sxyz[3 * i + 0] = p.x;
    sxyz[3 * i + 1] = p.y;
    sxyz[3 * i + 2] = p.z;
  }
  float px[PTS], py[PTS], pz[PTS], dist[PTS];
#pragma unroll
  for (int p = 0; p < PTS; ++p) {
    int pt = tid * PTS + p;
    if (FULL || pt < N) {
      float4 v = xb[pt];
      px[p] = v.x;
      py[p] = v.y;
      pz[p] = v.z;
    }
    dist[p] = 1e10f;
  }
  __syncthreads();
  int far = 0;
  float cx = sxyz[0], cy = sxyz[1], cz = sxyz[2];
  for (int t = 0; t < npoint; ++t) {
    if (tid == 0) hist[t] = far;
    float bestd = -1.0f;
    int bestp = 0;
#pragma unroll
    for (int p = 0; p < PTS; ++p) {
      int pt = tid * PTS + p;
      if (FULL || pt < N) {
        float dx = px[p] - cx, dy = py[p] - cy, dz = pz[p] - cz;
        float d = dx * dx + dy * dy + dz * dz;
        float nd = fminf(dist[p], d);
        dist[p] = nd;
        if (nd > bestd) { bestd = nd; bestp = pt; }  // ascending pt: keeps lowest
      }
    }
    float wmax = bestd;
#pragma unroll
    for (int m = 1; m <= 32; m <<= 1) wmax = fmaxf(wmax, __shfl_xor(wmax, m));
    u64 mask = __ballot(bestd == wmax);
    int wl = __ffsll(mask) - 1;
    int widx = __shfl(bestp, wl);
    u64 key = (wmax < 0.0f)
                  ? 0ull
                  : (((u64)__float_as_uint(wmax) << 32) | (unsigned)(~widx));
    if constexpr (NW > 1) {
      int par = (t & 1) * NW;
      if ((tid & 63) == 0) rk[par + (tid >> 6)] = key;
      __syncthreads();
      key = rk[par + 0];
#pragma unroll
      for (int w = 1; w < NW; ++w) {
        u64 o = rk[par + w];
        if (o > key) key = o;
      }
    }
    far = (int)(~(unsigned)key);
    cx = sxyz[3 * far + 0];
    cy = sxyz[3 * far + 1];
    cz = sxyz[3 * far + 2];
  }
  __syncthreads();
  for (int s = tid; s < npoint; s += NT) {
    int idp = hist[s];
    idx_out[(size_t)b * npoint + s] = idp;
    xw_out[(size_t)b * npoint + s] = xb[idp];
  }
}

// ---------------------------------------------------------------------------
// knn_gw body: kNN + ball filter + softmax-weighted feature sum with source
// row indirection. One wave per query.
// ---------------------------------------------------------------------------
__device__ __forceinline__ void knn_gw_body(const float4* __restrict__ xw_s, int N, float r2,
                                            int* __restrict__ idxK,
                                            const int* __restrict__ srcmap,
                                            const float* __restrict__ fea_src, int Nsrc,
                                            int Cin, const float* __restrict__ A,
                                            float* __restrict__ wf, int bn, int lane,
                                            u64* lists, u64* win) {
  int b = bn / N, n = bn - b * N;
  const float4* xb = xw_s + (size_t)b * N;
  knn16_search(xb, N, n, lane, lists, win);
  int idv[16];
#pragma unroll
  for (int k = 0; k < 16; ++k) {
    u64 kk = win[k];
    float d2 = __uint_as_float((unsigned)(kk >> 32));
    idv[k] = (d2 <= r2) ? (int)(kk & 0xFFFFFFFFu) : n;
  }
  if (lane < 16) idxK[(size_t)bn * 16 + lane] = idv[lane];
  float al[16];
  lae_alphas(xb, n, idv, A, al);
  int row[16];
  const int* sm = srcmap + (size_t)b * N;
#pragma unroll
  for (int k = 0; k < 16; ++k) row[k] = sm[idv[k]];
  const float* fb = fea_src + (size_t)b * Nsrc * Cin;
  float* wo = wf + (size_t)bn * Cin;
  for (int c = lane; c < Cin; c += 64) {
    float acc = 0.0f;
#pragma unroll
    for (int k = 0; k < 16; ++k) acc += al[k] * fb[(size_t)row[k] * Cin + c];
    wo[c] = acc;
  }
}

// L0 variant: fea == xyz (Cin=3) with fused K=3 mini-GEMM -> fea0 (Cout=64)
__device__ __forceinline__ void knn_gw0_body(const float4* __restrict__ xw, int N, float r2,
                                             int* __restrict__ idxK,
                                             const float* __restrict__ W0,
                                             const float* __restrict__ b0,
                                             const float* __restrict__ A0,
                                             float* __restrict__ fea0, int bn, int lane,
                                             u64* lists, u64* win) {
  int b = bn / N, n = bn - b * N;
  const float4* xb = xw + (size_t)b * N;
  knn16_search(xb, N, n, lane, lists, win);
  int idv[16];
#pragma unroll
  for (int k = 0; k < 16; ++k) {
    u64 kk = win[k];
    float d2 = __uint_as_float((unsigned)(kk >> 32));
    idv[k] = (d2 <= r2) ? (int)(kk & 0xFFFFFFFFu) : n;
  }
  if (lane < 16) idxK[(size_t)bn * 16 + lane] = idv[lane];
  float al[16];
  lae_alphas(xb, n, idv, A0, al);
  float w0 = 0.0f, w1 = 0.0f, w2 = 0.0f;
#pragma unroll
  for (int k = 0; k < 16; ++k) {
    float4 p = xb[idv[k]];
    w0 += al[k] * p.x;
    w1 += al[k] * p.y;
    w2 += al[k] * p.z;
  }
  float v = w0 * W0[0 * 64 + lane] + w1 * W0[1 * 64 + lane] + w2 * W0[2 * 64 + lane] +
            b0[lane];
  fea0[(size_t)bn * 64 + lane] = fmaxf(v, 0.0f);
}

// ---------------------------------------------------------------------------
// 3-NN inverse-distance body (pdist2 form, stable top-3), packed coords.
// ---------------------------------------------------------------------------
__device__ __forceinline__ void interp3_body(const float4* __restrict__ xd,
                                             const float4* __restrict__ xs, int Nd, int Ns,
                                             int* __restrict__ idx3, float* __restrict__ w3,
                                             int gid) {
#pragma clang fp contract(off)
  int b = gid / Nd;
  const float4* xb = xs + (size_t)b * Ns;
  float4 q = xd[gid];
  float qq = q.w;
  float v0 = 3.0e38f, v1 = 3.0e38f, v2 = 3.0e38f;
  int i0 = 0, i1 = 0, i2 = 0;
  for (int m = 0; m < Ns; ++m) {
    float4 p = xb[m];
    float ab = q.x * p.x + q.y * p.y + q.z * p.z;
    float d2 = fmaxf((qq + p.w) - 2.0f * ab, 0.0f);
    if (d2 < v2) {
      if (d2 < v0) { v2 = v1; i2 = i1; v1 = v0; i1 = i0; v0 = d2; i0 = m; }
      else if (d2 < v1) { v2 = v1; i2 = i1; v1 = d2; i1 = m; }
      else { v2 = d2; i2 = m; }
    }
  }
  float w0 = 1.0f / fmaxf(v0, 1e-10f);
  float w1 = 1.0f / fmaxf(v1, 1e-10f);
  float w2 = 1.0f / fmaxf(v2, 1e-10f);
  float s = w0 + w1 + w2;
  idx3[gid * 3 + 0] = i0; idx3[gid * 3 + 1] = i1; idx3[gid * 3 + 2] = i2;
  w3[gid * 3 + 0] = w0 / s; w3[gid * 3 + 1] = w1 / s; w3[gid * 3 + 2] = w2 / s;
}

// ---------------------------------------------------------------------------
// Tiled fp32 GEMM body (tile bx, by given explicitly so combos can pack it).
// Block 256 = 64 couts x 4 row-groups; tile 32 rows x 64 couts.
// ---------------------------------------------------------------------------
__device__ __forceinline__ void gemm_body(int bx, int by, const float* __restrict__ Amat,
                                          const float* __restrict__ W,
                                          const float* __restrict__ bias,
                                          float* __restrict__ out, int K, int Cout, int relu,
                                          float* lds_a) {
  int co = bx * 64 + (threadIdx.x & 63);
  int rg = threadIdx.x >> 6;
  int r0 = by * 32;
  float acc[8];
#pragma unroll
  for (int j = 0; j < 8; ++j) acc[j] = 0.0f;
  for (int k0 = 0; k0 < K; k0 += 32) {
    int row = threadIdx.x >> 3;
    int kq = (threadIdx.x & 7) * 4;
    int gk = k0 + kq;
    const float* ap = Amat + (size_t)(r0 + row) * K + gk;
    float a0 = 0.0f, a1 = 0.0f, a2 = 0.0f, a3 = 0.0f;
    if (gk + 3 < K) {
      float4 tv = *(const float4*)ap;
      a0 = tv.x; a1 = tv.y; a2 = tv.z; a3 = tv.w;
    } else {
      if (gk + 0 < K) a0 = ap[0];
      if (gk + 1 < K) a1 = ap[1];
      if (gk + 2 < K) a2 = ap[2];
    }
    __syncthreads();
    lds_a[(kq + 0) * 36 + row] = a0;
    lds_a[(kq + 1) * 36 + row] = a1;
    lds_a[(kq + 2) * 36 + row] = a2;
    lds_a[(kq + 3) * 36 + row] = a3;
    __syncthreads();
    int kmax = K - k0;
    if (kmax > 32) kmax = 32;
    if (kmax == 32) {
#pragma unroll
      for (int kk = 0; kk < 32; ++kk) {
        float w = W[(size_t)(k0 + kk) * Cout + co];
        const float* ar = &lds_a[kk * 36 + rg * 8];
        float4 x0 = *(const float4*)ar;
        float4 x1 = *(const float4*)(ar + 4);
        acc[0] += x0.x * w; acc[1] += x0.y * w; acc[2] += x0.z * w; acc[3] += x0.w * w;
        acc[4] += x1.x * w; acc[5] += x1.y * w; acc[6] += x1.z * w; acc[7] += x1.w * w;
      }
    } else {
      for (int kk = 0; kk < kmax; ++kk) {
        float w = W[(size_t)(k0 + kk) * Cout + co];
        const float* ar = &lds_a[kk * 36 + rg * 8];
        float4 x0 = *(const float4*)ar;
        float4 x1 = *(const float4*)(ar + 4);
        acc[0] += x0.x * w; acc[1] += x0.y * w; acc[2] += x0.z * w; acc[3] += x0.w * w;
        acc[4] += x1.x * w; acc[5] += x1.y * w; acc[6] += x1.z * w; acc[7] += x1.w * w;
      }
    }
  }
  float bb = bias ? bias[co] : 0.0f;
#pragma unroll
  for (int j = 0; j < 8; ++j) {
    int r = r0 + rg * 8 + j;
    float vv = acc[j] + bb;
    if (relu) vv = fmaxf(vv, 0.0f);
    out[(size_t)r * Cout + co] = vv;
  }
}

__global__ __launch_bounds__(256) void gemm_kernel(const float* __restrict__ Amat,
                                                   const float* __restrict__ W,
                                                   const float* __restrict__ bias,
                                                   float* __restrict__ out, int K, int Cout,
                                                   int relu) {
  __shared__ float lds_a[32 * 36];
  gemm_body(blockIdx.x, blockIdx.y, Amat, W, bias, out, K, Cout, relu, lds_a);
}

__global__ __launch_bounds__(256) void gemm_qkv_kernel(
    const float* __restrict__ Amat, const float* __restrict__ Wq,
    const float* __restrict__ Wk, const float* __restrict__ Wv, float* __restrict__ oq,
    float* __restrict__ ok, float* __restrict__ ov, int K, int Cout) {
  __shared__ float lds_a[32 * 36];
  const float* W = blockIdx.z == 0 ? Wq : (blockIdx.z == 1 ? Wk : Wv);
  float* o = blockIdx.z == 0 ? oq : (blockIdx.z == 1 ? ok : ov);
  gemm_body(blockIdx.x, blockIdx.y, Amat, W, nullptr, o, K, Cout, 0, lds_a);
}

// interp-add: Y[r][c] += sum_j w3[r][j] * Zb[i3[r][j]][c]  (bit-identical to
// the old fused GEMM epilogue decomposition)
__global__ __launch_bounds__(256) void interp_add_kernel(float* __restrict__ Y,
                                                         const int* __restrict__ i3,
                                                         const float* __restrict__ w3,
                                                         const float* __restrict__ Zb,
                                                         int Nd, int Ns, int C, int total) {
  int gid = blockIdx.x * 256 + threadIdx.x;
  if (gid >= total) return;
  int c = gid % C;
  int r = gid / C;
  int b = r / Nd;
  const int* ii = i3 + (size_t)r * 3;
  const float* ww = w3 + (size_t)r * 3;
  const float* zb = Zb + (size_t)b * Ns * C;
  Y[gid] += ww[0] * zb[(size_t)ii[0] * C + c] + ww[1] * zb[(size_t)ii[1] * C + c] +
            ww[2] * zb[(size_t)ii[2] * C + c];
}

// ---------------------------------------------------------------------------
// Combined launches (fps blocks FIRST so they are resident from t=0).
// ---------------------------------------------------------------------------
// A: fps 4096->512 (4 blocks) || knn_gw0 (4096 blocks x 4 queries)
__global__ __launch_bounds__(256) void combo_A_kernel(
    const float4* __restrict__ xw0, float r2, int* __restrict__ idxK0,
    const float* __restrict__ W0, const float* __restrict__ b0,
    const float* __restrict__ A0, float* __restrict__ fea0, int* __restrict__ idx1,
    float4* __restrict__ xw1) {
  __shared__ u64 smem[6432];
  if (blockIdx.x < NB) {
    fps_body<256, 16, 4096>(xw0, 4096, 512, idx1, xw1, smem, blockIdx.x, threadIdx.x);
  } else {
    int wave = threadIdx.x >> 6, lane = threadIdx.x & 63;
    int bn = (blockIdx.x - NB) * 4 + wave;
    knn_gw0_body(xw0, 4096, r2, idxK0, W0, b0, A0, fea0, bn, lane, smem + (size_t)wave * 1024,
                 smem + 4096 + wave * 16);
  }
}

// B: fps 512->128 (4) || knn_gw L1 (512 x 4 waves) || interp0 (64) || Y6a gemm (1024)
__global__ __launch_bounds__(256) void combo_B_kernel(
    const float4* __restrict__ xw0, const float4* __restrict__ xw1, float r2,
    int* __restrict__ idxK1, const int* __restrict__ idx1, const float* __restrict__ fea0,
    const float* __restrict__ A1, float* __restrict__ wf, int* __restrict__ idx2,
    float4* __restrict__ xw2, int* __restrict__ idxI0, float* __restrict__ wI0,
    const float* __restrict__ W6a, float* __restrict__ Y6) {
  __shared__ u64 smem[4160];
  int bid = blockIdx.x;
  if (bid < NB) {
    fps_body<256, 2, 512>(xw1, 512, 128, idx2, xw2, smem, bid, threadIdx.x);
  } else if (bid < NB + 512) {
    int wave = threadIdx.x >> 6, lane = threadIdx.x & 63;
    int bn = (bid - NB) * 4 + wave;
    knn_gw_body(xw1, 512, r2, idxK1, idx1, fea0, 4096, 64, A1, wf, bn, lane,
                smem + (size_t)wave * 1024, smem + 4096 + wave * 16);
  } else if (bid < NB + 512 + 64) {
    int gid = (bid - NB - 512) * 256 + threadIdx.x;
    interp3_body(xw0, xw1, 4096, 512, idxI0, wI0, gid);
  } else {
    int gb = bid - (NB + 512 + 64);
    gemm_body(gb & 1, gb >> 1, fea0, W6a, nullptr, Y6, 64, 128, 0, (float*)smem);
  }
}

// D: fps 128->64 (4) || knn_gw L2 (128 x 4 waves) || interp1 (8) || Y5a gemm (256)
__global__ __launch_bounds__(256) void combo_D_kernel(
    const float4* __restrict__ xw1, const float4* __restrict__ xw2, float r2,
    int* __restrict__ idxK2, const int* __restrict__ idx2, const float* __restrict__ fea1,
    const float* __restrict__ A2, float* __restrict__ wf, int* __restrict__ idx3,
    float4* __restrict__ xw3, int* __restrict__ idxI1, float* __restrict__ wI1,
    const float* __restrict__ W5a, float* __restrict__ Y5) {
  __shared__ u64 smem[4160];
  int bid = blockIdx.x;
  if (bid < NB) {
    fps_body<256, 1, 128>(xw2, 128, 64, idx3, xw3, smem, bid, threadIdx.x);
  } else if (bid < NB + 128) {
    int wave = threadIdx.x >> 6, lane = threadIdx.x & 63;
    int bn = (bid - NB) * 4 + wave;
    knn_gw_body(xw2, 128, r2, idxK2, idx2, fea1, 512, 128, A2, wf, bn, lane,
                smem + (size_t)wave * 1024, smem + 4096 + wave * 16);
  } else if (bid < NB + 128 + 8) {
    int gid = (bid - NB - 128) * 256 + threadIdx.x;
    interp3_body(xw1, xw2, 512, 128, idxI1, wI1, gid);
  } else {
    int gb = bid - (NB + 128 + 8);
    gemm_body(gb & 3, gb >> 2, fea1, W5a, nullptr, Y5, 128, 256, 0, (float*)smem);
  }
}

// H: knn_gw L3 (64 x 4 waves) || interp2 (2) || Y4a gemm (64)
__global__ __launch_bounds__(256) void combo_H_kernel(
    const float4* __restrict__ xw2, const float4* __restrict__ xw3, float r2,
    int* __restrict__ idxK3, const int* __restrict__ idx3, const float* __restrict__ fea2b,
    const float* __restrict__ A3, float* __restrict__ wf, int* __restrict__ idxI2,
    float* __restrict__ wI2, const float* __restrict__ W4a, float* __restrict__ Y4) {
  __shared__ u64 smem[4160];
  int bid = blockIdx.x;
  if (bid < 64) {
    int wave = threadIdx.x >> 6, lane = threadIdx.x & 63;
    int bn = bid * 4 + wave;
    knn_gw_body(xw3, 64, r2, idxK3, idx3, fea2b, 128, 256, A3, wf, bn, lane,
                smem + (size_t)wave * 1024, smem + 4096 + wave * 16);
  } else if (bid < 64 + 2) {
    int gid = (bid - 64) * 256 + threadIdx.x;
    interp3_body(xw2, xw3, 128, 64, idxI2, wI2, gid);
  } else {
    int gb = bid - 66;
    gemm_body(gb & 3, gb >> 2, fea2b, W4a, nullptr, Y4, 256, 256, 0, (float*)smem);
  }
}

// ---------------------------------------------------------------------------
// LAE gather-weight (POST-GEMM): out = relu(sum_k al_k Y[idx_k][c] + b[c])
// ---------------------------------------------------------------------------
__global__ __launch_bounds__(64) void gwpost_kernel(const float4* __restrict__ xw,
                                                    const float* __restrict__ Y,
                                                    const int* __restrict__ knn,
                                                    const float* __restrict__ A,
                                                    const float* __restrict__ bias,
                                                    float* __restrict__ out, int N, int C) {
  int bn = blockIdx.x;
  int b = bn / N, n = bn - b * N;
  int lane = threadIdx.x;
  const float4* xb = xw + (size_t)b * N;
  const int* kn = knn + (size_t)bn * 16;
  int idv[16];
#pragma unroll
  for (int k = 0; k < 16; ++k) idv[k] = kn[k];
  float al[16];
  lae_alphas(xb, n, idv, A, al);
  const float* Yb = Y + (size_t)b * N * C;
  float* wo = out + (size_t)bn * C;
  for (int c = lane; c < C; c += 64) {
    float acc = 0.0f;
#pragma unroll
    for (int k = 0; k < 16; ++k) acc += al[k] * Yb[(size_t)idv[k] * C + c];
    wo[c] = fmaxf(acc + bias[c], 0.0f);
  }
}

// L6 gwpost fused with final classifier (C=128 fixed), out (B,13,N)
__global__ __launch_bounds__(64) void gwpost_final_kernel(
    const float4* __restrict__ xw, const float* __restrict__ Y, const int* __restrict__ knn,
    const float* __restrict__ A, const float* __restrict__ bias,
    const float* __restrict__ Wf, const float* __restrict__ bfv, float* __restrict__ out,
    int N) {
  int bn = blockIdx.x;
  int b = bn / N, n = bn - b * N;
  int lane = threadIdx.x;
  const float4* xb = xw + (size_t)b * N;
  const int* kn = knn + (size_t)bn * 16;
  int idv[16];
#pragma unroll
  for (int k = 0; k < 16; ++k) idv[k] = kn[k];
  float al[16];
  lae_alphas(xb, n, idv, A, al);
  const float* Yb = Y + (size_t)b * N * 128;
  float a0 = 0.0f, a1 = 0.0f;
#pragma unroll
  for (int k = 0; k < 16; ++k) {
    const float* yr = Yb + (size_t)idv[k] * 128;
    a0 += al[k] * yr[lane];
    a1 += al[k] * yr[lane + 64];
  }
  float v0 = fmaxf(a0 + bias[lane], 0.0f);
  float v1 = fmaxf(a1 + bias[lane + 64], 0.0f);
  float* ob = out + ((size_t)b * 13) * N + n;
#pragma unroll
  for (int cls = 0; cls < 13; ++cls) {
    float p = v0 * Wf[lane * 13 + cls] + v1 * Wf[(lane + 64) * 13 + cls];
#pragma unroll
    for (int m = 32; m; m >>= 1) p += __shfl_xor(p, m);
    if (lane == 0) ob[(size_t)cls * N] = p + bfv[cls];
  }
}

// ---------------------------------------------------------------------------
// Self-attention mix: out[n] = softmax(q[n]·k^T) @ v + fea[n]. Block per (b,n).
// ---------------------------------------------------------------------------
__global__ __launch_bounds__(128) void attn_kernel(const float* __restrict__ q,
                                                   const float* __restrict__ k,
                                                   const float* __restrict__ v,
                                                   const float* __restrict__ fea,
                                                   float* __restrict__ out, int N, int C) {
  __shared__ float sa[128];
  __shared__ float sb[128];
  int b = blockIdx.y, n = blockIdx.x, t = threadIdx.x;
  const float* qn = q + ((size_t)b * N + n) * C;
  if (t < N) {
    const float4* km = (const float4*)(k + ((size_t)b * N + t) * C);
    const float4* q4 = (const float4*)qn;
    float acc = 0.0f;
    int C4 = C >> 2;
    for (int c = 0; c < C4; ++c) {
      float4 kv = km[c];
      float4 qv = q4[c];
      acc += qv.x * kv.x + qv.y * kv.y + qv.z * kv.z + qv.w * kv.w;
    }
    sa[t] = acc;
  }
  __syncthreads();
  float mx = -3.0e38f;
  for (int i = 0; i < N; ++i) mx = fmaxf(mx, sa[i]);
  if (t < N) sb[t] = expf(sa[t] - mx);
  __syncthreads();
  float sum = 0.0f;
  for (int i = 0; i < N; ++i) sum += sb[i];
  size_t rowo = ((size_t)b * N + n) * C;
  for (int c = t; c < C; c += 128) {
    float acc = 0.0f;
    for (int m = 0; m < N; ++m) acc += sb[m] * v[((size_t)b * N + m) * C + c];
    out[rowo + c] = acc / sum + fea[rowo + c];
  }
}

// ---------------------------------------------------------------------------
extern "C" void kernel_launch(void* const* d_in, const int* in_sizes, int n_in,
                              void* d_out, int out_size, void* d_ws, size_t ws_size,
                              hipStream_t stream) {
  (void)in_sizes; (void)n_in; (void)out_size; (void)ws_size;
  const float* xyz = (const float*)d_in[0];
  const float* W[7]; const float* bi[7]; const float* A[7];
  for (int i = 0; i < 7; ++i) {
    W[i] = (const float*)d_in[1 + 3 * i];
    bi[i] = (const float*)d_in[2 + 3 * i];
    A[i] = (const float*)d_in[3 + 3 * i];
  }
  const float* Wq1 = (const float*)d_in[22];
  const float* Wk1 = (const float*)d_in[23];
  const float* Wv1 = (const float*)d_in[24];
  const float* Wq2 = (const float*)d_in[25];
  const float* Wk2 = (const float*)d_in[26];
  const float* Wv2 = (const float*)d_in[27];
  const float* Wq3 = (const float*)d_in[28];
  const float* Wk3 = (const float*)d_in[29];
  const float* Wv3 = (const float*)d_in[30];
  const float* Wf = (const float*)d_in[31];
  const float* bf = (const float*)d_in[32];
  float* out = (float*)d_out;

  const int B = NB, N0 = 4096, N1 = 512, N2 = 128, N3 = 64;
  char* base = (char*)d_ws;
  size_t off = 0;
  auto alloc = [&](size_t bytes) -> void* {
    void* p = base + off;
    off += (bytes + 255) & ~(size_t)255;
    return p;
  };
  float4* xw0 = (float4*)alloc((size_t)B * N0 * 16);
  float4* xw1 = (float4*)alloc((size_t)B * N1 * 16);
  float4* xw2 = (float4*)alloc((size_t)B * N2 * 16);
  float4* xw3 = (float4*)alloc((size_t)B * N3 * 16);
  int* idxK0 = (int*)alloc((size_t)B * N0 * 16 * 4);
  int* idxK1 = (int*)alloc((size_t)B * N1 * 16 * 4);
  int* idxK2 = (int*)alloc((size_t)B * N2 * 16 * 4);
  int* idxK3 = (int*)alloc((size_t)B * N3 * 16 * 4);
  int* idx1 = (int*)alloc((size_t)B * N1 * 4);
  int* idx2 = (int*)alloc((size_t)B * N2 * 4);
  int* idx3 = (int*)alloc((size_t)B * N3 * 4);
  float* fea0 = (float*)alloc((size_t)B * N0 * 64 * 4);
  float* fea1 = (float*)alloc((size_t)B * N1 * 128 * 4);
  float* fea1b = (float*)alloc((size_t)B * N1 * 256 * 4);
  float* fea2a = (float*)alloc((size_t)B * N2 * 256 * 4);
  float* fea2b = (float*)alloc((size_t)B * N2 * 256 * 4);
  float* fea2c = (float*)alloc((size_t)B * N2 * 256 * 4);
  float* fea2d = (float*)alloc((size_t)B * N2 * 256 * 4);
  float* fea3a = (float*)alloc((size_t)B * N3 * 512 * 4);
  float* fea3b = (float*)alloc((size_t)B * N3 * 512 * 4);
  float* qb = (float*)alloc((size_t)B * 32768 * 4);
  float* kb = (float*)alloc((size_t)B * 32768 * 4);
  float* vb = (float*)alloc((size_t)B * 32768 * 4);
  int* idxI2 = (int*)alloc((size_t)B * N2 * 3 * 4);
  float* wI2 = (float*)alloc((size_t)B * N2 * 3 * 4);
  int* idxI1 = (int*)alloc((size_t)B * N1 * 3 * 4);
  float* wI1 = (float*)alloc((size_t)B * N1 * 3 * 4);
  int* idxI0 = (int*)alloc((size_t)B * N0 * 3 * 4);
  float* wI0 = (float*)alloc((size_t)B * N0 * 3 * 4);
  float* Zb4 = (float*)alloc((size_t)B * N3 * 256 * 4);
  float* Zb5 = (float*)alloc((size_t)B * N2 * 256 * 4);
  float* Zb6 = (float*)alloc((size_t)B * N1 * 128 * 4);
  float* Y4 = (float*)alloc((size_t)B * N2 * 256 * 4);
  float* Y5 = (float*)alloc((size_t)B * N1 * 256 * 4);
  float* Y6 = (float*)alloc((size_t)B * N0 * 128 * 4);
  float* wfb = (float*)alloc((size_t)B * N0 * 320 * 4);

  float r2_0 = (float)(0.06 * 0.06);
  float r2_1 = (float)(0.12 * 0.12);
  float r2_2 = (float)(0.3 * 0.3);
  float r2_3 = (float)(0.5 * 0.5);

  // 0: pack coords + norms
  norms_kernel<<<B * N0 / 256, 256, 0, stream>>>(xyz, xw0, B * N0);

  // A: fps(4096->512) || L0 knn+gw+gemm
  combo_A_kernel<<<B + B * N0 / 4, 256, 0, stream>>>(xw0, r2_0, idxK0, W[0], bi[0], A[0],
                                                     fea0, idx1, xw1);
  // B: fps(512->128) || L1 knn+gw || interp0 || Y6a = fea0@W6a
  combo_B_kernel<<<NB + 512 + 64 + 1024, 256, 0, stream>>>(
      xw0, xw1, r2_1, idxK1, idx1, fea0, A[1], wfb, idx2, xw2, idxI0, wI0, W[6], Y6);
  // C: gemm L1 -> fea1
  gemm_kernel<<<dim3(2, B * N1 / 32), 256, 0, stream>>>(wfb, W[1], bi[1], fea1, 64, 128, 1);
  // D: fps(128->64) || L2 knn+gw || interp1 || Y5a = fea1@W5a
  combo_D_kernel<<<NB + 128 + 8 + 256, 256, 0, stream>>>(
      xw1, xw2, r2_2, idxK2, idx2, fea1, A[2], wfb, idx3, xw3, idxI1, wI1, W[5], Y5);
  // E: gemm L2 -> fea2a; qkv1; attn1 -> fea2b
  gemm_kernel<<<dim3(4, B * N2 / 32), 256, 0, stream>>>(wfb, W[2], bi[2], fea2a, 128, 256, 1);
  gemm_qkv_kernel<<<dim3(4, B * N2 / 32, 3), 256, 0, stream>>>(fea2a, Wq1, Wk1, Wv1, qb, kb,
                                                               vb, 256, 256);
  attn_kernel<<<dim3(N2, B), 128, 0, stream>>>(qb, kb, vb, fea2a, fea2b, N2, 256);

  // H: L3 knn+gw || interp2 || Y4a = fea2b@W4a
  combo_H_kernel<<<64 + 2 + 64, 256, 0, stream>>>(xw2, xw3, r2_3, idxK3, idx3, fea2b, A[3],
                                                  wfb, idxI2, wI2, W[4], Y4);
  // I: gemm L3 -> fea3a; qkv2; attn2 -> fea3b
  gemm_kernel<<<dim3(8, B * N3 / 32), 256, 0, stream>>>(wfb, W[3], bi[3], fea3a, 256, 512, 1);
  gemm_qkv_kernel<<<dim3(8, B * N3 / 32, 3), 256, 0, stream>>>(fea3a, Wq2, Wk2, Wv2, qb, kb,
                                                               vb, 512, 512);
  attn_kernel<<<dim3(N3, B), 128, 0, stream>>>(qb, kb, vb, fea3a, fea3b, N3, 512);

  // L4: Zb4 = fea3b@W4b; Y4 += interp(Zb4); gwpost -> fea2c; qkv3; attn3
  gemm_kernel<<<dim3(4, B * N3 / 32), 256, 0, stream>>>(fea3b, W[4] + 256 * 256, nullptr, Zb4,
                                                        512, 256, 0);
  interp_add_kernel<<<B * N2 * 256 / 256, 256, 0, stream>>>(Y4, idxI2, wI2, Zb4, N2, N3, 256,
                                                            B * N2 * 256);
  gwpost_kernel<<<B * N2, 64, 0, stream>>>(xw2, Y4, idxK2, A[4], bi[4], fea2c, N2, 256);
  gemm_qkv_kernel<<<dim3(4, B * N2 / 32, 3), 256, 0, stream>>>(fea2c, Wq3, Wk3, Wv3, qb, kb,
                                                               vb, 256, 256);
  attn_kernel<<<dim3(N2, B), 128, 0, stream>>>(qb, kb, vb, fea2c, fea2d, N2, 256);

  // L5: Zb5 = fea2d@W5b; Y5 += interp(Zb5); gwpost -> fea1b
  gemm_kernel<<<dim3(4, B * N2 / 32), 256, 0, stream>>>(fea2d, W[5] + 128 * 256, nullptr, Zb5,
                                                        256, 256, 0);
  interp_add_kernel<<<B * N1 * 256 / 256, 256, 0, stream>>>(Y5, idxI1, wI1, Zb5, N1, N2, 256,
                                                            B * N1 * 256);
  gwpost_kernel<<<B * N1, 64, 0, stream>>>(xw1, Y5, idxK1, A[5], bi[5], fea1b, N1, 256);

  // L6: Zb6 = fea1b@W6b; Y6 += interp(Zb6); gwpost+final -> out
  gemm_kernel<<<dim3(2, B * N1 / 32), 256, 0, stream>>>(fea1b, W[6] + 64 * 128, nullptr, Zb6,
                                                        256, 128, 0);
  interp_add_kernel<<<B * N0 * 128 / 256, 256, 0, stream>>>(Y6, idxI0, wI0, Zb6, N0, N1, 128,
                                                            B * N0 * 128);
  gwpost_final_kernel<<<B * N0, 64, 0, stream>>>(xw0, Y6, idxK0, A[6], bi[6], Wf, bf, out,
                                                 N0);
}